// Round 5
// baseline (301.391 us; speedup 1.0000x reference)
//
#include <hip/hip_runtime.h>

#define NTOK 196
#define QPAD 208
#define KP 208
#define PSTR 232
#define VKP 208

typedef __attribute__((ext_vector_type(8))) short short8;
typedef __attribute__((ext_vector_type(4))) short short4_t;
typedef __attribute__((ext_vector_type(4))) float float4_t;

__device__ __forceinline__ short f2bf(float f) {
  unsigned u = __float_as_uint(f);
  u = (u + 0x7fffu + ((u >> 16) & 1u)) >> 16;
  return (short)u;
}

// ---------------- fallback: signal insufficient workspace ----------------
__global__ __launch_bounds__(256) void fill_kernel(float* __restrict__ out,
                                                   int n) {
  int i = blockIdx.x * 256 + threadIdx.x;
  if (i < n) out[i] = 1000.0f;
}

// ---------------- x fp32 -> bf16 (fused fallback path only) ----------------
__global__ __launch_bounds__(256) void cvt_kernel(const float* __restrict__ in,
                                                  short* __restrict__ out) {
  int i = (blockIdx.x * 256 + threadIdx.x) * 8;  // total = 25088*512
  float4_t a = *(const float4_t*)&in[i];
  float4_t b = *(const float4_t*)&in[i + 4];
  short8 v;
  v[0] = f2bf(a[0]); v[1] = f2bf(a[1]); v[2] = f2bf(a[2]); v[3] = f2bf(a[3]);
  v[4] = f2bf(b[0]); v[5] = f2bf(b[1]); v[6] = f2bf(b[2]); v[7] = f2bf(b[3]);
  *(short8*)&out[i] = v;
}

// ------------- transpose body: out_bf16[C][R] = in_f32[R][C] -----------------
__device__ __forceinline__ void transpose_body(const float* __restrict__ in,
                                               short* __restrict__ out, int R,
                                               int C, int bx, int by,
                                               float (*tile)[65]) {
  int c0 = bx * 64, r0 = by * 64;
  int tc = threadIdx.x & 63, tr = threadIdx.x >> 6;
#pragma unroll
  for (int s = 0; s < 16; s++) {
    int r = s * 4 + tr;
    tile[r][tc] = in[(r0 + r) * C + c0 + tc];
  }
  __syncthreads();
#pragma unroll
  for (int s = 0; s < 16; s++) {
    int i = s * 4 + tr;
    out[(c0 + i) * R + r0 + tc] = f2bf(tile[tc][i]);
  }
}

// ---- merged preamble: transposes + bias gather + V^T pad zero (1 launch) ----
// blocks [0,192): qkv_w^T  [192,256): proj_w^T  [256,2960): bias  [2960,3728): vpad
__global__ __launch_bounds__(256) void prep_kernel(
    const float* __restrict__ qkv_w, const float* __restrict__ proj_w,
    const float* __restrict__ table, const int* __restrict__ rpi,
    short* __restrict__ wt1, short* __restrict__ wt2, float* __restrict__ bias,
    short* __restrict__ vb, int do_vpad) {
  __shared__ float tile[64][65];
  int blk = blockIdx.x;
  if (blk < 192) {
    transpose_body(qkv_w, wt1, 512, 1536, blk % 24, blk / 24, tile);
  } else if (blk < 256) {
    int i = blk - 192;
    transpose_body(proj_w, wt2, 512, 512, i % 8, i / 8, tile);
  } else if (blk < 2960) {
    int idx = (blk - 256) * 256 + threadIdx.x;  // < 16*208*208 = 692224
    int h = idx / (QPAD * KP);
    int rem = idx % (QPAD * KP);
    int q = rem / KP, k = rem % KP;
    float v = 0.f;
    if (q < NTOK && k < NTOK) v = table[rpi[q * NTOK + k] * 16 + h];
    bias[idx] = v;
  } else if (do_vpad) {
    int i = (blk - 2960) * 256 + threadIdx.x;  // < 2048*32*3 = 196608
    int row = i / 3, g = i - 3 * (i / 3);
    short4_t z = {0, 0, 0, 0};
    *(short4_t*)&vb[row * VKP + 196 + g * 4] = z;
  }
}

// ---------------- shared 128x128 GEMM mainloop (validated, padded LDS) -------
// CVTA: stage A from fp32 with in-register bf16 convert (fuses cvt_kernel).
template <bool CVTA>
__device__ __forceinline__ void gemm_tile_t(const void* __restrict__ Aptr,
                                            const short* __restrict__ B, int K,
                                            int m0, int n0, short (*As)[72],
                                            short (*Bs)[72],
                                            float4_t acc[4][4]) {
  int tid = threadIdx.x;
  int lane = tid & 63, wave = tid >> 6;
  int quad = lane >> 4, l16 = lane & 15;
  int wm = (wave >> 1) * 64, wn = (wave & 1) * 64;
  int srow = tid >> 3, scol = (tid & 7) * 8;
  for (int k0 = 0; k0 < K; k0 += 64) {
#pragma unroll
    for (int i = 0; i < 4; i++) {
      int r = srow + i * 32;
      if (CVTA) {
        const float* Af = (const float*)Aptr;
        float4_t a = *(const float4_t*)&Af[(m0 + r) * K + k0 + scol];
        float4_t b = *(const float4_t*)&Af[(m0 + r) * K + k0 + scol + 4];
        short8 v;
        v[0] = f2bf(a[0]); v[1] = f2bf(a[1]);
        v[2] = f2bf(a[2]); v[3] = f2bf(a[3]);
        v[4] = f2bf(b[0]); v[5] = f2bf(b[1]);
        v[6] = f2bf(b[2]); v[7] = f2bf(b[3]);
        *(short8*)&As[r][scol] = v;
      } else {
        const short* Ab = (const short*)Aptr;
        *(short8*)&As[r][scol] = *(const short8*)&Ab[(m0 + r) * K + k0 + scol];
      }
      *(short8*)&Bs[r][scol] = *(const short8*)&B[(n0 + r) * K + k0 + scol];
    }
    __syncthreads();
#pragma unroll
    for (int ks = 0; ks < 2; ks++) {
      short8 af[4], bfr[4];
#pragma unroll
      for (int i = 0; i < 4; i++) {
        af[i] = *(short8*)&As[wm + i * 16 + l16][ks * 32 + quad * 8];
        bfr[i] = *(short8*)&Bs[wn + i * 16 + l16][ks * 32 + quad * 8];
      }
#pragma unroll
      for (int mi = 0; mi < 4; mi++)
#pragma unroll
        for (int ni = 0; ni < 4; ni++)
          acc[mi][ni] = __builtin_amdgcn_mfma_f32_16x16x32_bf16(
              af[mi], bfr[ni], acc[mi][ni], 0, 0, 0);
    }
    __syncthreads();
  }
}

// -------- split path: QKV GEMM (A = fp32 x, converted in staging) --------
// V is written TRANSPOSED: vb[bh][d][VKP] so attn stages it with a coalesced
// row copy. rowg0 is a multiple of 4 and 196 % 4 == 0, so a 4-row group never
// straddles a batch boundary -> one short4 store.
__global__ __launch_bounds__(256) void qkv_gemm(
    const float* __restrict__ x, const short* __restrict__ wt1,
    short* __restrict__ qb, short* __restrict__ kb, short* __restrict__ vb) {
  __shared__ __align__(16) short As[128][72];
  __shared__ __align__(16) short Bs[128][72];
  float4_t acc[4][4];
  float4_t z = {0.f, 0.f, 0.f, 0.f};
#pragma unroll
  for (int i = 0; i < 4; i++)
#pragma unroll
    for (int j = 0; j < 4; j++) acc[i][j] = z;
  // XCD-chunked bijective swizzle: nwg = 12*196 = 2352 = 8*294
  int lin = blockIdx.x + blockIdx.y * 12;
  int xcd = lin & 7, loc = lin >> 3;
  int nl = xcd * 294 + loc;
  int bx = nl % 12, by = nl / 12;
  int m0 = by * 128, n0 = bx * 128;
  gemm_tile_t<true>(x, wt1, 512, m0, n0, As, Bs, acc);
  int lane = threadIdx.x & 63, wave = threadIdx.x >> 6;
  int quad = lane >> 4, l16 = lane & 15;
  int wm = (wave >> 1) * 64, wn = (wave & 1) * 64;
  const float qscale = 0.17677669529663687f;  // 32^-0.5
#pragma unroll
  for (int mi = 0; mi < 4; mi++)
#pragma unroll
    for (int ni = 0; ni < 4; ni++) {
      int colg = n0 + wn + ni * 16 + l16;
      int s = colg >> 9, rem = colg & 511;
      int h = rem >> 5, d = rem & 31;
      int rowg0 = m0 + wm + mi * 16 + quad * 4;
      if (s == 2) {
        int b = rowg0 / NTOK, nt = rowg0 - b * NTOK;  // nt % 4 == 0, <= 192
        short4_t v4;
        v4[0] = f2bf(acc[mi][ni][0]);
        v4[1] = f2bf(acc[mi][ni][1]);
        v4[2] = f2bf(acc[mi][ni][2]);
        v4[3] = f2bf(acc[mi][ni][3]);
        *(short4_t*)&vb[((b * 16 + h) * 32 + d) * VKP + nt] = v4;
      } else {
#pragma unroll
        for (int r = 0; r < 4; r++) {
          int rowg = rowg0 + r;
          int b = rowg / NTOK, n = rowg - b * NTOK;
          int off = ((b * 16 + h) * QPAD + n) * 32 + d;
          if (s == 0)
            qb[off] = f2bf(acc[mi][ni][r] * qscale);
          else
            kb[off] = f2bf(acc[mi][ni][r]);
        }
      }
    }
}

// -------- split path: attention, one block per (b,h), 8 waves --------
// 8 waves x 2 q-tile rounds (was 4 waves x 4): LDS 74.2 KB -> 2 blocks/CU
// = 16 waves/CU (was 12). P is WAVE-PRIVATE -> only the staging barrier.
// 1/sum normalization deferred from P (13 muls/row) to fp32 epilogue (2).
__global__ __launch_bounds__(512) void attn_kernel(
    const short* __restrict__ qb, const short* __restrict__ kb,
    const short* __restrict__ vb, const float* __restrict__ bias,
    short* __restrict__ aout) {
  __shared__ __align__(16) short vT[32][PSTR];
  __shared__ __align__(16) short P[8][16][PSTR];
  int bh = blockIdx.x, b = bh >> 4, h = bh & 15;
  int tid = threadIdx.x, wave = tid >> 6, lane = tid & 63;
  int quad = lane >> 4, l16 = lane & 15;
  int base_row = b * NTOK;
  // stage V^T rows: 32 rows x 208 shorts, coalesced 16B chunks
  const short* vsrc = vb + bh * 32 * VKP;
  for (int i = tid; i < 32 * 26; i += 512) {
    int d = i / 26, c = (i - d * 26) * 8;
    *(short8*)&vT[d][c] = *(const short8*)&vsrc[d * VKP + c];
  }
  short8 z8 = {0, 0, 0, 0, 0, 0, 0, 0};
  if (tid < 32 * 3) {
    int d = tid / 3, c = 208 + (tid - d * 3) * 8;
    *(short8*)&vT[d][c] = z8;
  }
  __syncthreads();
  float4_t z4 = {0.f, 0.f, 0.f, 0.f};
  for (int i2 = 0; i2 < 2; i2++) {
    int qt = wave + 8 * i2;
    if (qt > 12) break;  // waves 5-7 exit after round 0; no barriers below
    int qr0 = qt * 16;
    short8 qf = *(const short8*)&qb[(bh * QPAD + qr0 + l16) * 32 + quad * 8];
    float4_t s[13];
#pragma unroll
    for (int kt = 0; kt < 13; kt++) {
      short8 kf =
          *(const short8*)&kb[(bh * QPAD + kt * 16 + l16) * 32 + quad * 8];
      s[kt] = __builtin_amdgcn_mfma_f32_16x16x32_bf16(qf, kf, z4, 0, 0, 0);
    }
    const float* brow = bias + (h * QPAD + qr0 + quad * 4) * KP;
#pragma unroll
    for (int kt = 0; kt < 13; kt++) {
      int col = kt * 16 + l16;
#pragma unroll
      for (int r = 0; r < 4; r++) s[kt][r] += brow[r * KP + col];
    }
    if (l16 >= 4) {
#pragma unroll
      for (int r = 0; r < 4; r++) s[12][r] = -1e30f;  // mask pad keys
    }
    float invr[4];
#pragma unroll
    for (int r = 0; r < 4; r++) {
      float m = s[0][r];
#pragma unroll
      for (int kt = 1; kt < 13; kt++) m = fmaxf(m, s[kt][r]);
      m = fmaxf(m, __shfl_xor(m, 8, 16));
      m = fmaxf(m, __shfl_xor(m, 4, 16));
      m = fmaxf(m, __shfl_xor(m, 2, 16));
      m = fmaxf(m, __shfl_xor(m, 1, 16));
      float sum = 0.f;
#pragma unroll
      for (int kt = 0; kt < 13; kt++) {
        float p = __expf(s[kt][r] - m);
        s[kt][r] = p;
        sum += p;
      }
      sum += __shfl_xor(sum, 8, 16);
      sum += __shfl_xor(sum, 4, 16);
      sum += __shfl_xor(sum, 2, 16);
      sum += __shfl_xor(sum, 1, 16);
      invr[r] = 1.f / sum;
      short* prow = &P[wave][quad * 4 + r][0];
#pragma unroll
      for (int kt = 0; kt < 13; kt++)
        prow[kt * 16 + l16] = f2bf(s[kt][r]);  // unnormalized, <= 1
      prow[208 + l16] = 0;  // zero pad cols 208..223 (224.. never read)
    }
    // in-wave LDS ordering guarantees P writes visible to same-wave reads
    float4_t o0 = z4, o1 = z4;
#pragma unroll
    for (int kt = 0; kt < 7; kt++) {
      short8 pf = *(short8*)&P[wave][l16][kt * 32 + quad * 8];
      short8 vf0 = *(short8*)&vT[l16][kt * 32 + quad * 8];
      short8 vf1 = *(short8*)&vT[16 + l16][kt * 32 + quad * 8];
      o0 = __builtin_amdgcn_mfma_f32_16x16x32_bf16(pf, vf0, o0, 0, 0, 0);
      o1 = __builtin_amdgcn_mfma_f32_16x16x32_bf16(pf, vf1, o1, 0, 0, 0);
    }
#pragma unroll
    for (int r = 0; r < 4; r++) {
      int row = qr0 + quad * 4 + r;
      if (row < NTOK) {
        int off = (base_row + row) * 512 + h * 32;
        aout[off + l16] = f2bf(o0[r] * invr[r]);
        aout[off + 16 + l16] = f2bf(o1[r] * invr[r]);
      }
    }
  }
}

// ---------------- fallback fused QKV-GEMM + attention (round-4, validated) ---
__global__ __launch_bounds__(256, 2) void fused_attn(
    const short* __restrict__ xb, const short* __restrict__ wt1,
    const float* __restrict__ bias, short* __restrict__ aout) {
  __shared__ __align__(16) short R1[64 * PSTR];
  __shared__ __align__(16) short R2[32 * PSTR];
  __shared__ __align__(16) short Qs[224][40];
  __shared__ __align__(16) short Ks[224][40];
  short(*As)[40] = (short(*)[40])R1;
  short(*P)[PSTR] = (short(*)[PSTR])R1;
  short(*Bs)[40] = (short(*)[40])R2;
  short(*vTs)[PSTR] = (short(*)[PSTR])R2;

  int bh = blockIdx.x, b = bh >> 4, h = bh & 15;
  int tid = threadIdx.x, wave = tid >> 6, lane = tid & 63;
  int quad = lane >> 4, l16 = lane & 15;
  int base_row = b * NTOK;

  float4_t z4 = {0.f, 0.f, 0.f, 0.f};
  float4_t acc[4][6];
#pragma unroll
  for (int i = 0; i < 4; i++)
#pragma unroll
    for (int n = 0; n < 6; n++) acc[i][n] = z4;

  int srow = tid >> 2, scol = (tid & 3) * 8;
  for (int k0 = 0; k0 < 512; k0 += 32) {
#pragma unroll
    for (int i = 0; i < 4; i++) {
      int r = srow + i * 64;
      if (r < 224) {
        int gr = base_row + r;
        if (gr > 25087) gr = 25087;
        *(short8*)&As[r][scol] = *(const short8*)&xb[gr * 512 + k0 + scol];
      }
    }
#pragma unroll
    for (int i = 0; i < 2; i++) {
      int r = srow + i * 64;
      if (r < 96) {
        int sec = r >> 5, r32 = r & 31;
        *(short8*)&Bs[r][scol] =
            *(const short8*)&wt1[(sec * 512 + h * 32 + r32) * 512 + k0 + scol];
      }
    }
    __syncthreads();
    short8 af[4], bfv[6];
#pragma unroll
    for (int i = 0; i < 4; i++) {
      int mt = (i < 3) ? (wave + 4 * i) : (12 + (wave & 1));
      af[i] = *(short8*)&As[mt * 16 + l16][quad * 8];
    }
#pragma unroll
    for (int n = 0; n < 6; n++) bfv[n] = *(short8*)&Bs[n * 16 + l16][quad * 8];
#pragma unroll
    for (int i = 0; i < 4; i++)
#pragma unroll
      for (int n = 0; n < 6; n++)
        acc[i][n] = __builtin_amdgcn_mfma_f32_16x16x32_bf16(af[i], bfv[n],
                                                            acc[i][n], 0, 0, 0);
    __syncthreads();
  }
  const float qscale = 0.17677669529663687f;
#pragma unroll
  for (int i = 0; i < 4; i++) {
    if (i == 3 && wave >= 2) break;
    int mt = (i < 3) ? (wave + 4 * i) : (12 + wave);
    int row0 = mt * 16 + quad * 4;
#pragma unroll
    for (int n = 0; n < 6; n++) {
      int c = n * 16 + l16;
#pragma unroll
      for (int r = 0; r < 4; r++) {
        int row = row0 + r;
        float v = acc[i][n][r];
        if (c < 32)
          Qs[row][c] = f2bf(v * qscale);
        else if (c < 64)
          Ks[row][c - 32] = f2bf(v);
        else
          vTs[c - 64][row] = f2bf(v);
      }
    }
  }
  __syncthreads();
  for (int i2 = 0; i2 < 4; i2++) {
    bool active = (i2 < 3) || (wave == 0);
    int qt = (i2 < 3) ? (wave + 4 * i2) : 12;
    int qr0 = qt * 16;
    if (active) {
      short8 qf = *(short8*)&Qs[qr0 + l16][quad * 8];
      float4_t s[13];
#pragma unroll
      for (int kt = 0; kt < 13; kt++) {
        short8 kf = *(short8*)&Ks[kt * 16 + l16][quad * 8];
        s[kt] = __builtin_amdgcn_mfma_f32_16x16x32_bf16(qf, kf, z4, 0, 0, 0);
      }
      const float* brow = bias + (h * QPAD + qr0 + quad * 4) * KP;
#pragma unroll
      for (int kt = 0; kt < 13; kt++) {
        int col = kt * 16 + l16;
#pragma unroll
        for (int r = 0; r < 4; r++) s[kt][r] += brow[r * KP + col];
      }
      if (l16 >= 4) {
#pragma unroll
        for (int r = 0; r < 4; r++) s[12][r] = -1e30f;
      }
      int prow_base = wave * 16 + quad * 4;
#pragma unroll
      for (int r = 0; r < 4; r++) {
        float m = s[0][r];
#pragma unroll
        for (int kt = 1; kt < 13; kt++) m = fmaxf(m, s[kt][r]);
        m = fmaxf(m, __shfl_xor(m, 8, 16));
        m = fmaxf(m, __shfl_xor(m, 4, 16));
        m = fmaxf(m, __shfl_xor(m, 2, 16));
        m = fmaxf(m, __shfl_xor(m, 1, 16));
        float sum = 0.f;
#pragma unroll
        for (int kt = 0; kt < 13; kt++) {
          float p = __expf(s[kt][r] - m);
          s[kt][r] = p;
          sum += p;
        }
        sum += __shfl_xor(sum, 8, 16);
        sum += __shfl_xor(sum, 4, 16);
        sum += __shfl_xor(sum, 2, 16);
        sum += __shfl_xor(sum, 1, 16);
        float inv = 1.f / sum;
        short* prow = &P[prow_base + r][0];
#pragma unroll
        for (int kt = 0; kt < 13; kt++)
          prow[kt * 16 + l16] = f2bf(s[kt][r] * inv);
        prow[208 + l16] = 0;
      }
    }
    __syncthreads();
    if (active) {
      float4_t o0 = z4, o1 = z4;
#pragma unroll
      for (int kt = 0; kt < 7; kt++) {
        short8 pf = *(short8*)&P[wave * 16 + l16][kt * 32 + quad * 8];
        short8 vf0 = *(short8*)&vTs[l16][kt * 32 + quad * 8];
        short8 vf1 = *(short8*)&vTs[16 + l16][kt * 32 + quad * 8];
        o0 = __builtin_amdgcn_mfma_f32_16x16x32_bf16(pf, vf0, o0, 0, 0, 0);
        o1 = __builtin_amdgcn_mfma_f32_16x16x32_bf16(pf, vf1, o1, 0, 0, 0);
      }
#pragma unroll
      for (int r = 0; r < 4; r++) {
        int row = qr0 + quad * 4 + r;
        if (row < NTOK) {
          int off = (base_row + row) * 512 + h * 32;
          aout[off + l16] = f2bf(o0[r]);
          aout[off + 16 + l16] = f2bf(o1[r]);
        }
      }
    }
    __syncthreads();
  }
}

// ------------- proj GEMM + bias: out_f32 = aout[25088,512] @ w2^T + b --------
__global__ __launch_bounds__(256) void proj_gemm(
    const short* __restrict__ a, const short* __restrict__ wt,
    const float* __restrict__ pb, float* __restrict__ out) {
  __shared__ __align__(16) short As[128][72];
  __shared__ __align__(16) short Bs[128][72];
  float4_t acc[4][4];
  float4_t z = {0.f, 0.f, 0.f, 0.f};
#pragma unroll
  for (int i = 0; i < 4; i++)
#pragma unroll
    for (int j = 0; j < 4; j++) acc[i][j] = z;
  // XCD-chunked bijective swizzle: nwg = 4*196 = 784 = 8*98
  int lin = blockIdx.x + blockIdx.y * 4;
  int xcd = lin & 7, loc = lin >> 3;
  int nl = xcd * 98 + loc;
  int bx = nl % 4, by = nl / 4;
  int m0 = by * 128, n0 = bx * 128;
  gemm_tile_t<false>(a, wt, 512, m0, n0, As, Bs, acc);
  int lane = threadIdx.x & 63, wave = threadIdx.x >> 6;
  int quad = lane >> 4, l16 = lane & 15;
  int wm = (wave >> 1) * 64, wn = (wave & 1) * 64;
#pragma unroll
  for (int mi = 0; mi < 4; mi++)
#pragma unroll
    for (int ni = 0; ni < 4; ni++) {
      int colg = n0 + wn + ni * 16 + l16;
      float bv = pb[colg];
#pragma unroll
      for (int r = 0; r < 4; r++) {
        int rowg = m0 + wm + mi * 16 + quad * 4 + r;
        out[rowg * 512 + colg] = acc[mi][ni][r] + bv;
      }
    }
}

extern "C" void kernel_launch(void* const* d_in, const int* in_sizes, int n_in,
                              void* d_out, int out_size, void* d_ws,
                              size_t ws_size, hipStream_t stream) {
  const float* x = (const float*)d_in[0];       // [25088,512] fp32
  const float* qkv_w = (const float*)d_in[1];   // [512,1536] fp32
  const float* table = (const float*)d_in[2];   // [729,16] fp32
  const float* proj_w = (const float*)d_in[3];  // [512,512] fp32
  const float* proj_b = (const float*)d_in[4];  // [512] fp32
  const int* rpi = (const int*)d_in[5];         // [196,196] int32
  float* out = (float*)d_out;

  char* w = (char*)d_ws;
  short* wt1 = (short*)(w);              // 1536*512*2   = 1,572,864
  short* wt2 = (short*)(w + 1572864);    // 512*512*2    =   524,288
  float* bias = (float*)(w + 2097152);   // 16*208*208*4 = 2,768,896
  short* xb = (short*)(w + 4866048);     // 25088*512*2  = 25,690,112
  // split-path extra slabs (q,k,v) on top:
  short* qb = (short*)(w + 30556160);    // 2048*208*32*2 = 27,262,976
  short* kb = (short*)(w + 57819136);
  short* vb = (short*)(w + 85082112);    // V^T layout [bh][32][208], same size
  const size_t NEEDED_SPLIT = 112345088;
  const size_t NEEDED_FUSED = 30556160 + 25690112;  // fused path slabs

  int split = ws_size >= NEEDED_SPLIT;
  prep_kernel<<<3728, 256, 0, stream>>>(qkv_w, proj_w, table, rpi, wt1, wt2,
                                        bias, vb, split);
  if (split) {
    // split path: xb slab doubles as aout (x read fp32 directly by qkv_gemm)
    short* aout = xb;
    qkv_gemm<<<dim3(12, 196), 256, 0, stream>>>(x, wt1, qb, kb, vb);
    attn_kernel<<<2048, 512, 0, stream>>>(qb, kb, vb, bias, aout);
    proj_gemm<<<dim3(4, 196), 256, 0, stream>>>(aout, wt2, proj_b, out);
  } else if (ws_size >= NEEDED_FUSED) {
    short* aout = (short*)(w + 30556160);  // separate slab, round-4 layout
    cvt_kernel<<<25088 * 512 / (256 * 8), 256, 0, stream>>>(x, xb);
    fused_attn<<<2048, 256, 0, stream>>>(xb, wt1, bias, aout);
    proj_gemm<<<dim3(4, 196), 256, 0, stream>>>(aout, wt2, proj_b, out);
  } else {
    fill_kernel<<<(out_size + 255) / 256, 256, 0, stream>>>(out, out_size);
  }
}

// Round 6
// 276.033 us; speedup vs baseline: 1.0919x; 1.0919x over previous
//
#include <hip/hip_runtime.h>

#define NTOK 196
#define QPAD 208
#define KP 208
#define PSTR 232
#define VKP 208

typedef __attribute__((ext_vector_type(8))) short short8;
typedef __attribute__((ext_vector_type(4))) short short4_t;
typedef __attribute__((ext_vector_type(4))) float float4_t;

__device__ __forceinline__ short f2bf(float f) {
  unsigned u = __float_as_uint(f);
  u = (u + 0x7fffu + ((u >> 16) & 1u)) >> 16;
  return (short)u;
}

// ---------------- fallback: signal insufficient workspace ----------------
__global__ __launch_bounds__(256) void fill_kernel(float* __restrict__ out,
                                                   int n) {
  int i = blockIdx.x * 256 + threadIdx.x;
  if (i < n) out[i] = 1000.0f;
}

// ---------------- x fp32 -> bf16, 8 elems/thread ----------------
__global__ __launch_bounds__(256) void cvt_kernel(const float* __restrict__ in,
                                                  short* __restrict__ out) {
  int i = (blockIdx.x * 256 + threadIdx.x) * 8;  // total = 25088*512
  float4_t a = *(const float4_t*)&in[i];
  float4_t b = *(const float4_t*)&in[i + 4];
  short8 v;
  v[0] = f2bf(a[0]); v[1] = f2bf(a[1]); v[2] = f2bf(a[2]); v[3] = f2bf(a[3]);
  v[4] = f2bf(b[0]); v[5] = f2bf(b[1]); v[6] = f2bf(b[2]); v[7] = f2bf(b[3]);
  *(short8*)&out[i] = v;
}

// ------------- transpose body: out_bf16[C][R] = in_f32[R][C] -----------------
__device__ __forceinline__ void transpose_body(const float* __restrict__ in,
                                               short* __restrict__ out, int R,
                                               int C, int bx, int by,
                                               float (*tile)[65]) {
  int c0 = bx * 64, r0 = by * 64;
  int tc = threadIdx.x & 63, tr = threadIdx.x >> 6;
#pragma unroll
  for (int s = 0; s < 16; s++) {
    int r = s * 4 + tr;
    tile[r][tc] = in[(r0 + r) * C + c0 + tc];
  }
  __syncthreads();
#pragma unroll
  for (int s = 0; s < 16; s++) {
    int i = s * 4 + tr;
    out[(c0 + i) * R + r0 + tc] = f2bf(tile[tc][i]);
  }
}

// ---- merged preamble: transposes + bias gather + V^T pad zero (1 launch) ----
// blocks [0,192): qkv_w^T  [192,256): proj_w^T  [256,2960): bias  [2960,3728): vpad
__global__ __launch_bounds__(256) void prep_kernel(
    const float* __restrict__ qkv_w, const float* __restrict__ proj_w,
    const float* __restrict__ table, const int* __restrict__ rpi,
    short* __restrict__ wt1, short* __restrict__ wt2, float* __restrict__ bias,
    short* __restrict__ vb, int do_vpad) {
  __shared__ float tile[64][65];
  int blk = blockIdx.x;
  if (blk < 192) {
    transpose_body(qkv_w, wt1, 512, 1536, blk % 24, blk / 24, tile);
  } else if (blk < 256) {
    int i = blk - 192;
    transpose_body(proj_w, wt2, 512, 512, i % 8, i / 8, tile);
  } else if (blk < 2960) {
    int idx = (blk - 256) * 256 + threadIdx.x;  // < 16*208*208 = 692224
    int h = idx / (QPAD * KP);
    int rem = idx % (QPAD * KP);
    int q = rem / KP, k = rem % KP;
    float v = 0.f;
    if (q < NTOK && k < NTOK) v = table[rpi[q * NTOK + k] * 16 + h];
    bias[idx] = v;
  } else if (do_vpad) {
    int i = (blk - 2960) * 256 + threadIdx.x;  // < 2048*32*3 = 196608
    int row = i / 3, g = i - 3 * (i / 3);
    short4_t z = {0, 0, 0, 0};
    *(short4_t*)&vb[row * VKP + 196 + g * 4] = z;
  }
}

// ---------------- shared 128x128 GEMM mainloop (validated, padded LDS) -------
__device__ __forceinline__ void gemm_tile(const short* __restrict__ A,
                                          const short* __restrict__ B, int K,
                                          int m0, int n0, short (*As)[72],
                                          short (*Bs)[72], float4_t acc[4][4]) {
  int tid = threadIdx.x;
  int lane = tid & 63, wave = tid >> 6;
  int quad = lane >> 4, l16 = lane & 15;
  int wm = (wave >> 1) * 64, wn = (wave & 1) * 64;
  int srow = tid >> 3, scol = (tid & 7) * 8;
  for (int k0 = 0; k0 < K; k0 += 64) {
#pragma unroll
    for (int i = 0; i < 4; i++) {
      int r = srow + i * 32;
      *(short8*)&As[r][scol] = *(const short8*)&A[(m0 + r) * K + k0 + scol];
      *(short8*)&Bs[r][scol] = *(const short8*)&B[(n0 + r) * K + k0 + scol];
    }
    __syncthreads();
#pragma unroll
    for (int ks = 0; ks < 2; ks++) {
      short8 af[4], bfr[4];
#pragma unroll
      for (int i = 0; i < 4; i++) {
        af[i] = *(short8*)&As[wm + i * 16 + l16][ks * 32 + quad * 8];
        bfr[i] = *(short8*)&Bs[wn + i * 16 + l16][ks * 32 + quad * 8];
      }
#pragma unroll
      for (int mi = 0; mi < 4; mi++)
#pragma unroll
        for (int ni = 0; ni < 4; ni++)
          acc[mi][ni] = __builtin_amdgcn_mfma_f32_16x16x32_bf16(
              af[mi], bfr[ni], acc[mi][ni], 0, 0, 0);
    }
    __syncthreads();
  }
}

// -------- split path: QKV GEMM with scatter epilogue into q/k/v slabs --------
// V is written TRANSPOSED: vb[bh][d][VKP] so attn stages it with a coalesced
// row copy. rowg0 is a multiple of 4 and 196 % 4 == 0, so a 4-row group never
// straddles a batch boundary -> one short4 store.
__global__ __launch_bounds__(256) void qkv_gemm(
    const short* __restrict__ xb, const short* __restrict__ wt1,
    short* __restrict__ qb, short* __restrict__ kb, short* __restrict__ vb) {
  __shared__ __align__(16) short As[128][72];
  __shared__ __align__(16) short Bs[128][72];
  float4_t acc[4][4];
  float4_t z = {0.f, 0.f, 0.f, 0.f};
#pragma unroll
  for (int i = 0; i < 4; i++)
#pragma unroll
    for (int j = 0; j < 4; j++) acc[i][j] = z;
  // XCD-chunked bijective swizzle: nwg = 12*196 = 2352 = 8*294
  int lin = blockIdx.x + blockIdx.y * 12;
  int xcd = lin & 7, loc = lin >> 3;
  int nl = xcd * 294 + loc;
  int bx = nl % 12, by = nl / 12;
  int m0 = by * 128, n0 = bx * 128;
  gemm_tile(xb, wt1, 512, m0, n0, As, Bs, acc);
  int lane = threadIdx.x & 63, wave = threadIdx.x >> 6;
  int quad = lane >> 4, l16 = lane & 15;
  int wm = (wave >> 1) * 64, wn = (wave & 1) * 64;
  const float qscale = 0.17677669529663687f;  // 32^-0.5
#pragma unroll
  for (int mi = 0; mi < 4; mi++)
#pragma unroll
    for (int ni = 0; ni < 4; ni++) {
      int colg = n0 + wn + ni * 16 + l16;
      int s = colg >> 9, rem = colg & 511;
      int h = rem >> 5, d = rem & 31;
      int rowg0 = m0 + wm + mi * 16 + quad * 4;
      if (s == 2) {
        int b = rowg0 / NTOK, nt = rowg0 - b * NTOK;  // nt % 4 == 0, <= 192
        short4_t v4;
        v4[0] = f2bf(acc[mi][ni][0]);
        v4[1] = f2bf(acc[mi][ni][1]);
        v4[2] = f2bf(acc[mi][ni][2]);
        v4[3] = f2bf(acc[mi][ni][3]);
        *(short4_t*)&vb[((b * 16 + h) * 32 + d) * VKP + nt] = v4;
      } else {
#pragma unroll
        for (int r = 0; r < 4; r++) {
          int rowg = rowg0 + r;
          int b = rowg / NTOK, n = rowg - b * NTOK;
          int off = ((b * 16 + h) * QPAD + n) * 32 + d;
          if (s == 0)
            qb[off] = f2bf(acc[mi][ni][r] * qscale);
          else
            kb[off] = f2bf(acc[mi][ni][r]);
        }
      }
    }
}

// -------- split path: attention, one block per (b,h), 8 waves --------
// 8 waves x 2 q-tile rounds: LDS 74.2 KB -> 2 blocks/CU = 16 waves/CU.
// P is WAVE-PRIVATE -> only the staging barrier. 1/sum normalization
// deferred from P (13 muls/row) to fp32 epilogue (2 muls/row).
__global__ __launch_bounds__(512) void attn_kernel(
    const short* __restrict__ qb, const short* __restrict__ kb,
    const short* __restrict__ vb, const float* __restrict__ bias,
    short* __restrict__ aout) {
  __shared__ __align__(16) short vT[32][PSTR];
  __shared__ __align__(16) short P[8][16][PSTR];
  int bh = blockIdx.x, b = bh >> 4, h = bh & 15;
  int tid = threadIdx.x, wave = tid >> 6, lane = tid & 63;
  int quad = lane >> 4, l16 = lane & 15;
  int base_row = b * NTOK;
  // stage V^T rows: 32 rows x 208 shorts, coalesced 16B chunks
  const short* vsrc = vb + bh * 32 * VKP;
  for (int i = tid; i < 32 * 26; i += 512) {
    int d = i / 26, c = (i - d * 26) * 8;
    *(short8*)&vT[d][c] = *(const short8*)&vsrc[d * VKP + c];
  }
  short8 z8 = {0, 0, 0, 0, 0, 0, 0, 0};
  if (tid < 32 * 3) {
    int d = tid / 3, c = 208 + (tid - d * 3) * 8;
    *(short8*)&vT[d][c] = z8;
  }
  __syncthreads();
  float4_t z4 = {0.f, 0.f, 0.f, 0.f};
  for (int i2 = 0; i2 < 2; i2++) {
    int qt = wave + 8 * i2;
    if (qt > 12) break;  // waves 5-7 exit after round 0; no barriers below
    int qr0 = qt * 16;
    short8 qf = *(const short8*)&qb[(bh * QPAD + qr0 + l16) * 32 + quad * 8];
    float4_t s[13];
#pragma unroll
    for (int kt = 0; kt < 13; kt++) {
      short8 kf =
          *(const short8*)&kb[(bh * QPAD + kt * 16 + l16) * 32 + quad * 8];
      s[kt] = __builtin_amdgcn_mfma_f32_16x16x32_bf16(qf, kf, z4, 0, 0, 0);
    }
    const float* brow = bias + (h * QPAD + qr0 + quad * 4) * KP;
#pragma unroll
    for (int kt = 0; kt < 13; kt++) {
      int col = kt * 16 + l16;
#pragma unroll
      for (int r = 0; r < 4; r++) s[kt][r] += brow[r * KP + col];
    }
    if (l16 >= 4) {
#pragma unroll
      for (int r = 0; r < 4; r++) s[12][r] = -1e30f;  // mask pad keys
    }
    float invr[4];
#pragma unroll
    for (int r = 0; r < 4; r++) {
      float m = s[0][r];
#pragma unroll
      for (int kt = 1; kt < 13; kt++) m = fmaxf(m, s[kt][r]);
      m = fmaxf(m, __shfl_xor(m, 8, 16));
      m = fmaxf(m, __shfl_xor(m, 4, 16));
      m = fmaxf(m, __shfl_xor(m, 2, 16));
      m = fmaxf(m, __shfl_xor(m, 1, 16));
      float sum = 0.f;
#pragma unroll
      for (int kt = 0; kt < 13; kt++) {
        float p = __expf(s[kt][r] - m);
        s[kt][r] = p;
        sum += p;
      }
      sum += __shfl_xor(sum, 8, 16);
      sum += __shfl_xor(sum, 4, 16);
      sum += __shfl_xor(sum, 2, 16);
      sum += __shfl_xor(sum, 1, 16);
      invr[r] = 1.f / sum;
      short* prow = &P[wave][quad * 4 + r][0];
#pragma unroll
      for (int kt = 0; kt < 13; kt++)
        prow[kt * 16 + l16] = f2bf(s[kt][r]);  // unnormalized, <= 1
      prow[208 + l16] = 0;  // zero pad cols 208..223 (224.. never read)
    }
    // in-wave LDS ordering guarantees P writes visible to same-wave reads
    float4_t o0 = z4, o1 = z4;
#pragma unroll
    for (int kt = 0; kt < 7; kt++) {
      short8 pf = *(short8*)&P[wave][l16][kt * 32 + quad * 8];
      short8 vf0 = *(short8*)&vT[l16][kt * 32 + quad * 8];
      short8 vf1 = *(short8*)&vT[16 + l16][kt * 32 + quad * 8];
      o0 = __builtin_amdgcn_mfma_f32_16x16x32_bf16(pf, vf0, o0, 0, 0, 0);
      o1 = __builtin_amdgcn_mfma_f32_16x16x32_bf16(pf, vf1, o1, 0, 0, 0);
    }
#pragma unroll
    for (int r = 0; r < 4; r++) {
      int row = qr0 + quad * 4 + r;
      if (row < NTOK) {
        int off = (base_row + row) * 512 + h * 32;
        aout[off + l16] = f2bf(o0[r] * invr[r]);
        aout[off + 16 + l16] = f2bf(o1[r] * invr[r]);
      }
    }
  }
}

// ---------------- fallback fused QKV-GEMM + attention (round-4, validated) ---
__global__ __launch_bounds__(256, 2) void fused_attn(
    const short* __restrict__ xb, const short* __restrict__ wt1,
    const float* __restrict__ bias, short* __restrict__ aout) {
  __shared__ __align__(16) short R1[64 * PSTR];
  __shared__ __align__(16) short R2[32 * PSTR];
  __shared__ __align__(16) short Qs[224][40];
  __shared__ __align__(16) short Ks[224][40];
  short(*As)[40] = (short(*)[40])R1;
  short(*P)[PSTR] = (short(*)[PSTR])R1;
  short(*Bs)[40] = (short(*)[40])R2;
  short(*vTs)[PSTR] = (short(*)[PSTR])R2;

  int bh = blockIdx.x, b = bh >> 4, h = bh & 15;
  int tid = threadIdx.x, wave = tid >> 6, lane = tid & 63;
  int quad = lane >> 4, l16 = lane & 15;
  int base_row = b * NTOK;

  float4_t z4 = {0.f, 0.f, 0.f, 0.f};
  float4_t acc[4][6];
#pragma unroll
  for (int i = 0; i < 4; i++)
#pragma unroll
    for (int n = 0; n < 6; n++) acc[i][n] = z4;

  int srow = tid >> 2, scol = (tid & 3) * 8;
  for (int k0 = 0; k0 < 512; k0 += 32) {
#pragma unroll
    for (int i = 0; i < 4; i++) {
      int r = srow + i * 64;
      if (r < 224) {
        int gr = base_row + r;
        if (gr > 25087) gr = 25087;
        *(short8*)&As[r][scol] = *(const short8*)&xb[gr * 512 + k0 + scol];
      }
    }
#pragma unroll
    for (int i = 0; i < 2; i++) {
      int r = srow + i * 64;
      if (r < 96) {
        int sec = r >> 5, r32 = r & 31;
        *(short8*)&Bs[r][scol] =
            *(const short8*)&wt1[(sec * 512 + h * 32 + r32) * 512 + k0 + scol];
      }
    }
    __syncthreads();
    short8 af[4], bfv[6];
#pragma unroll
    for (int i = 0; i < 4; i++) {
      int mt = (i < 3) ? (wave + 4 * i) : (12 + (wave & 1));
      af[i] = *(short8*)&As[mt * 16 + l16][quad * 8];
    }
#pragma unroll
    for (int n = 0; n < 6; n++) bfv[n] = *(short8*)&Bs[n * 16 + l16][quad * 8];
#pragma unroll
    for (int i = 0; i < 4; i++)
#pragma unroll
      for (int n = 0; n < 6; n++)
        acc[i][n] = __builtin_amdgcn_mfma_f32_16x16x32_bf16(af[i], bfv[n],
                                                            acc[i][n], 0, 0, 0);
    __syncthreads();
  }
  const float qscale = 0.17677669529663687f;
#pragma unroll
  for (int i = 0; i < 4; i++) {
    if (i == 3 && wave >= 2) break;
    int mt = (i < 3) ? (wave + 4 * i) : (12 + wave);
    int row0 = mt * 16 + quad * 4;
#pragma unroll
    for (int n = 0; n < 6; n++) {
      int c = n * 16 + l16;
#pragma unroll
      for (int r = 0; r < 4; r++) {
        int row = row0 + r;
        float v = acc[i][n][r];
        if (c < 32)
          Qs[row][c] = f2bf(v * qscale);
        else if (c < 64)
          Ks[row][c - 32] = f2bf(v);
        else
          vTs[c - 64][row] = f2bf(v);
      }
    }
  }
  __syncthreads();
  for (int i2 = 0; i2 < 4; i2++) {
    bool active = (i2 < 3) || (wave == 0);
    int qt = (i2 < 3) ? (wave + 4 * i2) : 12;
    int qr0 = qt * 16;
    if (active) {
      short8 qf = *(short8*)&Qs[qr0 + l16][quad * 8];
      float4_t s[13];
#pragma unroll
      for (int kt = 0; kt < 13; kt++) {
        short8 kf = *(short8*)&Ks[kt * 16 + l16][quad * 8];
        s[kt] = __builtin_amdgcn_mfma_f32_16x16x32_bf16(qf, kf, z4, 0, 0, 0);
      }
      const float* brow = bias + (h * QPAD + qr0 + quad * 4) * KP;
#pragma unroll
      for (int kt = 0; kt < 13; kt++) {
        int col = kt * 16 + l16;
#pragma unroll
        for (int r = 0; r < 4; r++) s[kt][r] += brow[r * KP + col];
      }
      if (l16 >= 4) {
#pragma unroll
        for (int r = 0; r < 4; r++) s[12][r] = -1e30f;
      }
      int prow_base = wave * 16 + quad * 4;
#pragma unroll
      for (int r = 0; r < 4; r++) {
        float m = s[0][r];
#pragma unroll
        for (int kt = 1; kt < 13; kt++) m = fmaxf(m, s[kt][r]);
        m = fmaxf(m, __shfl_xor(m, 8, 16));
        m = fmaxf(m, __shfl_xor(m, 4, 16));
        m = fmaxf(m, __shfl_xor(m, 2, 16));
        m = fmaxf(m, __shfl_xor(m, 1, 16));
        float sum = 0.f;
#pragma unroll
        for (int kt = 0; kt < 13; kt++) {
          float p = __expf(s[kt][r] - m);
          s[kt][r] = p;
          sum += p;
        }
        sum += __shfl_xor(sum, 8, 16);
        sum += __shfl_xor(sum, 4, 16);
        sum += __shfl_xor(sum, 2, 16);
        sum += __shfl_xor(sum, 1, 16);
        float inv = 1.f / sum;
        short* prow = &P[prow_base + r][0];
#pragma unroll
        for (int kt = 0; kt < 13; kt++)
          prow[kt * 16 + l16] = f2bf(s[kt][r] * inv);
        prow[208 + l16] = 0;
      }
    }
    __syncthreads();
    if (active) {
      float4_t o0 = z4, o1 = z4;
#pragma unroll
      for (int kt = 0; kt < 7; kt++) {
        short8 pf = *(short8*)&P[wave * 16 + l16][kt * 32 + quad * 8];
        short8 vf0 = *(short8*)&vTs[l16][kt * 32 + quad * 8];
        short8 vf1 = *(short8*)&vTs[16 + l16][kt * 32 + quad * 8];
        o0 = __builtin_amdgcn_mfma_f32_16x16x32_bf16(pf, vf0, o0, 0, 0, 0);
        o1 = __builtin_amdgcn_mfma_f32_16x16x32_bf16(pf, vf1, o1, 0, 0, 0);
      }
#pragma unroll
      for (int r = 0; r < 4; r++) {
        int row = qr0 + quad * 4 + r;
        if (row < NTOK) {
          int off = (base_row + row) * 512 + h * 32;
          aout[off + l16] = f2bf(o0[r]);
          aout[off + 16 + l16] = f2bf(o1[r]);
        }
      }
    }
    __syncthreads();
  }
}

// ------------- proj GEMM + bias: out_f32 = aout[25088,512] @ w2^T + b --------
__global__ __launch_bounds__(256) void proj_gemm(
    const short* __restrict__ a, const short* __restrict__ wt,
    const float* __restrict__ pb, float* __restrict__ out) {
  __shared__ __align__(16) short As[128][72];
  __shared__ __align__(16) short Bs[128][72];
  float4_t acc[4][4];
  float4_t z = {0.f, 0.f, 0.f, 0.f};
#pragma unroll
  for (int i = 0; i < 4; i++)
#pragma unroll
    for (int j = 0; j < 4; j++) acc[i][j] = z;
  // XCD-chunked bijective swizzle: nwg = 4*196 = 784 = 8*98
  int lin = blockIdx.x + blockIdx.y * 4;
  int xcd = lin & 7, loc = lin >> 3;
  int nl = xcd * 98 + loc;
  int bx = nl % 4, by = nl / 4;
  int m0 = by * 128, n0 = bx * 128;
  gemm_tile(a, wt, 512, m0, n0, As, Bs, acc);
  int lane = threadIdx.x & 63, wave = threadIdx.x >> 6;
  int quad = lane >> 4, l16 = lane & 15;
  int wm = (wave >> 1) * 64, wn = (wave & 1) * 64;
#pragma unroll
  for (int mi = 0; mi < 4; mi++)
#pragma unroll
    for (int ni = 0; ni < 4; ni++) {
      int colg = n0 + wn + ni * 16 + l16;
      float bv = pb[colg];
#pragma unroll
      for (int r = 0; r < 4; r++) {
        int rowg = m0 + wm + mi * 16 + quad * 4 + r;
        out[rowg * 512 + colg] = acc[mi][ni][r] + bv;
      }
    }
}

extern "C" void kernel_launch(void* const* d_in, const int* in_sizes, int n_in,
                              void* d_out, int out_size, void* d_ws,
                              size_t ws_size, hipStream_t stream) {
  const float* x = (const float*)d_in[0];       // [25088,512] fp32
  const float* qkv_w = (const float*)d_in[1];   // [512,1536] fp32
  const float* table = (const float*)d_in[2];   // [729,16] fp32
  const float* proj_w = (const float*)d_in[3];  // [512,512] fp32
  const float* proj_b = (const float*)d_in[4];  // [512] fp32
  const int* rpi = (const int*)d_in[5];         // [196,196] int32
  float* out = (float*)d_out;

  char* w = (char*)d_ws;
  short* wt1 = (short*)(w);              // 1536*512*2   = 1,572,864
  short* wt2 = (short*)(w + 1572864);    // 512*512*2    =   524,288
  float* bias = (float*)(w + 2097152);   // 16*208*208*4 = 2,768,896
  short* xb = (short*)(w + 4866048);     // 25088*512*2  = 25,690,112
  // split-path extra slabs (q,k,v) on top:
  short* qb = (short*)(w + 30556160);    // 2048*208*32*2 = 27,262,976
  short* kb = (short*)(w + 57819136);
  short* vb = (short*)(w + 85082112);    // V^T layout [bh][32][208], same size
  const size_t NEEDED_SPLIT = 112345088;
  const size_t NEEDED_FUSED = 30556160 + 25690112;  // fused path slabs

  int split = ws_size >= NEEDED_SPLIT;
  prep_kernel<<<3728, 256, 0, stream>>>(qkv_w, proj_w, table, rpi, wt1, wt2,
                                        bias, vb, split);
  if (split) {
    // split path: xb slab doubles as aout (xb dead after qkv_gemm)
    short* aout = xb;
    cvt_kernel<<<25088 * 512 / (256 * 8), 256, 0, stream>>>(x, xb);
    qkv_gemm<<<dim3(12, 196), 256, 0, stream>>>(xb, wt1, qb, kb, vb);
    attn_kernel<<<2048, 512, 0, stream>>>(qb, kb, vb, bias, aout);
    proj_gemm<<<dim3(4, 196), 256, 0, stream>>>(aout, wt2, proj_b, out);
  } else if (ws_size >= NEEDED_FUSED) {
    short* aout = (short*)(w + 30556160);  // separate slab, round-4 layout
    cvt_kernel<<<25088 * 512 / (256 * 8), 256, 0, stream>>>(x, xb);
    fused_attn<<<2048, 256, 0, stream>>>(xb, wt1, bias, aout);
    proj_gemm<<<dim3(4, 196), 256, 0, stream>>>(aout, wt2, proj_b, out);
  } else {
    fill_kernel<<<(out_size + 255) / 256, 256, 0, stream>>>(out, out_size);
  }
}

// Round 7
// 274.933 us; speedup vs baseline: 1.0962x; 1.0040x over previous
//
#include <hip/hip_runtime.h>

#define NTOK 196
#define QPAD 208
#define KP 208
#define PSTR 232
#define VKP 208

typedef __attribute__((ext_vector_type(8))) short short8;
typedef __attribute__((ext_vector_type(4))) short short4_t;
typedef __attribute__((ext_vector_type(4))) float float4_t;

__device__ __forceinline__ short f2bf(float f) {
  unsigned u = __float_as_uint(f);
  u = (u + 0x7fffu + ((u >> 16) & 1u)) >> 16;
  return (short)u;
}

// ---------------- fallback: signal insufficient workspace ----------------
__global__ __launch_bounds__(256) void fill_kernel(float* __restrict__ out,
                                                   int n) {
  int i = blockIdx.x * 256 + threadIdx.x;
  if (i < n) out[i] = 1000.0f;
}

// ------------- transpose body: out_bf16[C][R] = in_f32[R][C] -----------------
__device__ __forceinline__ void transpose_body(const float* __restrict__ in,
                                               short* __restrict__ out, int R,
                                               int C, int bx, int by,
                                               float (*tile)[65]) {
  int c0 = bx * 64, r0 = by * 64;
  int tc = threadIdx.x & 63, tr = threadIdx.x >> 6;
#pragma unroll
  for (int s = 0; s < 16; s++) {
    int r = s * 4 + tr;
    tile[r][tc] = in[(r0 + r) * C + c0 + tc];
  }
  __syncthreads();
#pragma unroll
  for (int s = 0; s < 16; s++) {
    int i = s * 4 + tr;
    out[(c0 + i) * R + r0 + tc] = f2bf(tile[tc][i]);
  }
}

// ---- merged preamble: transposes + bias + V^T pad + x cvt (1 launch) ----
// blocks [0,192): qkv_w^T  [192,256): proj_w^T  [256,2960): bias
// [2960,3728): vpad  [3728,10000): x fp32->bf16
__global__ __launch_bounds__(256) void prep_kernel(
    const float* __restrict__ qkv_w, const float* __restrict__ proj_w,
    const float* __restrict__ table, const int* __restrict__ rpi,
    const float* __restrict__ x, short* __restrict__ wt1,
    short* __restrict__ wt2, float* __restrict__ bias, short* __restrict__ vb,
    short* __restrict__ xb, int do_vpad) {
  __shared__ float tile[64][65];
  int blk = blockIdx.x;
  if (blk < 192) {
    transpose_body(qkv_w, wt1, 512, 1536, blk % 24, blk / 24, tile);
  } else if (blk < 256) {
    int i = blk - 192;
    transpose_body(proj_w, wt2, 512, 512, i % 8, i / 8, tile);
  } else if (blk < 2960) {
    int idx = (blk - 256) * 256 + threadIdx.x;  // < 16*208*208 = 692224
    int h = idx / (QPAD * KP);
    int rem = idx % (QPAD * KP);
    int q = rem / KP, k = rem % KP;
    float v = 0.f;
    if (q < NTOK && k < NTOK) v = table[rpi[q * NTOK + k] * 16 + h];
    bias[idx] = v;
  } else if (blk < 3728) {
    if (do_vpad) {
      int i = (blk - 2960) * 256 + threadIdx.x;  // < 2048*32*3 = 196608
      int row = i / 3, g = i - 3 * (i / 3);
      short4_t z = {0, 0, 0, 0};
      *(short4_t*)&vb[row * VKP + 196 + g * 4] = z;
    }
  } else {
    int i = ((blk - 3728) * 256 + threadIdx.x) * 8;  // < 25088*512
    float4_t a = *(const float4_t*)&x[i];
    float4_t b = *(const float4_t*)&x[i + 4];
    short8 v;
    v[0] = f2bf(a[0]); v[1] = f2bf(a[1]); v[2] = f2bf(a[2]); v[3] = f2bf(a[3]);
    v[4] = f2bf(b[0]); v[5] = f2bf(b[1]); v[6] = f2bf(b[2]); v[7] = f2bf(b[3]);
    *(short8*)&xb[i] = v;
  }
}

// ------- 128x128 GEMM mainloop: global_load_lds + LINEAR LDS [128][64] -------
// (round-1 body, correctness-validated; now running under the XCD swizzle so
// staged loads hit L2 not HBM). Lane l of chunk rc covers row rc*8+(l>>3),
// cols (l&7)*8 -> LDS offset r*64 + l*8 shorts = base + l*16 B.  [m97/m104]
__device__ __forceinline__ void gemm_tile(const short* __restrict__ A,
                                          const short* __restrict__ B, int K,
                                          int m0, int n0, short* As, short* Bs,
                                          float4_t acc[4][4]) {
  int tid = threadIdx.x;
  int lane = tid & 63, wave = tid >> 6;
  int quad = lane >> 4, l16 = lane & 15;
  int wm = (wave >> 1) * 64, wn = (wave & 1) * 64;
  int lrow = lane >> 3, lcol = (lane & 7) * 8;  // within an 8-row chunk
  const short* Abase = A + m0 * K;
  const short* Bbase = B + n0 * K;
  for (int k0 = 0; k0 < K; k0 += 64) {
#pragma unroll
    for (int i = 0; i < 4; i++) {
      int r = (wave * 4 + i) * 8;  // chunk base row
      __builtin_amdgcn_global_load_lds(
          (const __attribute__((address_space(1))) void*)
              &Abase[(r + lrow) * K + k0 + lcol],
          (__attribute__((address_space(3))) void*)&As[r * 64], 16, 0, 0);
      __builtin_amdgcn_global_load_lds(
          (const __attribute__((address_space(1))) void*)
              &Bbase[(r + lrow) * K + k0 + lcol],
          (__attribute__((address_space(3))) void*)&Bs[r * 64], 16, 0, 0);
    }
    __syncthreads();  // vmcnt(0) drain emitted by compiler before s_barrier
#pragma unroll
    for (int ks = 0; ks < 2; ks++) {
      short8 af[4], bfr[4];
#pragma unroll
      for (int i = 0; i < 4; i++) {
        af[i] = *(short8*)&As[(wm + i * 16 + l16) * 64 + ks * 32 + quad * 8];
        bfr[i] = *(short8*)&Bs[(wn + i * 16 + l16) * 64 + ks * 32 + quad * 8];
      }
#pragma unroll
      for (int mi = 0; mi < 4; mi++)
#pragma unroll
        for (int ni = 0; ni < 4; ni++)
          acc[mi][ni] = __builtin_amdgcn_mfma_f32_16x16x32_bf16(
              af[mi], bfr[ni], acc[mi][ni], 0, 0, 0);
    }
    __syncthreads();
  }
}

// -------- split path: QKV GEMM with scatter epilogue into q/k/v slabs --------
// V is written TRANSPOSED: vb[bh][d][VKP] so attn stages it with a coalesced
// row copy. rowg0 is a multiple of 4 and 196 % 4 == 0, so a 4-row group never
// straddles a batch boundary -> one short4 store.
__global__ __launch_bounds__(256) void qkv_gemm(
    const short* __restrict__ xb, const short* __restrict__ wt1,
    short* __restrict__ qb, short* __restrict__ kb, short* __restrict__ vb) {
  __shared__ __align__(16) short As[128 * 64];
  __shared__ __align__(16) short Bs[128 * 64];
  float4_t acc[4][4];
  float4_t z = {0.f, 0.f, 0.f, 0.f};
#pragma unroll
  for (int i = 0; i < 4; i++)
#pragma unroll
    for (int j = 0; j < 4; j++) acc[i][j] = z;
  // XCD-chunked bijective swizzle: nwg = 12*196 = 2352 = 8*294
  int lin = blockIdx.x + blockIdx.y * 12;
  int xcd = lin & 7, loc = lin >> 3;
  int nl = xcd * 294 + loc;
  int bx = nl % 12, by = nl / 12;
  int m0 = by * 128, n0 = bx * 128;
  gemm_tile(xb, wt1, 512, m0, n0, As, Bs, acc);
  int lane = threadIdx.x & 63, wave = threadIdx.x >> 6;
  int quad = lane >> 4, l16 = lane & 15;
  int wm = (wave >> 1) * 64, wn = (wave & 1) * 64;
  const float qscale = 0.17677669529663687f;  // 32^-0.5
#pragma unroll
  for (int mi = 0; mi < 4; mi++)
#pragma unroll
    for (int ni = 0; ni < 4; ni++) {
      int colg = n0 + wn + ni * 16 + l16;
      int s = colg >> 9, rem = colg & 511;
      int h = rem >> 5, d = rem & 31;
      int rowg0 = m0 + wm + mi * 16 + quad * 4;
      if (s == 2) {
        int b = rowg0 / NTOK, nt = rowg0 - b * NTOK;  // nt % 4 == 0, <= 192
        short4_t v4;
        v4[0] = f2bf(acc[mi][ni][0]);
        v4[1] = f2bf(acc[mi][ni][1]);
        v4[2] = f2bf(acc[mi][ni][2]);
        v4[3] = f2bf(acc[mi][ni][3]);
        *(short4_t*)&vb[((b * 16 + h) * 32 + d) * VKP + nt] = v4;
      } else {
#pragma unroll
        for (int r = 0; r < 4; r++) {
          int rowg = rowg0 + r;
          int b = rowg / NTOK, n = rowg - b * NTOK;
          int off = ((b * 16 + h) * QPAD + n) * 32 + d;
          if (s == 0)
            qb[off] = f2bf(acc[mi][ni][r] * qscale);
          else
            kb[off] = f2bf(acc[mi][ni][r]);
        }
      }
    }
}

// -------- split path: attention, one block per (b,h), 4 waves --------
// 4 waves x 4 q-tile rounds (empirically beats 8x2: not occupancy-limited).
// vT staged via coalesced row copy from V^T layout. P is WAVE-PRIVATE ->
// only the staging barrier. 1/sum normalization deferred to fp32 epilogue.
__global__ __launch_bounds__(256) void attn_kernel(
    const short* __restrict__ qb, const short* __restrict__ kb,
    const short* __restrict__ vb, const float* __restrict__ bias,
    short* __restrict__ aout) {
  __shared__ __align__(16) short vT[32][PSTR];
  __shared__ __align__(16) short P[4][16][PSTR];
  int bh = blockIdx.x, b = bh >> 4, h = bh & 15;
  int tid = threadIdx.x, wave = tid >> 6, lane = tid & 63;
  int quad = lane >> 4, l16 = lane & 15;
  int base_row = b * NTOK;
  // stage V^T rows: 32 rows x 208 shorts, coalesced 16B chunks
  const short* vsrc = vb + bh * 32 * VKP;
  for (int i = tid; i < 32 * 26; i += 256) {
    int d = i / 26, c = (i - d * 26) * 8;
    *(short8*)&vT[d][c] = *(const short8*)&vsrc[d * VKP + c];
  }
  short8 z8 = {0, 0, 0, 0, 0, 0, 0, 0};
  if (tid < 96) {
    int d = tid / 3, c = 208 + (tid - d * 3) * 8;
    *(short8*)&vT[d][c] = z8;
  }
  __syncthreads();
  float4_t z4 = {0.f, 0.f, 0.f, 0.f};
  for (int i2 = 0; i2 < 4; i2++) {
    bool active = (i2 < 3) || (wave == 0);
    if (!active) break;  // no barriers below: inactive waves simply exit
    int qt = (i2 < 3) ? (wave + 4 * i2) : 12;
    int qr0 = qt * 16;
    short8 qf = *(const short8*)&qb[(bh * QPAD + qr0 + l16) * 32 + quad * 8];
    float4_t s[13];
#pragma unroll
    for (int kt = 0; kt < 13; kt++) {
      short8 kf =
          *(const short8*)&kb[(bh * QPAD + kt * 16 + l16) * 32 + quad * 8];
      s[kt] = __builtin_amdgcn_mfma_f32_16x16x32_bf16(qf, kf, z4, 0, 0, 0);
    }
    const float* brow = bias + (h * QPAD + qr0 + quad * 4) * KP;
#pragma unroll
    for (int kt = 0; kt < 13; kt++) {
      int col = kt * 16 + l16;
#pragma unroll
      for (int r = 0; r < 4; r++) s[kt][r] += brow[r * KP + col];
    }
    if (l16 >= 4) {
#pragma unroll
      for (int r = 0; r < 4; r++) s[12][r] = -1e30f;  // mask pad keys
    }
    float invr[4];
#pragma unroll
    for (int r = 0; r < 4; r++) {
      float m = s[0][r];
#pragma unroll
      for (int kt = 1; kt < 13; kt++) m = fmaxf(m, s[kt][r]);
      m = fmaxf(m, __shfl_xor(m, 8, 16));
      m = fmaxf(m, __shfl_xor(m, 4, 16));
      m = fmaxf(m, __shfl_xor(m, 2, 16));
      m = fmaxf(m, __shfl_xor(m, 1, 16));
      float sum = 0.f;
#pragma unroll
      for (int kt = 0; kt < 13; kt++) {
        float p = __expf(s[kt][r] - m);
        s[kt][r] = p;
        sum += p;
      }
      sum += __shfl_xor(sum, 8, 16);
      sum += __shfl_xor(sum, 4, 16);
      sum += __shfl_xor(sum, 2, 16);
      sum += __shfl_xor(sum, 1, 16);
      invr[r] = 1.f / sum;
      short* prow = &P[wave][quad * 4 + r][0];
#pragma unroll
      for (int kt = 0; kt < 13; kt++)
        prow[kt * 16 + l16] = f2bf(s[kt][r]);  // unnormalized, <= 1
      prow[208 + l16] = 0;  // zero pad cols 208..223 (224.. never read)
    }
    // in-wave LDS ordering guarantees P writes visible to same-wave reads
    float4_t o0 = z4, o1 = z4;
#pragma unroll
    for (int kt = 0; kt < 7; kt++) {
      short8 pf = *(short8*)&P[wave][l16][kt * 32 + quad * 8];
      short8 vf0 = *(short8*)&vT[l16][kt * 32 + quad * 8];
      short8 vf1 = *(short8*)&vT[16 + l16][kt * 32 + quad * 8];
      o0 = __builtin_amdgcn_mfma_f32_16x16x32_bf16(pf, vf0, o0, 0, 0, 0);
      o1 = __builtin_amdgcn_mfma_f32_16x16x32_bf16(pf, vf1, o1, 0, 0, 0);
    }
#pragma unroll
    for (int r = 0; r < 4; r++) {
      int row = qr0 + quad * 4 + r;
      if (row < NTOK) {
        int off = (base_row + row) * 512 + h * 32;
        aout[off + l16] = f2bf(o0[r] * invr[r]);
        aout[off + 16 + l16] = f2bf(o1[r] * invr[r]);
      }
    }
  }
}

// ---------------- fallback fused QKV-GEMM + attention (round-4, validated) ---
__global__ __launch_bounds__(256, 2) void fused_attn(
    const short* __restrict__ xb, const short* __restrict__ wt1,
    const float* __restrict__ bias, short* __restrict__ aout) {
  __shared__ __align__(16) short R1[64 * PSTR];
  __shared__ __align__(16) short R2[32 * PSTR];
  __shared__ __align__(16) short Qs[224][40];
  __shared__ __align__(16) short Ks[224][40];
  short(*As)[40] = (short(*)[40])R1;
  short(*P)[PSTR] = (short(*)[PSTR])R1;
  short(*Bs)[40] = (short(*)[40])R2;
  short(*vTs)[PSTR] = (short(*)[PSTR])R2;

  int bh = blockIdx.x, b = bh >> 4, h = bh & 15;
  int tid = threadIdx.x, wave = tid >> 6, lane = tid & 63;
  int quad = lane >> 4, l16 = lane & 15;
  int base_row = b * NTOK;

  float4_t z4 = {0.f, 0.f, 0.f, 0.f};
  float4_t acc[4][6];
#pragma unroll
  for (int i = 0; i < 4; i++)
#pragma unroll
    for (int n = 0; n < 6; n++) acc[i][n] = z4;

  int srow = tid >> 2, scol = (tid & 3) * 8;
  for (int k0 = 0; k0 < 512; k0 += 32) {
#pragma unroll
    for (int i = 0; i < 4; i++) {
      int r = srow + i * 64;
      if (r < 224) {
        int gr = base_row + r;
        if (gr > 25087) gr = 25087;
        *(short8*)&As[r][scol] = *(const short8*)&xb[gr * 512 + k0 + scol];
      }
    }
#pragma unroll
    for (int i = 0; i < 2; i++) {
      int r = srow + i * 64;
      if (r < 96) {
        int sec = r >> 5, r32 = r & 31;
        *(short8*)&Bs[r][scol] =
            *(const short8*)&wt1[(sec * 512 + h * 32 + r32) * 512 + k0 + scol];
      }
    }
    __syncthreads();
    short8 af[4], bfv[6];
#pragma unroll
    for (int i = 0; i < 4; i++) {
      int mt = (i < 3) ? (wave + 4 * i) : (12 + (wave & 1));
      af[i] = *(short8*)&As[mt * 16 + l16][quad * 8];
    }
#pragma unroll
    for (int n = 0; n < 6; n++) bfv[n] = *(short8*)&Bs[n * 16 + l16][quad * 8];
#pragma unroll
    for (int i = 0; i < 4; i++)
#pragma unroll
      for (int n = 0; n < 6; n++)
        acc[i][n] = __builtin_amdgcn_mfma_f32_16x16x32_bf16(af[i], bfv[n],
                                                            acc[i][n], 0, 0, 0);
    __syncthreads();
  }
  const float qscale = 0.17677669529663687f;
#pragma unroll
  for (int i = 0; i < 4; i++) {
    if (i == 3 && wave >= 2) break;
    int mt = (i < 3) ? (wave + 4 * i) : (12 + wave);
    int row0 = mt * 16 + quad * 4;
#pragma unroll
    for (int n = 0; n < 6; n++) {
      int c = n * 16 + l16;
#pragma unroll
      for (int r = 0; r < 4; r++) {
        int row = row0 + r;
        float v = acc[i][n][r];
        if (c < 32)
          Qs[row][c] = f2bf(v * qscale);
        else if (c < 64)
          Ks[row][c - 32] = f2bf(v);
        else
          vTs[c - 64][row] = f2bf(v);
      }
    }
  }
  __syncthreads();
  for (int i2 = 0; i2 < 4; i2++) {
    bool active = (i2 < 3) || (wave == 0);
    int qt = (i2 < 3) ? (wave + 4 * i2) : 12;
    int qr0 = qt * 16;
    if (active) {
      short8 qf = *(short8*)&Qs[qr0 + l16][quad * 8];
      float4_t s[13];
#pragma unroll
      for (int kt = 0; kt < 13; kt++) {
        short8 kf = *(short8*)&Ks[kt * 16 + l16][quad * 8];
        s[kt] = __builtin_amdgcn_mfma_f32_16x16x32_bf16(qf, kf, z4, 0, 0, 0);
      }
      const float* brow = bias + (h * QPAD + qr0 + quad * 4) * KP;
#pragma unroll
      for (int kt = 0; kt < 13; kt++) {
        int col = kt * 16 + l16;
#pragma unroll
        for (int r = 0; r < 4; r++) s[kt][r] += brow[r * KP + col];
      }
      if (l16 >= 4) {
#pragma unroll
        for (int r = 0; r < 4; r++) s[12][r] = -1e30f;
      }
      int prow_base = wave * 16 + quad * 4;
#pragma unroll
      for (int r = 0; r < 4; r++) {
        float m = s[0][r];
#pragma unroll
        for (int kt = 1; kt < 13; kt++) m = fmaxf(m, s[kt][r]);
        m = fmaxf(m, __shfl_xor(m, 8, 16));
        m = fmaxf(m, __shfl_xor(m, 4, 16));
        m = fmaxf(m, __shfl_xor(m, 2, 16));
        m = fmaxf(m, __shfl_xor(m, 1, 16));
        float sum = 0.f;
#pragma unroll
        for (int kt = 0; kt < 13; kt++) {
          float p = __expf(s[kt][r] - m);
          s[kt][r] = p;
          sum += p;
        }
        sum += __shfl_xor(sum, 8, 16);
        sum += __shfl_xor(sum, 4, 16);
        sum += __shfl_xor(sum, 2, 16);
        sum += __shfl_xor(sum, 1, 16);
        float inv = 1.f / sum;
        short* prow = &P[prow_base + r][0];
#pragma unroll
        for (int kt = 0; kt < 13; kt++)
          prow[kt * 16 + l16] = f2bf(s[kt][r] * inv);
        prow[208 + l16] = 0;
      }
    }
    __syncthreads();
    if (active) {
      float4_t o0 = z4, o1 = z4;
#pragma unroll
      for (int kt = 0; kt < 7; kt++) {
        short8 pf = *(short8*)&P[wave * 16 + l16][kt * 32 + quad * 8];
        short8 vf0 = *(short8*)&vTs[l16][kt * 32 + quad * 8];
        short8 vf1 = *(short8*)&vTs[16 + l16][kt * 32 + quad * 8];
        o0 = __builtin_amdgcn_mfma_f32_16x16x32_bf16(pf, vf0, o0, 0, 0, 0);
        o1 = __builtin_amdgcn_mfma_f32_16x16x32_bf16(pf, vf1, o1, 0, 0, 0);
      }
#pragma unroll
      for (int r = 0; r < 4; r++) {
        int row = qr0 + quad * 4 + r;
        if (row < NTOK) {
          int off = (base_row + row) * 512 + h * 32;
          aout[off + l16] = f2bf(o0[r]);
          aout[off + 16 + l16] = f2bf(o1[r]);
        }
      }
    }
    __syncthreads();
  }
}

// ------------- proj GEMM + bias: out_f32 = aout[25088,512] @ w2^T + b --------
__global__ __launch_bounds__(256) void proj_gemm(
    const short* __restrict__ a, const short* __restrict__ wt,
    const float* __restrict__ pb, float* __restrict__ out) {
  __shared__ __align__(16) short As[128 * 64];
  __shared__ __align__(16) short Bs[128 * 64];
  float4_t acc[4][4];
  float4_t z = {0.f, 0.f, 0.f, 0.f};
#pragma unroll
  for (int i = 0; i < 4; i++)
#pragma unroll
    for (int j = 0; j < 4; j++) acc[i][j] = z;
  // XCD-chunked bijective swizzle: nwg = 4*196 = 784 = 8*98
  int lin = blockIdx.x + blockIdx.y * 4;
  int xcd = lin & 7, loc = lin >> 3;
  int nl = xcd * 98 + loc;
  int bx = nl % 4, by = nl / 4;
  int m0 = by * 128, n0 = bx * 128;
  gemm_tile(a, wt, 512, m0, n0, As, Bs, acc);
  int lane = threadIdx.x & 63, wave = threadIdx.x >> 6;
  int quad = lane >> 4, l16 = lane & 15;
  int wm = (wave >> 1) * 64, wn = (wave & 1) * 64;
#pragma unroll
  for (int mi = 0; mi < 4; mi++)
#pragma unroll
    for (int ni = 0; ni < 4; ni++) {
      int colg = n0 + wn + ni * 16 + l16;
      float bv = pb[colg];
#pragma unroll
      for (int r = 0; r < 4; r++) {
        int rowg = m0 + wm + mi * 16 + quad * 4 + r;
        out[rowg * 512 + colg] = acc[mi][ni][r] + bv;
      }
    }
}

extern "C" void kernel_launch(void* const* d_in, const int* in_sizes, int n_in,
                              void* d_out, int out_size, void* d_ws,
                              size_t ws_size, hipStream_t stream) {
  const float* x = (const float*)d_in[0];       // [25088,512] fp32
  const float* qkv_w = (const float*)d_in[1];   // [512,1536] fp32
  const float* table = (const float*)d_in[2];   // [729,16] fp32
  const float* proj_w = (const float*)d_in[3];  // [512,512] fp32
  const float* proj_b = (const float*)d_in[4];  // [512] fp32
  const int* rpi = (const int*)d_in[5];         // [196,196] int32
  float* out = (float*)d_out;

  char* w = (char*)d_ws;
  short* wt1 = (short*)(w);              // 1536*512*2   = 1,572,864
  short* wt2 = (short*)(w + 1572864);    // 512*512*2    =   524,288
  float* bias = (float*)(w + 2097152);   // 16*208*208*4 = 2,768,896
  short* xb = (short*)(w + 4866048);     // 25088*512*2  = 25,690,112
  // split-path extra slabs (q,k,v) on top:
  short* qb = (short*)(w + 30556160);    // 2048*208*32*2 = 27,262,976
  short* kb = (short*)(w + 57819136);
  short* vb = (short*)(w + 85082112);    // V^T layout [bh][32][208], same size
  const size_t NEEDED_SPLIT = 112345088;
  const size_t NEEDED_FUSED = 30556160 + 25690112;  // fused path slabs

  int split = ws_size >= NEEDED_SPLIT;
  if (ws_size >= NEEDED_FUSED) {
    prep_kernel<<<10000, 256, 0, stream>>>(qkv_w, proj_w, table, rpi, x, wt1,
                                           wt2, bias, vb, xb, split);
  }
  if (split) {
    // split path: xb slab doubles as aout (xb dead after qkv_gemm)
    short* aout = xb;
    qkv_gemm<<<dim3(12, 196), 256, 0, stream>>>(xb, wt1, qb, kb, vb);
    attn_kernel<<<2048, 256, 0, stream>>>(qb, kb, vb, bias, aout);
    proj_gemm<<<dim3(4, 196), 256, 0, stream>>>(aout, wt2, proj_b, out);
  } else if (ws_size >= NEEDED_FUSED) {
    short* aout = (short*)(w + 30556160);  // separate slab, round-4 layout
    fused_attn<<<2048, 256, 0, stream>>>(xb, wt1, bias, aout);
    proj_gemm<<<dim3(4, 196), 256, 0, stream>>>(aout, wt2, proj_b, out);
  } else {
    fill_kernel<<<(out_size + 255) / 256, 256, 0, stream>>>(out, out_size);
  }
}

// Round 8
// 271.716 us; speedup vs baseline: 1.1092x; 1.0118x over previous
//
#include <hip/hip_runtime.h>

#define NTOK 196
#define QPAD 208
#define KP 208
#define PSTR 232
#define VKP 208

typedef __attribute__((ext_vector_type(8))) short short8;
typedef __attribute__((ext_vector_type(4))) short short4_t;
typedef __attribute__((ext_vector_type(4))) float float4_t;

__device__ __forceinline__ short f2bf(float f) {
  unsigned u = __float_as_uint(f);
  u = (u + 0x7fffu + ((u >> 16) & 1u)) >> 16;
  return (short)u;
}

// ---------------- fallback: signal insufficient workspace ----------------
__global__ __launch_bounds__(256) void fill_kernel(float* __restrict__ out,
                                                   int n) {
  int i = blockIdx.x * 256 + threadIdx.x;
  if (i < n) out[i] = 1000.0f;
}

// ------------- transpose body: out_bf16[C][R] = in_f32[R][C] -----------------
__device__ __forceinline__ void transpose_body(const float* __restrict__ in,
                                               short* __restrict__ out, int R,
                                               int C, int bx, int by,
                                               float (*tile)[65]) {
  int c0 = bx * 64, r0 = by * 64;
  int tc = threadIdx.x & 63, tr = threadIdx.x >> 6;
#pragma unroll
  for (int s = 0; s < 16; s++) {
    int r = s * 4 + tr;
    tile[r][tc] = in[(r0 + r) * C + c0 + tc];
  }
  __syncthreads();
#pragma unroll
  for (int s = 0; s < 16; s++) {
    int i = s * 4 + tr;
    out[(c0 + i) * R + r0 + tc] = f2bf(tile[tc][i]);
  }
}

// ---- merged preamble: transposes + bias + V^T pad + x cvt (1 launch) ----
// blocks [0,192): qkv_w^T  [192,256): proj_w^T  [256,2960): bias
// [2960,3728): vpad  [3728,10000): x fp32->bf16
// bias is PRE-SCALED by log2(e): softmax uses exp2 (scale-invariant).
__global__ __launch_bounds__(256) void prep_kernel(
    const float* __restrict__ qkv_w, const float* __restrict__ proj_w,
    const float* __restrict__ table, const int* __restrict__ rpi,
    const float* __restrict__ x, short* __restrict__ wt1,
    short* __restrict__ wt2, float* __restrict__ bias, short* __restrict__ vb,
    short* __restrict__ xb, int do_vpad) {
  __shared__ float tile[64][65];
  int blk = blockIdx.x;
  if (blk < 192) {
    transpose_body(qkv_w, wt1, 512, 1536, blk % 24, blk / 24, tile);
  } else if (blk < 256) {
    int i = blk - 192;
    transpose_body(proj_w, wt2, 512, 512, i % 8, i / 8, tile);
  } else if (blk < 2960) {
    int idx = (blk - 256) * 256 + threadIdx.x;  // < 16*208*208 = 692224
    int h = idx / (QPAD * KP);
    int rem = idx % (QPAD * KP);
    int q = rem / KP, k = rem % KP;
    float v = 0.f;
    if (q < NTOK && k < NTOK)
      v = table[rpi[q * NTOK + k] * 16 + h] * 1.4426950408889634f;
    bias[idx] = v;
  } else if (blk < 3728) {
    if (do_vpad) {
      int i = (blk - 2960) * 256 + threadIdx.x;  // < 2048*32*3 = 196608
      int row = i / 3, g = i - 3 * (i / 3);
      short4_t z = {0, 0, 0, 0};
      *(short4_t*)&vb[row * VKP + 196 + g * 4] = z;
    }
  } else {
    int i = ((blk - 3728) * 256 + threadIdx.x) * 8;  // < 25088*512
    float4_t a = *(const float4_t*)&x[i];
    float4_t b = *(const float4_t*)&x[i + 4];
    short8 v;
    v[0] = f2bf(a[0]); v[1] = f2bf(a[1]); v[2] = f2bf(a[2]); v[3] = f2bf(a[3]);
    v[4] = f2bf(b[0]); v[5] = f2bf(b[1]); v[6] = f2bf(b[2]); v[7] = f2bf(b[3]);
    *(short8*)&xb[i] = v;
  }
}

// ---------------- shared 128x128 GEMM mainloop (validated, padded LDS) -------
// A/B settled (r4 vs r7): reg-staged+padded 78.4us beats global_load_lds+
// linear 84.6us at this shape (bank conflicts 4.8e6 vs 1.45e7). FINAL.
__device__ __forceinline__ void gemm_tile(const short* __restrict__ A,
                                          const short* __restrict__ B, int K,
                                          int m0, int n0, short (*As)[72],
                                          short (*Bs)[72], float4_t acc[4][4]) {
  int tid = threadIdx.x;
  int lane = tid & 63, wave = tid >> 6;
  int quad = lane >> 4, l16 = lane & 15;
  int wm = (wave >> 1) * 64, wn = (wave & 1) * 64;
  int srow = tid >> 3, scol = (tid & 7) * 8;
  for (int k0 = 0; k0 < K; k0 += 64) {
#pragma unroll
    for (int i = 0; i < 4; i++) {
      int r = srow + i * 32;
      *(short8*)&As[r][scol] = *(const short8*)&A[(m0 + r) * K + k0 + scol];
      *(short8*)&Bs[r][scol] = *(const short8*)&B[(n0 + r) * K + k0 + scol];
    }
    __syncthreads();
#pragma unroll
    for (int ks = 0; ks < 2; ks++) {
      short8 af[4], bfr[4];
#pragma unroll
      for (int i = 0; i < 4; i++) {
        af[i] = *(short8*)&As[wm + i * 16 + l16][ks * 32 + quad * 8];
        bfr[i] = *(short8*)&Bs[wn + i * 16 + l16][ks * 32 + quad * 8];
      }
#pragma unroll
      for (int mi = 0; mi < 4; mi++)
#pragma unroll
        for (int ni = 0; ni < 4; ni++)
          acc[mi][ni] = __builtin_amdgcn_mfma_f32_16x16x32_bf16(
              af[mi], bfr[ni], acc[mi][ni], 0, 0, 0);
    }
    __syncthreads();
  }
}

// -------- split path: QKV GEMM with scatter epilogue into q/k/v slabs --------
// V is written TRANSPOSED: vb[bh][d][VKP] so attn stages it with a coalesced
// row copy. Q is pre-scaled by 32^-0.5 * log2(e) for the exp2 softmax.
__global__ __launch_bounds__(256) void qkv_gemm(
    const short* __restrict__ xb, const short* __restrict__ wt1,
    short* __restrict__ qb, short* __restrict__ kb, short* __restrict__ vb) {
  __shared__ __align__(16) short As[128][72];
  __shared__ __align__(16) short Bs[128][72];
  float4_t acc[4][4];
  float4_t z = {0.f, 0.f, 0.f, 0.f};
#pragma unroll
  for (int i = 0; i < 4; i++)
#pragma unroll
    for (int j = 0; j < 4; j++) acc[i][j] = z;
  // XCD-chunked bijective swizzle: nwg = 12*196 = 2352 = 8*294
  int lin = blockIdx.x + blockIdx.y * 12;
  int xcd = lin & 7, loc = lin >> 3;
  int nl = xcd * 294 + loc;
  int bx = nl % 12, by = nl / 12;
  int m0 = by * 128, n0 = bx * 128;
  gemm_tile(xb, wt1, 512, m0, n0, As, Bs, acc);
  int lane = threadIdx.x & 63, wave = threadIdx.x >> 6;
  int quad = lane >> 4, l16 = lane & 15;
  int wm = (wave >> 1) * 64, wn = (wave & 1) * 64;
  const float qscale = 0.17677669529663687f * 1.4426950408889634f;
#pragma unroll
  for (int mi = 0; mi < 4; mi++)
#pragma unroll
    for (int ni = 0; ni < 4; ni++) {
      int colg = n0 + wn + ni * 16 + l16;
      int s = colg >> 9, rem = colg & 511;
      int h = rem >> 5, d = rem & 31;
      int rowg0 = m0 + wm + mi * 16 + quad * 4;
      if (s == 2) {
        int b = rowg0 / NTOK, nt = rowg0 - b * NTOK;  // nt % 4 == 0, <= 192
        short4_t v4;
        v4[0] = f2bf(acc[mi][ni][0]);
        v4[1] = f2bf(acc[mi][ni][1]);
        v4[2] = f2bf(acc[mi][ni][2]);
        v4[3] = f2bf(acc[mi][ni][3]);
        *(short4_t*)&vb[((b * 16 + h) * 32 + d) * VKP + nt] = v4;
      } else {
#pragma unroll
        for (int r = 0; r < 4; r++) {
          int rowg = rowg0 + r;
          int b = rowg / NTOK, n = rowg - b * NTOK;
          int off = ((b * 16 + h) * QPAD + n) * 32 + d;
          if (s == 0)
            qb[off] = f2bf(acc[mi][ni][r] * qscale);
          else
            kb[off] = f2bf(acc[mi][ni][r]);
        }
      }
    }
}

// -------- split path: attention, one block per (b,h), 4 waves --------
// K fragments are q-tile-invariant: loaded ONCE into registers (52 VGPRs)
// and reused across all 4 rounds (was reloaded 4x from global). VGPR-free:
// occupancy is LDS-limited at 3 blocks/CU. exp2 softmax (Q,bias prescaled).
// P is WAVE-PRIVATE -> only the staging barrier. Norm deferred to epilogue.
__global__ __launch_bounds__(256) void attn_kernel(
    const short* __restrict__ qb, const short* __restrict__ kb,
    const short* __restrict__ vb, const float* __restrict__ bias,
    short* __restrict__ aout) {
  __shared__ __align__(16) short vT[32][PSTR];
  __shared__ __align__(16) short P[4][16][PSTR];
  int bh = blockIdx.x, b = bh >> 4, h = bh & 15;
  int tid = threadIdx.x, wave = tid >> 6, lane = tid & 63;
  int quad = lane >> 4, l16 = lane & 15;
  int base_row = b * NTOK;
  // stage V^T rows: 32 rows x 208 shorts, coalesced 16B chunks
  const short* vsrc = vb + bh * 32 * VKP;
  for (int i = tid; i < 32 * 26; i += 256) {
    int d = i / 26, c = (i - d * 26) * 8;
    *(short8*)&vT[d][c] = *(const short8*)&vsrc[d * VKP + c];
  }
  short8 z8 = {0, 0, 0, 0, 0, 0, 0, 0};
  if (tid < 96) {
    int d = tid / 3, c = 208 + (tid - d * 3) * 8;
    *(short8*)&vT[d][c] = z8;
  }
  __syncthreads();
  // hoisted K fragments (per-lane, reused by every q-tile round)
  short8 kfr[13];
#pragma unroll
  for (int kt = 0; kt < 13; kt++)
    kfr[kt] = *(const short8*)&kb[(bh * QPAD + kt * 16 + l16) * 32 + quad * 8];
  float4_t z4 = {0.f, 0.f, 0.f, 0.f};
  for (int i2 = 0; i2 < 4; i2++) {
    bool active = (i2 < 3) || (wave == 0);
    if (!active) break;  // no barriers below: inactive waves simply exit
    int qt = (i2 < 3) ? (wave + 4 * i2) : 12;
    int qr0 = qt * 16;
    short8 qf = *(const short8*)&qb[(bh * QPAD + qr0 + l16) * 32 + quad * 8];
    float4_t s[13];
#pragma unroll
    for (int kt = 0; kt < 13; kt++)
      s[kt] = __builtin_amdgcn_mfma_f32_16x16x32_bf16(qf, kfr[kt], z4, 0, 0, 0);
    const float* brow = bias + (h * QPAD + qr0 + quad * 4) * KP;
#pragma unroll
    for (int kt = 0; kt < 13; kt++) {
      int col = kt * 16 + l16;
#pragma unroll
      for (int r = 0; r < 4; r++) s[kt][r] += brow[r * KP + col];
    }
    if (l16 >= 4) {
#pragma unroll
      for (int r = 0; r < 4; r++) s[12][r] = -1e30f;  // mask pad keys
    }
    float invr[4];
#pragma unroll
    for (int r = 0; r < 4; r++) {
      float m = s[0][r];
#pragma unroll
      for (int kt = 1; kt < 13; kt++) m = fmaxf(m, s[kt][r]);
      m = fmaxf(m, __shfl_xor(m, 8, 16));
      m = fmaxf(m, __shfl_xor(m, 4, 16));
      m = fmaxf(m, __shfl_xor(m, 2, 16));
      m = fmaxf(m, __shfl_xor(m, 1, 16));
      float sum = 0.f;
#pragma unroll
      for (int kt = 0; kt < 13; kt++) {
        float p = exp2f(s[kt][r] - m);  // S pre-scaled by log2(e)
        s[kt][r] = p;
        sum += p;
      }
      sum += __shfl_xor(sum, 8, 16);
      sum += __shfl_xor(sum, 4, 16);
      sum += __shfl_xor(sum, 2, 16);
      sum += __shfl_xor(sum, 1, 16);
      invr[r] = 1.f / sum;
      short* prow = &P[wave][quad * 4 + r][0];
#pragma unroll
      for (int kt = 0; kt < 13; kt++)
        prow[kt * 16 + l16] = f2bf(s[kt][r]);  // unnormalized, <= 1
      prow[208 + l16] = 0;  // zero pad cols 208..223 (224.. never read)
    }
    // in-wave LDS ordering guarantees P writes visible to same-wave reads
    float4_t o0 = z4, o1 = z4;
#pragma unroll
    for (int kt = 0; kt < 7; kt++) {
      short8 pf = *(short8*)&P[wave][l16][kt * 32 + quad * 8];
      short8 vf0 = *(short8*)&vT[l16][kt * 32 + quad * 8];
      short8 vf1 = *(short8*)&vT[16 + l16][kt * 32 + quad * 8];
      o0 = __builtin_amdgcn_mfma_f32_16x16x32_bf16(pf, vf0, o0, 0, 0, 0);
      o1 = __builtin_amdgcn_mfma_f32_16x16x32_bf16(pf, vf1, o1, 0, 0, 0);
    }
#pragma unroll
    for (int r = 0; r < 4; r++) {
      int row = qr0 + quad * 4 + r;
      if (row < NTOK) {
        int off = (base_row + row) * 512 + h * 32;
        aout[off + l16] = f2bf(o0[r] * invr[r]);
        aout[off + 16 + l16] = f2bf(o1[r] * invr[r]);
      }
    }
  }
}

// ---------------- fallback fused QKV-GEMM + attention (exp2-consistent) ------
__global__ __launch_bounds__(256, 2) void fused_attn(
    const short* __restrict__ xb, const short* __restrict__ wt1,
    const float* __restrict__ bias, short* __restrict__ aout) {
  __shared__ __align__(16) short R1[64 * PSTR];
  __shared__ __align__(16) short R2[32 * PSTR];
  __shared__ __align__(16) short Qs[224][40];
  __shared__ __align__(16) short Ks[224][40];
  short(*As)[40] = (short(*)[40])R1;
  short(*P)[PSTR] = (short(*)[PSTR])R1;
  short(*Bs)[40] = (short(*)[40])R2;
  short(*vTs)[PSTR] = (short(*)[PSTR])R2;

  int bh = blockIdx.x, b = bh >> 4, h = bh & 15;
  int tid = threadIdx.x, wave = tid >> 6, lane = tid & 63;
  int quad = lane >> 4, l16 = lane & 15;
  int base_row = b * NTOK;

  float4_t z4 = {0.f, 0.f, 0.f, 0.f};
  float4_t acc[4][6];
#pragma unroll
  for (int i = 0; i < 4; i++)
#pragma unroll
    for (int n = 0; n < 6; n++) acc[i][n] = z4;

  int srow = tid >> 2, scol = (tid & 3) * 8;
  for (int k0 = 0; k0 < 512; k0 += 32) {
#pragma unroll
    for (int i = 0; i < 4; i++) {
      int r = srow + i * 64;
      if (r < 224) {
        int gr = base_row + r;
        if (gr > 25087) gr = 25087;
        *(short8*)&As[r][scol] = *(const short8*)&xb[gr * 512 + k0 + scol];
      }
    }
#pragma unroll
    for (int i = 0; i < 2; i++) {
      int r = srow + i * 64;
      if (r < 96) {
        int sec = r >> 5, r32 = r & 31;
        *(short8*)&Bs[r][scol] =
            *(const short8*)&wt1[(sec * 512 + h * 32 + r32) * 512 + k0 + scol];
      }
    }
    __syncthreads();
    short8 af[4], bfv[6];
#pragma unroll
    for (int i = 0; i < 4; i++) {
      int mt = (i < 3) ? (wave + 4 * i) : (12 + (wave & 1));
      af[i] = *(short8*)&As[mt * 16 + l16][quad * 8];
    }
#pragma unroll
    for (int n = 0; n < 6; n++) bfv[n] = *(short8*)&Bs[n * 16 + l16][quad * 8];
#pragma unroll
    for (int i = 0; i < 4; i++)
#pragma unroll
      for (int n = 0; n < 6; n++)
        acc[i][n] = __builtin_amdgcn_mfma_f32_16x16x32_bf16(af[i], bfv[n],
                                                            acc[i][n], 0, 0, 0);
    __syncthreads();
  }
  const float qscale = 0.17677669529663687f * 1.4426950408889634f;
#pragma unroll
  for (int i = 0; i < 4; i++) {
    if (i == 3 && wave >= 2) break;
    int mt = (i < 3) ? (wave + 4 * i) : (12 + wave);
    int row0 = mt * 16 + quad * 4;
#pragma unroll
    for (int n = 0; n < 6; n++) {
      int c = n * 16 + l16;
#pragma unroll
      for (int r = 0; r < 4; r++) {
        int row = row0 + r;
        float v = acc[i][n][r];
        if (c < 32)
          Qs[row][c] = f2bf(v * qscale);
        else if (c < 64)
          Ks[row][c - 32] = f2bf(v);
        else
          vTs[c - 64][row] = f2bf(v);
      }
    }
  }
  __syncthreads();
  for (int i2 = 0; i2 < 4; i2++) {
    bool active = (i2 < 3) || (wave == 0);
    int qt = (i2 < 3) ? (wave + 4 * i2) : 12;
    int qr0 = qt * 16;
    if (active) {
      short8 qf = *(short8*)&Qs[qr0 + l16][quad * 8];
      float4_t s[13];
#pragma unroll
      for (int kt = 0; kt < 13; kt++) {
        short8 kf = *(short8*)&Ks[kt * 16 + l16][quad * 8];
        s[kt] = __builtin_amdgcn_mfma_f32_16x16x32_bf16(qf, kf, z4, 0, 0, 0);
      }
      const float* brow = bias + (h * QPAD + qr0 + quad * 4) * KP;
#pragma unroll
      for (int kt = 0; kt < 13; kt++) {
        int col = kt * 16 + l16;
#pragma unroll
        for (int r = 0; r < 4; r++) s[kt][r] += brow[r * KP + col];
      }
      if (l16 >= 4) {
#pragma unroll
        for (int r = 0; r < 4; r++) s[12][r] = -1e30f;
      }
      int prow_base = wave * 16 + quad * 4;
#pragma unroll
      for (int r = 0; r < 4; r++) {
        float m = s[0][r];
#pragma unroll
        for (int kt = 1; kt < 13; kt++) m = fmaxf(m, s[kt][r]);
        m = fmaxf(m, __shfl_xor(m, 8, 16));
        m = fmaxf(m, __shfl_xor(m, 4, 16));
        m = fmaxf(m, __shfl_xor(m, 2, 16));
        m = fmaxf(m, __shfl_xor(m, 1, 16));
        float sum = 0.f;
#pragma unroll
        for (int kt = 0; kt < 13; kt++) {
          float p = exp2f(s[kt][r] - m);
          s[kt][r] = p;
          sum += p;
        }
        sum += __shfl_xor(sum, 8, 16);
        sum += __shfl_xor(sum, 4, 16);
        sum += __shfl_xor(sum, 2, 16);
        sum += __shfl_xor(sum, 1, 16);
        float inv = 1.f / sum;
        short* prow = &P[prow_base + r][0];
#pragma unroll
        for (int kt = 0; kt < 13; kt++)
          prow[kt * 16 + l16] = f2bf(s[kt][r] * inv);
        prow[208 + l16] = 0;
      }
    }
    __syncthreads();
    if (active) {
      float4_t o0 = z4, o1 = z4;
#pragma unroll
      for (int kt = 0; kt < 7; kt++) {
        short8 pf = *(short8*)&P[wave * 16 + l16][kt * 32 + quad * 8];
        short8 vf0 = *(short8*)&vTs[l16][kt * 32 + quad * 8];
        short8 vf1 = *(short8*)&vTs[16 + l16][kt * 32 + quad * 8];
        o0 = __builtin_amdgcn_mfma_f32_16x16x32_bf16(pf, vf0, o0, 0, 0, 0);
        o1 = __builtin_amdgcn_mfma_f32_16x16x32_bf16(pf, vf1, o1, 0, 0, 0);
      }
#pragma unroll
      for (int r = 0; r < 4; r++) {
        int row = qr0 + quad * 4 + r;
        if (row < NTOK) {
          int off = (base_row + row) * 512 + h * 32;
          aout[off + l16] = f2bf(o0[r]);
          aout[off + 16 + l16] = f2bf(o1[r]);
        }
      }
    }
    __syncthreads();
  }
}

// ------------- proj GEMM + bias: out_f32 = aout[25088,512] @ w2^T + b --------
__global__ __launch_bounds__(256) void proj_gemm(
    const short* __restrict__ a, const short* __restrict__ wt,
    const float* __restrict__ pb, float* __restrict__ out) {
  __shared__ __align__(16) short As[128][72];
  __shared__ __align__(16) short Bs[128][72];
  float4_t acc[4][4];
  float4_t z = {0.f, 0.f, 0.f, 0.f};
#pragma unroll
  for (int i = 0; i < 4; i++)
#pragma unroll
    for (int j = 0; j < 4; j++) acc[i][j] = z;
  // XCD-chunked bijective swizzle: nwg = 4*196 = 784 = 8*98
  int lin = blockIdx.x + blockIdx.y * 4;
  int xcd = lin & 7, loc = lin >> 3;
  int nl = xcd * 98 + loc;
  int bx = nl % 4, by = nl / 4;
  int m0 = by * 128, n0 = bx * 128;
  gemm_tile(a, wt, 512, m0, n0, As, Bs, acc);
  int lane = threadIdx.x & 63, wave = threadIdx.x >> 6;
  int quad = lane >> 4, l16 = lane & 15;
  int wm = (wave >> 1) * 64, wn = (wave & 1) * 64;
#pragma unroll
  for (int mi = 0; mi < 4; mi++)
#pragma unroll
    for (int ni = 0; ni < 4; ni++) {
      int colg = n0 + wn + ni * 16 + l16;
      float bv = pb[colg];
#pragma unroll
      for (int r = 0; r < 4; r++) {
        int rowg = m0 + wm + mi * 16 + quad * 4 + r;
        out[rowg * 512 + colg] = acc[mi][ni][r] + bv;
      }
    }
}

extern "C" void kernel_launch(void* const* d_in, const int* in_sizes, int n_in,
                              void* d_out, int out_size, void* d_ws,
                              size_t ws_size, hipStream_t stream) {
  const float* x = (const float*)d_in[0];       // [25088,512] fp32
  const float* qkv_w = (const float*)d_in[1];   // [512,1536] fp32
  const float* table = (const float*)d_in[2];   // [729,16] fp32
  const float* proj_w = (const float*)d_in[3];  // [512,512] fp32
  const float* proj_b = (const float*)d_in[4];  // [512] fp32
  const int* rpi = (const int*)d_in[5];         // [196,196] int32
  float* out = (float*)d_out;

  char* w = (char*)d_ws;
  short* wt1 = (short*)(w);              // 1536*512*2   = 1,572,864
  short* wt2 = (short*)(w + 1572864);    // 512*512*2    =   524,288
  float* bias = (float*)(w + 2097152);   // 16*208*208*4 = 2,768,896
  short* xb = (short*)(w + 4866048);     // 25088*512*2  = 25,690,112
  // split-path extra slabs (q,k,v) on top:
  short* qb = (short*)(w + 30556160);    // 2048*208*32*2 = 27,262,976
  short* kb = (short*)(w + 57819136);
  short* vb = (short*)(w + 85082112);    // V^T layout [bh][32][208], same size
  const size_t NEEDED_SPLIT = 112345088;
  const size_t NEEDED_FUSED = 30556160 + 25690112;  // fused path slabs

  int split = ws_size >= NEEDED_SPLIT;
  if (ws_size >= NEEDED_FUSED) {
    prep_kernel<<<10000, 256, 0, stream>>>(qkv_w, proj_w, table, rpi, x, wt1,
                                           wt2, bias, vb, xb, split);
  }
  if (split) {
    // split path: xb slab doubles as aout (xb dead after qkv_gemm)
    short* aout = xb;
    qkv_gemm<<<dim3(12, 196), 256, 0, stream>>>(xb, wt1, qb, kb, vb);
    attn_kernel<<<2048, 256, 0, stream>>>(qb, kb, vb, bias, aout);
    proj_gemm<<<dim3(4, 196), 256, 0, stream>>>(aout, wt2, proj_b, out);
  } else if (ws_size >= NEEDED_FUSED) {
    short* aout = (short*)(w + 30556160);  // separate slab, round-4 layout
    fused_attn<<<2048, 256, 0, stream>>>(xb, wt1, bias, aout);
    proj_gemm<<<dim3(4, 196), 256, 0, stream>>>(aout, wt2, proj_b, out);
  } else {
    fill_kernel<<<(out_size + 255) / 256, 256, 0, stream>>>(out, out_size);
  }
}

// Round 9
// 265.630 us; speedup vs baseline: 1.1346x; 1.0229x over previous
//
#include <hip/hip_runtime.h>

#define NTOK 196
#define QPAD 208
#define KP 208
#define PSTR 232
#define VKP 208

typedef __attribute__((ext_vector_type(8))) short short8;
typedef __attribute__((ext_vector_type(4))) short short4_t;
typedef __attribute__((ext_vector_type(4))) float float4_t;

__device__ __forceinline__ short f2bf(float f) {
  unsigned u = __float_as_uint(f);
  u = (u + 0x7fffu + ((u >> 16) & 1u)) >> 16;
  return (short)u;
}

// ---------------- fallback: signal insufficient workspace ----------------
__global__ __launch_bounds__(256) void fill_kernel(float* __restrict__ out,
                                                   int n) {
  int i = blockIdx.x * 256 + threadIdx.x;
  if (i < n) out[i] = 1000.0f;
}

// ------------- transpose body: out_bf16[C][R] = in_f32[R][C] -----------------
__device__ __forceinline__ void transpose_body(const float* __restrict__ in,
                                               short* __restrict__ out, int R,
                                               int C, int bx, int by,
                                               float (*tile)[65]) {
  int c0 = bx * 64, r0 = by * 64;
  int tc = threadIdx.x & 63, tr = threadIdx.x >> 6;
#pragma unroll
  for (int s = 0; s < 16; s++) {
    int r = s * 4 + tr;
    tile[r][tc] = in[(r0 + r) * C + c0 + tc];
  }
  __syncthreads();
#pragma unroll
  for (int s = 0; s < 16; s++) {
    int i = s * 4 + tr;
    out[(c0 + i) * R + r0 + tc] = f2bf(tile[tc][i]);
  }
}

// ---- merged preamble: transposes + bias + V^T pad + x cvt (1 launch) ----
// blocks [0,192): qkv_w^T  [192,256): proj_w^T  [256,2960): bias-frag
// [2960,3728): vpad  [3728,10000): x fp32->bf16
// bias stored in MFMA-C fragment layout [h][qt13][kt13][lane64][r4] fp32,
// pre-scaled by log2(e) (softmax uses exp2; scale-invariant). Same 2.77MB.
__global__ __launch_bounds__(256) void prep_kernel(
    const float* __restrict__ qkv_w, const float* __restrict__ proj_w,
    const float* __restrict__ table, const int* __restrict__ rpi,
    const float* __restrict__ x, short* __restrict__ wt1,
    short* __restrict__ wt2, float* __restrict__ bias, short* __restrict__ vb,
    short* __restrict__ xb, int do_vpad) {
  __shared__ float tile[64][65];
  int blk = blockIdx.x;
  if (blk < 192) {
    transpose_body(qkv_w, wt1, 512, 1536, blk % 24, blk / 24, tile);
  } else if (blk < 256) {
    int i = blk - 192;
    transpose_body(proj_w, wt2, 512, 512, i % 8, i / 8, tile);
  } else if (blk < 2960) {
    int idx = (blk - 256) * 256 + threadIdx.x;  // < 16*13*13*64*4 = 692224
    int h = idx / 43264;                        // 13*13*64*4
    int rem = idx - h * 43264;
    int qt = rem / 3328;                        // 13*64*4
    int rem2 = rem - qt * 3328;
    int kt = rem2 >> 8;                         // 64*4
    int rem3 = rem2 & 255;
    int lane = rem3 >> 2, r = rem3 & 3;
    int q = qt * 16 + (lane >> 4) * 4 + r;
    int k = kt * 16 + (lane & 15);
    float v = 0.f;
    if (q < NTOK && k < NTOK)
      v = table[rpi[q * NTOK + k] * 16 + h] * 1.4426950408889634f;
    bias[idx] = v;
  } else if (blk < 3728) {
    if (do_vpad) {
      int i = (blk - 2960) * 256 + threadIdx.x;  // < 2048*32*3 = 196608
      int row = i / 3, g = i - 3 * (i / 3);
      short4_t z = {0, 0, 0, 0};
      *(short4_t*)&vb[row * VKP + 196 + g * 4] = z;
    }
  } else {
    int i = ((blk - 3728) * 256 + threadIdx.x) * 8;  // < 25088*512
    float4_t a = *(const float4_t*)&x[i];
    float4_t b = *(const float4_t*)&x[i + 4];
    short8 v;
    v[0] = f2bf(a[0]); v[1] = f2bf(a[1]); v[2] = f2bf(a[2]); v[3] = f2bf(a[3]);
    v[4] = f2bf(b[0]); v[5] = f2bf(b[1]); v[6] = f2bf(b[2]); v[7] = f2bf(b[3]);
    *(short8*)&xb[i] = v;
  }
}

// ---------------- shared 128x128 GEMM mainloop (validated, padded LDS) -------
// A/B settled (r4 vs r7): reg-staged+padded 78.4us beats global_load_lds+
// linear 84.6us at this shape (bank conflicts 4.8e6 vs 1.45e7). FINAL.
__device__ __forceinline__ void gemm_tile(const short* __restrict__ A,
                                          const short* __restrict__ B, int K,
                                          int m0, int n0, short (*As)[72],
                                          short (*Bs)[72], float4_t acc[4][4]) {
  int tid = threadIdx.x;
  int lane = tid & 63, wave = tid >> 6;
  int quad = lane >> 4, l16 = lane & 15;
  int wm = (wave >> 1) * 64, wn = (wave & 1) * 64;
  int srow = tid >> 3, scol = (tid & 7) * 8;
  for (int k0 = 0; k0 < K; k0 += 64) {
#pragma unroll
    for (int i = 0; i < 4; i++) {
      int r = srow + i * 32;
      *(short8*)&As[r][scol] = *(const short8*)&A[(m0 + r) * K + k0 + scol];
      *(short8*)&Bs[r][scol] = *(const short8*)&B[(n0 + r) * K + k0 + scol];
    }
    __syncthreads();
#pragma unroll
    for (int ks = 0; ks < 2; ks++) {
      short8 af[4], bfr[4];
#pragma unroll
      for (int i = 0; i < 4; i++) {
        af[i] = *(short8*)&As[wm + i * 16 + l16][ks * 32 + quad * 8];
        bfr[i] = *(short8*)&Bs[wn + i * 16 + l16][ks * 32 + quad * 8];
      }
#pragma unroll
      for (int mi = 0; mi < 4; mi++)
#pragma unroll
        for (int ni = 0; ni < 4; ni++)
          acc[mi][ni] = __builtin_amdgcn_mfma_f32_16x16x32_bf16(
              af[mi], bfr[ni], acc[mi][ni], 0, 0, 0);
    }
    __syncthreads();
  }
}

// -------- split path: QKV GEMM with scatter epilogue into q/k/v slabs --------
// V is written TRANSPOSED: vb[bh][d][VKP] so attn stages it with a coalesced
// row copy. Q is pre-scaled by 32^-0.5 * log2(e) for the exp2 softmax.
__global__ __launch_bounds__(256) void qkv_gemm(
    const short* __restrict__ xb, const short* __restrict__ wt1,
    short* __restrict__ qb, short* __restrict__ kb, short* __restrict__ vb) {
  __shared__ __align__(16) short As[128][72];
  __shared__ __align__(16) short Bs[128][72];
  float4_t acc[4][4];
  float4_t z = {0.f, 0.f, 0.f, 0.f};
#pragma unroll
  for (int i = 0; i < 4; i++)
#pragma unroll
    for (int j = 0; j < 4; j++) acc[i][j] = z;
  // XCD-chunked bijective swizzle: nwg = 12*196 = 2352 = 8*294
  int lin = blockIdx.x + blockIdx.y * 12;
  int xcd = lin & 7, loc = lin >> 3;
  int nl = xcd * 294 + loc;
  int bx = nl % 12, by = nl / 12;
  int m0 = by * 128, n0 = bx * 128;
  gemm_tile(xb, wt1, 512, m0, n0, As, Bs, acc);
  int lane = threadIdx.x & 63, wave = threadIdx.x >> 6;
  int quad = lane >> 4, l16 = lane & 15;
  int wm = (wave >> 1) * 64, wn = (wave & 1) * 64;
  const float qscale = 0.17677669529663687f * 1.4426950408889634f;
#pragma unroll
  for (int mi = 0; mi < 4; mi++)
#pragma unroll
    for (int ni = 0; ni < 4; ni++) {
      int colg = n0 + wn + ni * 16 + l16;
      int s = colg >> 9, rem = colg & 511;
      int h = rem >> 5, d = rem & 31;
      int rowg0 = m0 + wm + mi * 16 + quad * 4;
      if (s == 2) {
        int b = rowg0 / NTOK, nt = rowg0 - b * NTOK;  // nt % 4 == 0, <= 192
        short4_t v4;
        v4[0] = f2bf(acc[mi][ni][0]);
        v4[1] = f2bf(acc[mi][ni][1]);
        v4[2] = f2bf(acc[mi][ni][2]);
        v4[3] = f2bf(acc[mi][ni][3]);
        *(short4_t*)&vb[((b * 16 + h) * 32 + d) * VKP + nt] = v4;
      } else {
#pragma unroll
        for (int r = 0; r < 4; r++) {
          int rowg = rowg0 + r;
          int b = rowg / NTOK, n = rowg - b * NTOK;
          int off = ((b * 16 + h) * QPAD + n) * 32 + d;
          if (s == 0)
            qb[off] = f2bf(acc[mi][ni][r] * qscale);
          else
            kb[off] = f2bf(acc[mi][ni][r]);
        }
      }
    }
}

// -------- split path: attention, one block per (b,h), 4 waves --------
// Bias enters through the MFMA C-operand (fragment-layout float4 loads,
// 13 coalesced 16B loads/round replace 52 strided 4B loads + 52 VALU adds).
// K NOT register-hoisted (r8 A/B: neutral, cost 52 VGPRs). exp2 softmax.
// P is WAVE-PRIVATE -> only the staging barrier. Norm deferred to epilogue.
__global__ __launch_bounds__(256) void attn_kernel(
    const short* __restrict__ qb, const short* __restrict__ kb,
    const short* __restrict__ vb, const float* __restrict__ bias,
    short* __restrict__ aout) {
  __shared__ __align__(16) short vT[32][PSTR];
  __shared__ __align__(16) short P[4][16][PSTR];
  int bh = blockIdx.x, b = bh >> 4, h = bh & 15;
  int tid = threadIdx.x, wave = tid >> 6, lane = tid & 63;
  int quad = lane >> 4, l16 = lane & 15;
  int base_row = b * NTOK;
  // stage V^T rows: 32 rows x 208 shorts, coalesced 16B chunks
  const short* vsrc = vb + bh * 32 * VKP;
  for (int i = tid; i < 32 * 26; i += 256) {
    int d = i / 26, c = (i - d * 26) * 8;
    *(short8*)&vT[d][c] = *(const short8*)&vsrc[d * VKP + c];
  }
  short8 z8 = {0, 0, 0, 0, 0, 0, 0, 0};
  if (tid < 96) {
    int d = tid / 3, c = 208 + (tid - d * 3) * 8;
    *(short8*)&vT[d][c] = z8;
  }
  __syncthreads();
  const float4_t* bfrag = (const float4_t*)bias;  // [h][13][13][64] float4
  float4_t z4 = {0.f, 0.f, 0.f, 0.f};
  for (int i2 = 0; i2 < 4; i2++) {
    bool active = (i2 < 3) || (wave == 0);
    if (!active) break;  // no barriers below: inactive waves simply exit
    int qt = (i2 < 3) ? (wave + 4 * i2) : 12;
    int qr0 = qt * 16;
    short8 qf = *(const short8*)&qb[(bh * QPAD + qr0 + l16) * 32 + quad * 8];
    const float4_t* bq = bfrag + (h * 13 + qt) * 13 * 64 + lane;
    float4_t s[13];
#pragma unroll
    for (int kt = 0; kt < 13; kt++) {
      short8 kf =
          *(const short8*)&kb[(bh * QPAD + kt * 16 + l16) * 32 + quad * 8];
      s[kt] =
          __builtin_amdgcn_mfma_f32_16x16x32_bf16(qf, kf, bq[kt * 64], 0, 0, 0);
    }
    if (l16 >= 4) {
#pragma unroll
      for (int r = 0; r < 4; r++) s[12][r] = -1e30f;  // mask pad keys
    }
    float invr[4];
#pragma unroll
    for (int r = 0; r < 4; r++) {
      float m = s[0][r];
#pragma unroll
      for (int kt = 1; kt < 13; kt++) m = fmaxf(m, s[kt][r]);
      m = fmaxf(m, __shfl_xor(m, 8, 16));
      m = fmaxf(m, __shfl_xor(m, 4, 16));
      m = fmaxf(m, __shfl_xor(m, 2, 16));
      m = fmaxf(m, __shfl_xor(m, 1, 16));
      float sum = 0.f;
#pragma unroll
      for (int kt = 0; kt < 13; kt++) {
        float p = exp2f(s[kt][r] - m);  // S pre-scaled by log2(e)
        s[kt][r] = p;
        sum += p;
      }
      sum += __shfl_xor(sum, 8, 16);
      sum += __shfl_xor(sum, 4, 16);
      sum += __shfl_xor(sum, 2, 16);
      sum += __shfl_xor(sum, 1, 16);
      invr[r] = 1.f / sum;
      short* prow = &P[wave][quad * 4 + r][0];
#pragma unroll
      for (int kt = 0; kt < 13; kt++)
        prow[kt * 16 + l16] = f2bf(s[kt][r]);  // unnormalized, <= 1
      prow[208 + l16] = 0;  // zero pad cols 208..223 (224.. never read)
    }
    // in-wave LDS ordering guarantees P writes visible to same-wave reads
    float4_t o0 = z4, o1 = z4;
#pragma unroll
    for (int kt = 0; kt < 7; kt++) {
      short8 pf = *(short8*)&P[wave][l16][kt * 32 + quad * 8];
      short8 vf0 = *(short8*)&vT[l16][kt * 32 + quad * 8];
      short8 vf1 = *(short8*)&vT[16 + l16][kt * 32 + quad * 8];
      o0 = __builtin_amdgcn_mfma_f32_16x16x32_bf16(pf, vf0, o0, 0, 0, 0);
      o1 = __builtin_amdgcn_mfma_f32_16x16x32_bf16(pf, vf1, o1, 0, 0, 0);
    }
#pragma unroll
    for (int r = 0; r < 4; r++) {
      int row = qr0 + quad * 4 + r;
      if (row < NTOK) {
        int off = (base_row + row) * 512 + h * 32;
        aout[off + l16] = f2bf(o0[r] * invr[r]);
        aout[off + 16 + l16] = f2bf(o1[r] * invr[r]);
      }
    }
  }
}

// ---------------- fallback fused QKV-GEMM + attention (bias-frag version) ----
__global__ __launch_bounds__(256, 2) void fused_attn(
    const short* __restrict__ xb, const short* __restrict__ wt1,
    const float* __restrict__ bias, short* __restrict__ aout) {
  __shared__ __align__(16) short R1[64 * PSTR];
  __shared__ __align__(16) short R2[32 * PSTR];
  __shared__ __align__(16) short Qs[224][40];
  __shared__ __align__(16) short Ks[224][40];
  short(*As)[40] = (short(*)[40])R1;
  short(*P)[PSTR] = (short(*)[PSTR])R1;
  short(*Bs)[40] = (short(*)[40])R2;
  short(*vTs)[PSTR] = (short(*)[PSTR])R2;

  int bh = blockIdx.x, b = bh >> 4, h = bh & 15;
  int tid = threadIdx.x, wave = tid >> 6, lane = tid & 63;
  int quad = lane >> 4, l16 = lane & 15;
  int base_row = b * NTOK;

  float4_t z4 = {0.f, 0.f, 0.f, 0.f};
  float4_t acc[4][6];
#pragma unroll
  for (int i = 0; i < 4; i++)
#pragma unroll
    for (int n = 0; n < 6; n++) acc[i][n] = z4;

  int srow = tid >> 2, scol = (tid & 3) * 8;
  for (int k0 = 0; k0 < 512; k0 += 32) {
#pragma unroll
    for (int i = 0; i < 4; i++) {
      int r = srow + i * 64;
      if (r < 224) {
        int gr = base_row + r;
        if (gr > 25087) gr = 25087;
        *(short8*)&As[r][scol] = *(const short8*)&xb[gr * 512 + k0 + scol];
      }
    }
#pragma unroll
    for (int i = 0; i < 2; i++) {
      int r = srow + i * 64;
      if (r < 96) {
        int sec = r >> 5, r32 = r & 31;
        *(short8*)&Bs[r][scol] =
            *(const short8*)&wt1[(sec * 512 + h * 32 + r32) * 512 + k0 + scol];
      }
    }
    __syncthreads();
    short8 af[4], bfv[6];
#pragma unroll
    for (int i = 0; i < 4; i++) {
      int mt = (i < 3) ? (wave + 4 * i) : (12 + (wave & 1));
      af[i] = *(short8*)&As[mt * 16 + l16][quad * 8];
    }
#pragma unroll
    for (int n = 0; n < 6; n++) bfv[n] = *(short8*)&Bs[n * 16 + l16][quad * 8];
#pragma unroll
    for (int i = 0; i < 4; i++)
#pragma unroll
      for (int n = 0; n < 6; n++)
        acc[i][n] = __builtin_amdgcn_mfma_f32_16x16x32_bf16(af[i], bfv[n],
                                                            acc[i][n], 0, 0, 0);
    __syncthreads();
  }
  const float qscale = 0.17677669529663687f * 1.4426950408889634f;
#pragma unroll
  for (int i = 0; i < 4; i++) {
    if (i == 3 && wave >= 2) break;
    int mt = (i < 3) ? (wave + 4 * i) : (12 + wave);
    int row0 = mt * 16 + quad * 4;
#pragma unroll
    for (int n = 0; n < 6; n++) {
      int c = n * 16 + l16;
#pragma unroll
      for (int r = 0; r < 4; r++) {
        int row = row0 + r;
        float v = acc[i][n][r];
        if (c < 32)
          Qs[row][c] = f2bf(v * qscale);
        else if (c < 64)
          Ks[row][c - 32] = f2bf(v);
        else
          vTs[c - 64][row] = f2bf(v);
      }
    }
  }
  __syncthreads();
  for (int i2 = 0; i2 < 4; i2++) {
    bool active = (i2 < 3) || (wave == 0);
    int qt = (i2 < 3) ? (wave + 4 * i2) : 12;
    int qr0 = qt * 16;
    if (active) {
      short8 qf = *(short8*)&Qs[qr0 + l16][quad * 8];
      const float4_t* bq =
          (const float4_t*)bias + (h * 13 + qt) * 13 * 64 + lane;
      float4_t s[13];
#pragma unroll
      for (int kt = 0; kt < 13; kt++) {
        short8 kf = *(short8*)&Ks[kt * 16 + l16][quad * 8];
        s[kt] = __builtin_amdgcn_mfma_f32_16x16x32_bf16(qf, kf, bq[kt * 64], 0,
                                                        0, 0);
      }
      if (l16 >= 4) {
#pragma unroll
        for (int r = 0; r < 4; r++) s[12][r] = -1e30f;
      }
      int prow_base = wave * 16 + quad * 4;
#pragma unroll
      for (int r = 0; r < 4; r++) {
        float m = s[0][r];
#pragma unroll
        for (int kt = 1; kt < 13; kt++) m = fmaxf(m, s[kt][r]);
        m = fmaxf(m, __shfl_xor(m, 8, 16));
        m = fmaxf(m, __shfl_xor(m, 4, 16));
        m = fmaxf(m, __shfl_xor(m, 2, 16));
        m = fmaxf(m, __shfl_xor(m, 1, 16));
        float sum = 0.f;
#pragma unroll
        for (int kt = 0; kt < 13; kt++) {
          float p = exp2f(s[kt][r] - m);
          s[kt][r] = p;
          sum += p;
        }
        sum += __shfl_xor(sum, 8, 16);
        sum += __shfl_xor(sum, 4, 16);
        sum += __shfl_xor(sum, 2, 16);
        sum += __shfl_xor(sum, 1, 16);
        float inv = 1.f / sum;
        short* prow = &P[prow_base + r][0];
#pragma unroll
        for (int kt = 0; kt < 13; kt++)
          prow[kt * 16 + l16] = f2bf(s[kt][r] * inv);
        prow[208 + l16] = 0;
      }
    }
    __syncthreads();
    if (active) {
      float4_t o0 = z4, o1 = z4;
#pragma unroll
      for (int kt = 0; kt < 7; kt++) {
        short8 pf = *(short8*)&P[wave * 16 + l16][kt * 32 + quad * 8];
        short8 vf0 = *(short8*)&vTs[l16][kt * 32 + quad * 8];
        short8 vf1 = *(short8*)&vTs[16 + l16][kt * 32 + quad * 8];
        o0 = __builtin_amdgcn_mfma_f32_16x16x32_bf16(pf, vf0, o0, 0, 0, 0);
        o1 = __builtin_amdgcn_mfma_f32_16x16x32_bf16(pf, vf1, o1, 0, 0, 0);
      }
#pragma unroll
      for (int r = 0; r < 4; r++) {
        int row = qr0 + quad * 4 + r;
        if (row < NTOK) {
          int off = (base_row + row) * 512 + h * 32;
          aout[off + l16] = f2bf(o0[r]);
          aout[off + 16 + l16] = f2bf(o1[r]);
        }
      }
    }
    __syncthreads();
  }
}

// ------------- proj GEMM + bias: out_f32 = aout[25088,512] @ w2^T + b --------
__global__ __launch_bounds__(256) void proj_gemm(
    const short* __restrict__ a, const short* __restrict__ wt,
    const float* __restrict__ pb, float* __restrict__ out) {
  __shared__ __align__(16) short As[128][72];
  __shared__ __align__(16) short Bs[128][72];
  float4_t acc[4][4];
  float4_t z = {0.f, 0.f, 0.f, 0.f};
#pragma unroll
  for (int i = 0; i < 4; i++)
#pragma unroll
    for (int j = 0; j < 4; j++) acc[i][j] = z;
  // XCD-chunked bijective swizzle: nwg = 4*196 = 784 = 8*98
  int lin = blockIdx.x + blockIdx.y * 4;
  int xcd = lin & 7, loc = lin >> 3;
  int nl = xcd * 98 + loc;
  int bx = nl % 4, by = nl / 4;
  int m0 = by * 128, n0 = bx * 128;
  gemm_tile(a, wt, 512, m0, n0, As, Bs, acc);
  int lane = threadIdx.x & 63, wave = threadIdx.x >> 6;
  int quad = lane >> 4, l16 = lane & 15;
  int wm = (wave >> 1) * 64, wn = (wave & 1) * 64;
#pragma unroll
  for (int mi = 0; mi < 4; mi++)
#pragma unroll
    for (int ni = 0; ni < 4; ni++) {
      int colg = n0 + wn + ni * 16 + l16;
      float bv = pb[colg];
#pragma unroll
      for (int r = 0; r < 4; r++) {
        int rowg = m0 + wm + mi * 16 + quad * 4 + r;
        out[rowg * 512 + colg] = acc[mi][ni][r] + bv;
      }
    }
}

extern "C" void kernel_launch(void* const* d_in, const int* in_sizes, int n_in,
                              void* d_out, int out_size, void* d_ws,
                              size_t ws_size, hipStream_t stream) {
  const float* x = (const float*)d_in[0];       // [25088,512] fp32
  const float* qkv_w = (const float*)d_in[1];   // [512,1536] fp32
  const float* table = (const float*)d_in[2];   // [729,16] fp32
  const float* proj_w = (const float*)d_in[3];  // [512,512] fp32
  const float* proj_b = (const float*)d_in[4];  // [512] fp32
  const int* rpi = (const int*)d_in[5];         // [196,196] int32
  float* out = (float*)d_out;

  char* w = (char*)d_ws;
  short* wt1 = (short*)(w);              // 1536*512*2   = 1,572,864
  short* wt2 = (short*)(w + 1572864);    // 512*512*2    =   524,288
  float* bias = (float*)(w + 2097152);   // 16*13*13*64*4*4 = 2,768,896
  short* xb = (short*)(w + 4866048);     // 25088*512*2  = 25,690,112
  // split-path extra slabs (q,k,v) on top:
  short* qb = (short*)(w + 30556160);    // 2048*208*32*2 = 27,262,976
  short* kb = (short*)(w + 57819136);
  short* vb = (short*)(w + 85082112);    // V^T layout [bh][32][208], same size
  const size_t NEEDED_SPLIT = 112345088;
  const size_t NEEDED_FUSED = 30556160 + 25690112;  // fused path slabs

  int split = ws_size >= NEEDED_SPLIT;
  if (ws_size >= NEEDED_FUSED) {
    prep_kernel<<<10000, 256, 0, stream>>>(qkv_w, proj_w, table, rpi, x, wt1,
                                           wt2, bias, vb, xb, split);
  }
  if (split) {
    // split path: xb slab doubles as aout (xb dead after qkv_gemm)
    short* aout = xb;
    qkv_gemm<<<dim3(12, 196), 256, 0, stream>>>(xb, wt1, qb, kb, vb);
    attn_kernel<<<2048, 256, 0, stream>>>(qb, kb, vb, bias, aout);
    proj_gemm<<<dim3(4, 196), 256, 0, stream>>>(aout, wt2, proj_b, out);
  } else if (ws_size >= NEEDED_FUSED) {
    short* aout = (short*)(w + 30556160);  // separate slab, round-4 layout
    fused_attn<<<2048, 256, 0, stream>>>(xb, wt1, bias, aout);
    proj_gemm<<<dim3(4, 196), 256, 0, stream>>>(aout, wt2, proj_b, out);
  } else {
    fill_kernel<<<(out_size + 255) / 256, 256, 0, stream>>>(out, out_size);
  }
}

// Round 10
// 265.454 us; speedup vs baseline: 1.1354x; 1.0007x over previous
//
#include <hip/hip_runtime.h>

#define NTOK 196
#define QPAD 208
#define KP 208
#define PSTR 232
#define VKP 208

typedef __attribute__((ext_vector_type(8))) short short8;
typedef __attribute__((ext_vector_type(4))) short short4_t;
typedef __attribute__((ext_vector_type(4))) float float4_t;

__device__ __forceinline__ short f2bf(float f) {
  unsigned u = __float_as_uint(f);
  u = (u + 0x7fffu + ((u >> 16) & 1u)) >> 16;
  return (short)u;
}

// DPP row_ror reductions over 16-lane groups (VALU pipe; replaces
// __shfl_xor's ds_bpermute on the DS pipe). Rotation trees reduce fully.
template <int CTRL>
__device__ __forceinline__ float red_fmax(float m) {
  int t = __builtin_amdgcn_update_dpp(0, __float_as_int(m), CTRL, 0xF, 0xF,
                                      true);
  return fmaxf(m, __int_as_float(t));
}
template <int CTRL>
__device__ __forceinline__ float red_add(float s) {
  int t = __builtin_amdgcn_update_dpp(0, __float_as_int(s), CTRL, 0xF, 0xF,
                                      true);
  return s + __int_as_float(t);
}

// v_cvt_pk_bf16_f32: lo->bits[15:0], hi->bits[31:16], RNE (matches f2bf).
__device__ __forceinline__ unsigned cvt_pk_bf16(float lo, float hi) {
  unsigned r;
  asm("v_cvt_pk_bf16_f32 %0, %1, %2" : "=v"(r) : "v"(lo), "v"(hi));
  return r;
}

// ---------------- fallback: signal insufficient workspace ----------------
__global__ __launch_bounds__(256) void fill_kernel(float* __restrict__ out,
                                                   int n) {
  int i = blockIdx.x * 256 + threadIdx.x;
  if (i < n) out[i] = 1000.0f;
}

// ------------- transpose body: out_bf16[C][R] = in_f32[R][C] -----------------
__device__ __forceinline__ void transpose_body(const float* __restrict__ in,
                                               short* __restrict__ out, int R,
                                               int C, int bx, int by,
                                               float (*tile)[65]) {
  int c0 = bx * 64, r0 = by * 64;
  int tc = threadIdx.x & 63, tr = threadIdx.x >> 6;
#pragma unroll
  for (int s = 0; s < 16; s++) {
    int r = s * 4 + tr;
    tile[r][tc] = in[(r0 + r) * C + c0 + tc];
  }
  __syncthreads();
#pragma unroll
  for (int s = 0; s < 16; s++) {
    int i = s * 4 + tr;
    out[(c0 + i) * R + r0 + tc] = f2bf(tile[tc][i]);
  }
}

// ---- merged preamble: transposes + bias + V^T pad + x cvt (1 launch) ----
// blocks [0,192): qkv_w^T  [192,256): proj_w^T  [256,2960): bias-frag
// [2960,3728): vpad  [3728,10000): x fp32->bf16
// bias stored in MFMA-C fragment layout [h][qt13][kt13][lane64][r4] fp32,
// pre-scaled by log2(e) (softmax uses exp2; scale-invariant). Same 2.77MB.
__global__ __launch_bounds__(256) void prep_kernel(
    const float* __restrict__ qkv_w, const float* __restrict__ proj_w,
    const float* __restrict__ table, const int* __restrict__ rpi,
    const float* __restrict__ x, short* __restrict__ wt1,
    short* __restrict__ wt2, float* __restrict__ bias, short* __restrict__ vb,
    short* __restrict__ xb, int do_vpad) {
  __shared__ float tile[64][65];
  int blk = blockIdx.x;
  if (blk < 192) {
    transpose_body(qkv_w, wt1, 512, 1536, blk % 24, blk / 24, tile);
  } else if (blk < 256) {
    int i = blk - 192;
    transpose_body(proj_w, wt2, 512, 512, i % 8, i / 8, tile);
  } else if (blk < 2960) {
    int idx = (blk - 256) * 256 + threadIdx.x;  // < 16*13*13*64*4 = 692224
    int h = idx / 43264;                        // 13*13*64*4
    int rem = idx - h * 43264;
    int qt = rem / 3328;                        // 13*64*4
    int rem2 = rem - qt * 3328;
    int kt = rem2 >> 8;                         // 64*4
    int rem3 = rem2 & 255;
    int lane = rem3 >> 2, r = rem3 & 3;
    int q = qt * 16 + (lane >> 4) * 4 + r;
    int k = kt * 16 + (lane & 15);
    float v = 0.f;
    if (q < NTOK && k < NTOK)
      v = table[rpi[q * NTOK + k] * 16 + h] * 1.4426950408889634f;
    bias[idx] = v;
  } else if (blk < 3728) {
    if (do_vpad) {
      int i = (blk - 2960) * 256 + threadIdx.x;  // < 2048*32*3 = 196608
      int row = i / 3, g = i - 3 * (i / 3);
      short4_t z = {0, 0, 0, 0};
      *(short4_t*)&vb[row * VKP + 196 + g * 4] = z;
    }
  } else {
    int i = ((blk - 3728) * 256 + threadIdx.x) * 8;  // < 25088*512
    float4_t a = *(const float4_t*)&x[i];
    float4_t b = *(const float4_t*)&x[i + 4];
    short8 v;
    v[0] = f2bf(a[0]); v[1] = f2bf(a[1]); v[2] = f2bf(a[2]); v[3] = f2bf(a[3]);
    v[4] = f2bf(b[0]); v[5] = f2bf(b[1]); v[6] = f2bf(b[2]); v[7] = f2bf(b[3]);
    *(short8*)&xb[i] = v;
  }
}

// ---------------- shared 128x128 GEMM mainloop (validated, padded LDS) -------
// A/B settled (r4 vs r7): reg-staged+padded 78.4us beats global_load_lds+
// linear 84.6us at this shape (bank conflicts 4.8e6 vs 1.45e7). FINAL.
__device__ __forceinline__ void gemm_tile(const short* __restrict__ A,
                                          const short* __restrict__ B, int K,
                                          int m0, int n0, short (*As)[72],
                                          short (*Bs)[72], float4_t acc[4][4]) {
  int tid = threadIdx.x;
  int lane = tid & 63, wave = tid >> 6;
  int quad = lane >> 4, l16 = lane & 15;
  int wm = (wave >> 1) * 64, wn = (wave & 1) * 64;
  int srow = tid >> 3, scol = (tid & 7) * 8;
  for (int k0 = 0; k0 < K; k0 += 64) {
#pragma unroll
    for (int i = 0; i < 4; i++) {
      int r = srow + i * 32;
      *(short8*)&As[r][scol] = *(const short8*)&A[(m0 + r) * K + k0 + scol];
      *(short8*)&Bs[r][scol] = *(const short8*)&B[(n0 + r) * K + k0 + scol];
    }
    __syncthreads();
#pragma unroll
    for (int ks = 0; ks < 2; ks++) {
      short8 af[4], bfr[4];
#pragma unroll
      for (int i = 0; i < 4; i++) {
        af[i] = *(short8*)&As[wm + i * 16 + l16][ks * 32 + quad * 8];
        bfr[i] = *(short8*)&Bs[wn + i * 16 + l16][ks * 32 + quad * 8];
      }
#pragma unroll
      for (int mi = 0; mi < 4; mi++)
#pragma unroll
        for (int ni = 0; ni < 4; ni++)
          acc[mi][ni] = __builtin_amdgcn_mfma_f32_16x16x32_bf16(
              af[mi], bfr[ni], acc[mi][ni], 0, 0, 0);
    }
    __syncthreads();
  }
}

// -------- split path: QKV GEMM with scatter epilogue into q/k/v slabs --------
// V is written TRANSPOSED: vb[bh][d][VKP] so attn stages it with a coalesced
// row copy. Q is pre-scaled by 32^-0.5 * log2(e) for the exp2 softmax.
__global__ __launch_bounds__(256) void qkv_gemm(
    const short* __restrict__ xb, const short* __restrict__ wt1,
    short* __restrict__ qb, short* __restrict__ kb, short* __restrict__ vb) {
  __shared__ __align__(16) short As[128][72];
  __shared__ __align__(16) short Bs[128][72];
  float4_t acc[4][4];
  float4_t z = {0.f, 0.f, 0.f, 0.f};
#pragma unroll
  for (int i = 0; i < 4; i++)
#pragma unroll
    for (int j = 0; j < 4; j++) acc[i][j] = z;
  // XCD-chunked bijective swizzle: nwg = 12*196 = 2352 = 8*294
  int lin = blockIdx.x + blockIdx.y * 12;
  int xcd = lin & 7, loc = lin >> 3;
  int nl = xcd * 294 + loc;
  int bx = nl % 12, by = nl / 12;
  int m0 = by * 128, n0 = bx * 128;
  gemm_tile(xb, wt1, 512, m0, n0, As, Bs, acc);
  int lane = threadIdx.x & 63, wave = threadIdx.x >> 6;
  int quad = lane >> 4, l16 = lane & 15;
  int wm = (wave >> 1) * 64, wn = (wave & 1) * 64;
  const float qscale = 0.17677669529663687f * 1.4426950408889634f;
#pragma unroll
  for (int mi = 0; mi < 4; mi++)
#pragma unroll
    for (int ni = 0; ni < 4; ni++) {
      int colg = n0 + wn + ni * 16 + l16;
      int s = colg >> 9, rem = colg & 511;
      int h = rem >> 5, d = rem & 31;
      int rowg0 = m0 + wm + mi * 16 + quad * 4;
      if (s == 2) {
        int b = rowg0 / NTOK, nt = rowg0 - b * NTOK;  // nt % 4 == 0, <= 192
        short4_t v4;
        v4[0] = f2bf(acc[mi][ni][0]);
        v4[1] = f2bf(acc[mi][ni][1]);
        v4[2] = f2bf(acc[mi][ni][2]);
        v4[3] = f2bf(acc[mi][ni][3]);
        *(short4_t*)&vb[((b * 16 + h) * 32 + d) * VKP + nt] = v4;
      } else {
#pragma unroll
        for (int r = 0; r < 4; r++) {
          int rowg = rowg0 + r;
          int b = rowg / NTOK, n = rowg - b * NTOK;
          int off = ((b * 16 + h) * QPAD + n) * 32 + d;
          if (s == 0)
            qb[off] = f2bf(acc[mi][ni][r] * qscale);
          else
            kb[off] = f2bf(acc[mi][ni][r]);
        }
      }
    }
}

// -------- split path: attention, one block per (b,h), 4 waves --------
// Bias enters through the MFMA C-operand (fragment-layout float4 loads).
// Softmax reductions via DPP row_ror (VALU pipe, no DS latency); tree
// fmax/add for ILP; P conversion via v_cvt_pk_bf16_f32 (1 op / 2 values).
// P is WAVE-PRIVATE -> only the staging barrier. Norm deferred to epilogue.
__global__ __launch_bounds__(256) void attn_kernel(
    const short* __restrict__ qb, const short* __restrict__ kb,
    const short* __restrict__ vb, const float* __restrict__ bias,
    short* __restrict__ aout) {
  __shared__ __align__(16) short vT[32][PSTR];
  __shared__ __align__(16) short P[4][16][PSTR];
  int bh = blockIdx.x, b = bh >> 4, h = bh & 15;
  int tid = threadIdx.x, wave = tid >> 6, lane = tid & 63;
  int quad = lane >> 4, l16 = lane & 15;
  int base_row = b * NTOK;
  // stage V^T rows: 32 rows x 208 shorts, coalesced 16B chunks
  const short* vsrc = vb + bh * 32 * VKP;
  for (int i = tid; i < 32 * 26; i += 256) {
    int d = i / 26, c = (i - d * 26) * 8;
    *(short8*)&vT[d][c] = *(const short8*)&vsrc[d * VKP + c];
  }
  short8 z8 = {0, 0, 0, 0, 0, 0, 0, 0};
  if (tid < 96) {
    int d = tid / 3, c = 208 + (tid - d * 3) * 8;
    *(short8*)&vT[d][c] = z8;
  }
  // P pad cols 208..223 never change: zero once per wave (rows l16 x quad*4)
  {
    short4_t zp = {0, 0, 0, 0};
    *(short4_t*)&P[wave][l16][208 + quad * 4] = zp;
  }
  __syncthreads();
  const float4_t* bfrag = (const float4_t*)bias;  // [h][13][13][64] float4
  float4_t z4 = {0.f, 0.f, 0.f, 0.f};
  for (int i2 = 0; i2 < 4; i2++) {
    bool active = (i2 < 3) || (wave == 0);
    if (!active) break;  // no barriers below: inactive waves simply exit
    int qt = (i2 < 3) ? (wave + 4 * i2) : 12;
    int qr0 = qt * 16;
    short8 qf = *(const short8*)&qb[(bh * QPAD + qr0 + l16) * 32 + quad * 8];
    const float4_t* bq = bfrag + (h * 13 + qt) * 13 * 64 + lane;
    float4_t s[13];
#pragma unroll
    for (int kt = 0; kt < 13; kt++) {
      short8 kf =
          *(const short8*)&kb[(bh * QPAD + kt * 16 + l16) * 32 + quad * 8];
      s[kt] =
          __builtin_amdgcn_mfma_f32_16x16x32_bf16(qf, kf, bq[kt * 64], 0, 0, 0);
    }
    if (l16 >= 4) {
#pragma unroll
      for (int r = 0; r < 4; r++) s[12][r] = -1e30f;  // mask pad keys
    }
    float invr[4];
#pragma unroll
    for (int r = 0; r < 4; r++) {
      // tree max over 13 (enables max3 fusion + ILP)
      float a0 = fmaxf(s[0][r], s[1][r]);
      float a1 = fmaxf(s[2][r], s[3][r]);
      float a2 = fmaxf(s[4][r], s[5][r]);
      float a3 = fmaxf(s[6][r], s[7][r]);
      float a4 = fmaxf(s[8][r], s[9][r]);
      float a5 = fmaxf(s[10][r], s[11][r]);
      float m = fmaxf(fmaxf(fmaxf(a0, a1), fmaxf(a2, a3)),
                      fmaxf(fmaxf(a4, a5), s[12][r]));
      m = red_fmax<0x128>(m);
      m = red_fmax<0x124>(m);
      m = red_fmax<0x122>(m);
      m = red_fmax<0x121>(m);
#pragma unroll
      for (int kt = 0; kt < 13; kt++) s[kt][r] = exp2f(s[kt][r] - m);
      float b0 = s[0][r] + s[1][r];
      float b1 = s[2][r] + s[3][r];
      float b2 = s[4][r] + s[5][r];
      float b3 = s[6][r] + s[7][r];
      float b4 = s[8][r] + s[9][r];
      float b5 = s[10][r] + s[11][r];
      float sum = ((b0 + b1) + (b2 + b3)) + ((b4 + b5) + s[12][r]);
      sum = red_add<0x128>(sum);
      sum = red_add<0x124>(sum);
      sum = red_add<0x122>(sum);
      sum = red_add<0x121>(sum);
      invr[r] = 1.f / sum;
      short* prow = &P[wave][quad * 4 + r][0];
#pragma unroll
      for (int j = 0; j < 6; j++) {
        unsigned u = cvt_pk_bf16(s[2 * j][r], s[2 * j + 1][r]);
        prow[(2 * j) * 16 + l16] = (short)u;
        prow[(2 * j + 1) * 16 + l16] = (short)(u >> 16);
      }
      prow[192 + l16] = f2bf(s[12][r]);  // unnormalized, <= 1
    }
    // in-wave LDS ordering guarantees P writes visible to same-wave reads
    float4_t o0 = z4, o1 = z4;
#pragma unroll
    for (int kt = 0; kt < 7; kt++) {
      short8 pf = *(short8*)&P[wave][l16][kt * 32 + quad * 8];
      short8 vf0 = *(short8*)&vT[l16][kt * 32 + quad * 8];
      short8 vf1 = *(short8*)&vT[16 + l16][kt * 32 + quad * 8];
      o0 = __builtin_amdgcn_mfma_f32_16x16x32_bf16(pf, vf0, o0, 0, 0, 0);
      o1 = __builtin_amdgcn_mfma_f32_16x16x32_bf16(pf, vf1, o1, 0, 0, 0);
    }
#pragma unroll
    for (int r = 0; r < 4; r++) {
      int row = qr0 + quad * 4 + r;
      if (row < NTOK) {
        int off = (base_row + row) * 512 + h * 32;
        aout[off + l16] = f2bf(o0[r] * invr[r]);
        aout[off + 16 + l16] = f2bf(o1[r] * invr[r]);
      }
    }
  }
}

// ---------------- fallback fused QKV-GEMM + attention (bias-frag version) ----
__global__ __launch_bounds__(256, 2) void fused_attn(
    const short* __restrict__ xb, const short* __restrict__ wt1,
    const float* __restrict__ bias, short* __restrict__ aout) {
  __shared__ __align__(16) short R1[64 * PSTR];
  __shared__ __align__(16) short R2[32 * PSTR];
  __shared__ __align__(16) short Qs[224][40];
  __shared__ __align__(16) short Ks[224][40];
  short(*As)[40] = (short(*)[40])R1;
  short(*P)[PSTR] = (short(*)[PSTR])R1;
  short(*Bs)[40] = (short(*)[40])R2;
  short(*vTs)[PSTR] = (short(*)[PSTR])R2;

  int bh = blockIdx.x, b = bh >> 4, h = bh & 15;
  int tid = threadIdx.x, wave = tid >> 6, lane = tid & 63;
  int quad = lane >> 4, l16 = lane & 15;
  int base_row = b * NTOK;

  float4_t z4 = {0.f, 0.f, 0.f, 0.f};
  float4_t acc[4][6];
#pragma unroll
  for (int i = 0; i < 4; i++)
#pragma unroll
    for (int n = 0; n < 6; n++) acc[i][n] = z4;

  int srow = tid >> 2, scol = (tid & 3) * 8;
  for (int k0 = 0; k0 < 512; k0 += 32) {
#pragma unroll
    for (int i = 0; i < 4; i++) {
      int r = srow + i * 64;
      if (r < 224) {
        int gr = base_row + r;
        if (gr > 25087) gr = 25087;
        *(short8*)&As[r][scol] = *(const short8*)&xb[gr * 512 + k0 + scol];
      }
    }
#pragma unroll
    for (int i = 0; i < 2; i++) {
      int r = srow + i * 64;
      if (r < 96) {
        int sec = r >> 5, r32 = r & 31;
        *(short8*)&Bs[r][scol] =
            *(const short8*)&wt1[(sec * 512 + h * 32 + r32) * 512 + k0 + scol];
      }
    }
    __syncthreads();
    short8 af[4], bfv[6];
#pragma unroll
    for (int i = 0; i < 4; i++) {
      int mt = (i < 3) ? (wave + 4 * i) : (12 + (wave & 1));
      af[i] = *(short8*)&As[mt * 16 + l16][quad * 8];
    }
#pragma unroll
    for (int n = 0; n < 6; n++) bfv[n] = *(short8*)&Bs[n * 16 + l16][quad * 8];
#pragma unroll
    for (int i = 0; i < 4; i++)
#pragma unroll
      for (int n = 0; n < 6; n++)
        acc[i][n] = __builtin_amdgcn_mfma_f32_16x16x32_bf16(af[i], bfv[n],
                                                            acc[i][n], 0, 0, 0);
    __syncthreads();
  }
  const float qscale = 0.17677669529663687f * 1.4426950408889634f;
#pragma unroll
  for (int i = 0; i < 4; i++) {
    if (i == 3 && wave >= 2) break;
    int mt = (i < 3) ? (wave + 4 * i) : (12 + wave);
    int row0 = mt * 16 + quad * 4;
#pragma unroll
    for (int n = 0; n < 6; n++) {
      int c = n * 16 + l16;
#pragma unroll
      for (int r = 0; r < 4; r++) {
        int row = row0 + r;
        float v = acc[i][n][r];
        if (c < 32)
          Qs[row][c] = f2bf(v * qscale);
        else if (c < 64)
          Ks[row][c - 32] = f2bf(v);
        else
          vTs[c - 64][row] = f2bf(v);
      }
    }
  }
  __syncthreads();
  for (int i2 = 0; i2 < 4; i2++) {
    bool active = (i2 < 3) || (wave == 0);
    int qt = (i2 < 3) ? (wave + 4 * i2) : 12;
    int qr0 = qt * 16;
    if (active) {
      short8 qf = *(short8*)&Qs[qr0 + l16][quad * 8];
      const float4_t* bq =
          (const float4_t*)bias + (h * 13 + qt) * 13 * 64 + lane;
      float4_t s[13];
#pragma unroll
      for (int kt = 0; kt < 13; kt++) {
        short8 kf = *(short8*)&Ks[kt * 16 + l16][quad * 8];
        s[kt] = __builtin_amdgcn_mfma_f32_16x16x32_bf16(qf, kf, bq[kt * 64], 0,
                                                        0, 0);
      }
      if (l16 >= 4) {
#pragma unroll
        for (int r = 0; r < 4; r++) s[12][r] = -1e30f;
      }
      int prow_base = wave * 16 + quad * 4;
#pragma unroll
      for (int r = 0; r < 4; r++) {
        float m = s[0][r];
#pragma unroll
        for (int kt = 1; kt < 13; kt++) m = fmaxf(m, s[kt][r]);
        m = fmaxf(m, __shfl_xor(m, 8, 16));
        m = fmaxf(m, __shfl_xor(m, 4, 16));
        m = fmaxf(m, __shfl_xor(m, 2, 16));
        m = fmaxf(m, __shfl_xor(m, 1, 16));
        float sum = 0.f;
#pragma unroll
        for (int kt = 0; kt < 13; kt++) {
          float p = exp2f(s[kt][r] - m);
          s[kt][r] = p;
          sum += p;
        }
        sum += __shfl_xor(sum, 8, 16);
        sum += __shfl_xor(sum, 4, 16);
        sum += __shfl_xor(sum, 2, 16);
        sum += __shfl_xor(sum, 1, 16);
        float inv = 1.f / sum;
        short* prow = &P[prow_base + r][0];
#pragma unroll
        for (int kt = 0; kt < 13; kt++)
          prow[kt * 16 + l16] = f2bf(s[kt][r] * inv);
        prow[208 + l16] = 0;
      }
    }
    __syncthreads();
    if (active) {
      float4_t o0 = z4, o1 = z4;
#pragma unroll
      for (int kt = 0; kt < 7; kt++) {
        short8 pf = *(short8*)&P[wave * 16 + l16][kt * 32 + quad * 8];
        short8 vf0 = *(short8*)&vTs[l16][kt * 32 + quad * 8];
        short8 vf1 = *(short8*)&vTs[16 + l16][kt * 32 + quad * 8];
        o0 = __builtin_amdgcn_mfma_f32_16x16x32_bf16(pf, vf0, o0, 0, 0, 0);
        o1 = __builtin_amdgcn_mfma_f32_16x16x32_bf16(pf, vf1, o1, 0, 0, 0);
      }
#pragma unroll
      for (int r = 0; r < 4; r++) {
        int row = qr0 + quad * 4 + r;
        if (row < NTOK) {
          int off = (base_row + row) * 512 + h * 32;
          aout[off + l16] = f2bf(o0[r]);
          aout[off + 16 + l16] = f2bf(o1[r]);
        }
      }
    }
    __syncthreads();
  }
}

// ------------- proj GEMM + bias: out_f32 = aout[25088,512] @ w2^T + b --------
__global__ __launch_bounds__(256) void proj_gemm(
    const short* __restrict__ a, const short* __restrict__ wt,
    const float* __restrict__ pb, float* __restrict__ out) {
  __shared__ __align__(16) short As[128][72];
  __shared__ __align__(16) short Bs[128][72];
  float4_t acc[4][4];
  float4_t z = {0.f, 0.f, 0.f, 0.f};
#pragma unroll
  for (int i = 0; i < 4; i++)
#pragma unroll
    for (int j = 0; j < 4; j++) acc[i][j] = z;
  // XCD-chunked bijective swizzle: nwg = 4*196 = 784 = 8*98
  int lin = blockIdx.x + blockIdx.y * 4;
  int xcd = lin & 7, loc = lin >> 3;
  int nl = xcd * 98 + loc;
  int bx = nl % 4, by = nl / 4;
  int m0 = by * 128, n0 = bx * 128;
  gemm_tile(a, wt, 512, m0, n0, As, Bs, acc);
  int lane = threadIdx.x & 63, wave = threadIdx.x >> 6;
  int quad = lane >> 4, l16 = lane & 15;
  int wm = (wave >> 1) * 64, wn = (wave & 1) * 64;
#pragma unroll
  for (int mi = 0; mi < 4; mi++)
#pragma unroll
    for (int ni = 0; ni < 4; ni++) {
      int colg = n0 + wn + ni * 16 + l16;
      float bv = pb[colg];
#pragma unroll
      for (int r = 0; r < 4; r++) {
        int rowg = m0 + wm + mi * 16 + quad * 4 + r;
        out[rowg * 512 + colg] = acc[mi][ni][r] + bv;
      }
    }
}

extern "C" void kernel_launch(void* const* d_in, const int* in_sizes, int n_in,
                              void* d_out, int out_size, void* d_ws,
                              size_t ws_size, hipStream_t stream) {
  const float* x = (const float*)d_in[0];       // [25088,512] fp32
  const float* qkv_w = (const float*)d_in[1];   // [512,1536] fp32
  const float* table = (const float*)d_in[2];   // [729,16] fp32
  const float* proj_w = (const float*)d_in[3];  // [512,512] fp32
  const float* proj_b = (const float*)d_in[4];  // [512] fp32
  const int* rpi = (const int*)d_in[5];         // [196,196] int32
  float* out = (float*)d_out;

  char* w = (char*)d_ws;
  short* wt1 = (short*)(w);              // 1536*512*2   = 1,572,864
  short* wt2 = (short*)(w + 1572864);    // 512*512*2    =   524,288
  float* bias = (float*)(w + 2097152);   // 16*13*13*64*4*4 = 2,768,896
  short* xb = (short*)(w + 4866048);     // 25088*512*2  = 25,690,112
  // split-path extra slabs (q,k,v) on top:
  short* qb = (short*)(w + 30556160);    // 2048*208*32*2 = 27,262,976
  short* kb = (short*)(w + 57819136);
  short* vb = (short*)(w + 85082112);    // V^T layout [bh][32][208], same size
  const size_t NEEDED_SPLIT = 112345088;
  const size_t NEEDED_FUSED = 30556160 + 25690112;  // fused path slabs

  int split = ws_size >= NEEDED_SPLIT;
  if (ws_size >= NEEDED_FUSED) {
    prep_kernel<<<10000, 256, 0, stream>>>(qkv_w, proj_w, table, rpi, x, wt1,
                                           wt2, bias, vb, xb, split);
  }
  if (split) {
    // split path: xb slab doubles as aout (xb dead after qkv_gemm)
    short* aout = xb;
    qkv_gemm<<<dim3(12, 196), 256, 0, stream>>>(xb, wt1, qb, kb, vb);
    attn_kernel<<<2048, 256, 0, stream>>>(qb, kb, vb, bias, aout);
    proj_gemm<<<dim3(4, 196), 256, 0, stream>>>(aout, wt2, proj_b, out);
  } else if (ws_size >= NEEDED_FUSED) {
    short* aout = (short*)(w + 30556160);  // separate slab, round-4 layout
    fused_attn<<<2048, 256, 0, stream>>>(xb, wt1, bias, aout);
    proj_gemm<<<dim3(4, 196), 256, 0, stream>>>(aout, wt2, proj_b, out);
  } else {
    fill_kernel<<<(out_size + 255) / 256, 256, 0, stream>>>(out, out_size);
  }
}

// Round 11
// 258.982 us; speedup vs baseline: 1.1638x; 1.0250x over previous
//
#include <hip/hip_runtime.h>

#define NTOK 196
#define QPAD 208
#define KP 208
#define PSTR 232
#define VKP 208

typedef __attribute__((ext_vector_type(8))) short short8;
typedef __attribute__((ext_vector_type(4))) short short4_t;
typedef __attribute__((ext_vector_type(4))) float float4_t;
typedef __attribute__((ext_vector_type(2))) unsigned int uint2_t;

__device__ __forceinline__ short f2bf(float f) {
  unsigned u = __float_as_uint(f);
  u = (u + 0x7fffu + ((u >> 16) & 1u)) >> 16;
  return (short)u;
}

// v_cvt_pk_bf16_f32: lo->bits[15:0], hi->bits[31:16], RNE (matches f2bf).
__device__ __forceinline__ unsigned cvt_pk_bf16(float lo, float hi) {
  unsigned r;
  asm("v_cvt_pk_bf16_f32 %0, %1, %2" : "=v"(r) : "v"(lo), "v"(hi));
  return r;
}

// ---------------- fallback: signal insufficient workspace ----------------
__global__ __launch_bounds__(256) void fill_kernel(float* __restrict__ out,
                                                   int n) {
  int i = blockIdx.x * 256 + threadIdx.x;
  if (i < n) out[i] = 1000.0f;
}

// ------------- transpose body: out_bf16[C][R] = in_f32[R][C] -----------------
__device__ __forceinline__ void transpose_body(const float* __restrict__ in,
                                               short* __restrict__ out, int R,
                                               int C, int bx, int by,
                                               float (*tile)[65]) {
  int c0 = bx * 64, r0 = by * 64;
  int tc = threadIdx.x & 63, tr = threadIdx.x >> 6;
#pragma unroll
  for (int s = 0; s < 16; s++) {
    int r = s * 4 + tr;
    tile[r][tc] = in[(r0 + r) * C + c0 + tc];
  }
  __syncthreads();
#pragma unroll
  for (int s = 0; s < 16; s++) {
    int i = s * 4 + tr;
    out[(c0 + i) * R + r0 + tc] = f2bf(tile[tc][i]);
  }
}

// ---- merged preamble: transposes + bias + V^T pad + x cvt (1 launch) ----
// blocks [0,192): qkv_w^T  [192,256): proj_w^T  [256,2960): bias-frag
// [2960,3728): vpad  [3728,10000): x fp32->bf16
// bias stored in MFMA-C fragment layout for the SWAPPED QK^T (mfma(K,Q)):
// C col = lane&15 = q, C row = (lane>>4)*4+r = key.  [h][qt13][kt13][lane64][r4]
// fp32, pre-scaled by log2(e) (softmax uses exp2; scale-invariant). 2.77MB.
__global__ __launch_bounds__(256) void prep_kernel(
    const float* __restrict__ qkv_w, const float* __restrict__ proj_w,
    const float* __restrict__ table, const int* __restrict__ rpi,
    const float* __restrict__ x, short* __restrict__ wt1,
    short* __restrict__ wt2, float* __restrict__ bias, short* __restrict__ vb,
    short* __restrict__ xb, int do_vpad) {
  __shared__ float tile[64][65];
  int blk = blockIdx.x;
  if (blk < 192) {
    transpose_body(qkv_w, wt1, 512, 1536, blk % 24, blk / 24, tile);
  } else if (blk < 256) {
    int i = blk - 192;
    transpose_body(proj_w, wt2, 512, 512, i % 8, i / 8, tile);
  } else if (blk < 2960) {
    int idx = (blk - 256) * 256 + threadIdx.x;  // < 16*13*13*64*4 = 692224
    int h = idx / 43264;                        // 13*13*64*4
    int rem = idx - h * 43264;
    int qt = rem / 3328;                        // 13*64*4
    int rem2 = rem - qt * 3328;
    int kt = rem2 >> 8;                         // 64*4
    int rem3 = rem2 & 255;
    int lane = rem3 >> 2, r = rem3 & 3;
    int q = qt * 16 + (lane & 15);              // swapped: col = q
    int k = kt * 16 + (lane >> 4) * 4 + r;      // swapped: row = key
    float v = 0.f;
    if (q < NTOK && k < NTOK)
      v = table[rpi[q * NTOK + k] * 16 + h] * 1.4426950408889634f;
    bias[idx] = v;
  } else if (blk < 3728) {
    if (do_vpad) {
      int i = (blk - 2960) * 256 + threadIdx.x;  // < 2048*32*3 = 196608
      int row = i / 3, g = i - 3 * (i / 3);
      short4_t z = {0, 0, 0, 0};
      *(short4_t*)&vb[row * VKP + 196 + g * 4] = z;
    }
  } else {
    int i = ((blk - 3728) * 256 + threadIdx.x) * 8;  // < 25088*512
    float4_t a = *(const float4_t*)&x[i];
    float4_t b = *(const float4_t*)&x[i + 4];
    short8 v;
    v[0] = f2bf(a[0]); v[1] = f2bf(a[1]); v[2] = f2bf(a[2]); v[3] = f2bf(a[3]);
    v[4] = f2bf(b[0]); v[5] = f2bf(b[1]); v[6] = f2bf(b[2]); v[7] = f2bf(b[3]);
    *(short8*)&xb[i] = v;
  }
}

// ---------------- shared 128x128 GEMM mainloop (validated, padded LDS) -------
// A/B settled (r4 vs r7): reg-staged+padded 78.4us beats global_load_lds+
// linear 84.6us at this shape (bank conflicts 4.8e6 vs 1.45e7). FINAL.
__device__ __forceinline__ void gemm_tile(const short* __restrict__ A,
                                          const short* __restrict__ B, int K,
                                          int m0, int n0, short (*As)[72],
                                          short (*Bs)[72], float4_t acc[4][4]) {
  int tid = threadIdx.x;
  int lane = tid & 63, wave = tid >> 6;
  int quad = lane >> 4, l16 = lane & 15;
  int wm = (wave >> 1) * 64, wn = (wave & 1) * 64;
  int srow = tid >> 3, scol = (tid & 7) * 8;
  for (int k0 = 0; k0 < K; k0 += 64) {
#pragma unroll
    for (int i = 0; i < 4; i++) {
      int r = srow + i * 32;
      *(short8*)&As[r][scol] = *(const short8*)&A[(m0 + r) * K + k0 + scol];
      *(short8*)&Bs[r][scol] = *(const short8*)&B[(n0 + r) * K + k0 + scol];
    }
    __syncthreads();
#pragma unroll
    for (int ks = 0; ks < 2; ks++) {
      short8 af[4], bfr[4];
#pragma unroll
      for (int i = 0; i < 4; i++) {
        af[i] = *(short8*)&As[wm + i * 16 + l16][ks * 32 + quad * 8];
        bfr[i] = *(short8*)&Bs[wn + i * 16 + l16][ks * 32 + quad * 8];
      }
#pragma unroll
      for (int mi = 0; mi < 4; mi++)
#pragma unroll
        for (int ni = 0; ni < 4; ni++)
          acc[mi][ni] = __builtin_amdgcn_mfma_f32_16x16x32_bf16(
              af[mi], bfr[ni], acc[mi][ni], 0, 0, 0);
    }
    __syncthreads();
  }
}

// -------- split path: QKV GEMM with scatter epilogue into q/k/v slabs --------
// V is written TRANSPOSED: vb[bh][d][VKP] so attn stages it with a coalesced
// row copy. Q is pre-scaled by 32^-0.5 * log2(e) for the exp2 softmax.
__global__ __launch_bounds__(256) void qkv_gemm(
    const short* __restrict__ xb, const short* __restrict__ wt1,
    short* __restrict__ qb, short* __restrict__ kb, short* __restrict__ vb) {
  __shared__ __align__(16) short As[128][72];
  __shared__ __align__(16) short Bs[128][72];
  float4_t acc[4][4];
  float4_t z = {0.f, 0.f, 0.f, 0.f};
#pragma unroll
  for (int i = 0; i < 4; i++)
#pragma unroll
    for (int j = 0; j < 4; j++) acc[i][j] = z;
  // XCD-chunked bijective swizzle: nwg = 12*196 = 2352 = 8*294
  int lin = blockIdx.x + blockIdx.y * 12;
  int xcd = lin & 7, loc = lin >> 3;
  int nl = xcd * 294 + loc;
  int bx = nl % 12, by = nl / 12;
  int m0 = by * 128, n0 = bx * 128;
  gemm_tile(xb, wt1, 512, m0, n0, As, Bs, acc);
  int lane = threadIdx.x & 63, wave = threadIdx.x >> 6;
  int quad = lane >> 4, l16 = lane & 15;
  int wm = (wave >> 1) * 64, wn = (wave & 1) * 64;
  const float qscale = 0.17677669529663687f * 1.4426950408889634f;
#pragma unroll
  for (int mi = 0; mi < 4; mi++)
#pragma unroll
    for (int ni = 0; ni < 4; ni++) {
      int colg = n0 + wn + ni * 16 + l16;
      int s = colg >> 9, rem = colg & 511;
      int h = rem >> 5, d = rem & 31;
      int rowg0 = m0 + wm + mi * 16 + quad * 4;
      if (s == 2) {
        int b = rowg0 / NTOK, nt = rowg0 - b * NTOK;  // nt % 4 == 0, <= 192
        short4_t v4;
        v4[0] = f2bf(acc[mi][ni][0]);
        v4[1] = f2bf(acc[mi][ni][1]);
        v4[2] = f2bf(acc[mi][ni][2]);
        v4[3] = f2bf(acc[mi][ni][3]);
        *(short4_t*)&vb[((b * 16 + h) * 32 + d) * VKP + nt] = v4;
      } else {
#pragma unroll
        for (int r = 0; r < 4; r++) {
          int rowg = rowg0 + r;
          int b = rowg / NTOK, n = rowg - b * NTOK;
          int off = ((b * 16 + h) * QPAD + n) * 32 + d;
          if (s == 0)
            qb[off] = f2bf(acc[mi][ni][r] * qscale);
          else
            kb[off] = f2bf(acc[mi][ni][r]);
        }
      }
    }
}

// -------- split path: attention, one block per (b,h), 4 waves --------
// SWAPPED QK^T: s = mfma(K, Q, bias^T) -> lane holds q = l16 (lane-local),
// keys = quad*4+r+16kt in registers. Softmax over keys = in-lane 52-tree +
// 2 shfl_xor (quads) + 4 shfl to redistribute 1/sum -- replaces 32 chained
// cross-lane ops/round. Operand loads identical to non-swapped (A/B frags
// share the lane layout). Pad-key mask = (quad>0 @ kt=12); masked exp2 -> 0
// fills P cols 196..207. P write: 13 aligned b64 stores to row l16.
// P is WAVE-PRIVATE -> only the staging barrier. Norm deferred to epilogue.
__global__ __launch_bounds__(256) void attn_kernel(
    const short* __restrict__ qb, const short* __restrict__ kb,
    const short* __restrict__ vb, const float* __restrict__ bias,
    short* __restrict__ aout) {
  __shared__ __align__(16) short vT[32][PSTR];
  __shared__ __align__(16) short P[4][16][PSTR];
  int bh = blockIdx.x, b = bh >> 4, h = bh & 15;
  int tid = threadIdx.x, wave = tid >> 6, lane = tid & 63;
  int quad = lane >> 4, l16 = lane & 15;
  int base_row = b * NTOK;
  // stage V^T rows: 32 rows x 208 shorts, coalesced 16B chunks
  const short* vsrc = vb + bh * 32 * VKP;
  for (int i = tid; i < 32 * 26; i += 256) {
    int d = i / 26, c = (i - d * 26) * 8;
    *(short8*)&vT[d][c] = *(const short8*)&vsrc[d * VKP + c];
  }
  short8 z8 = {0, 0, 0, 0, 0, 0, 0, 0};
  if (tid < 96) {
    int d = tid / 3, c = 208 + (tid - d * 3) * 8;
    *(short8*)&vT[d][c] = z8;
  }
  // P pad cols 208..223 never change: zero once per wave
  {
    short4_t zp = {0, 0, 0, 0};
    *(short4_t*)&P[wave][l16][208 + quad * 4] = zp;
  }
  __syncthreads();
  const float4_t* bfrag = (const float4_t*)bias;  // [h][13][13][64] float4
  float4_t z4 = {0.f, 0.f, 0.f, 0.f};
  for (int i2 = 0; i2 < 4; i2++) {
    bool active = (i2 < 3) || (wave == 0);
    if (!active) break;  // no barriers below: inactive waves simply exit
    int qt = (i2 < 3) ? (wave + 4 * i2) : 12;
    int qr0 = qt * 16;
    short8 qf = *(const short8*)&qb[(bh * QPAD + qr0 + l16) * 32 + quad * 8];
    const float4_t* bq = bfrag + (h * 13 + qt) * 13 * 64 + lane;
    float4_t s[13];
#pragma unroll
    for (int kt = 0; kt < 13; kt++) {
      short8 kf =
          *(const short8*)&kb[(bh * QPAD + kt * 16 + l16) * 32 + quad * 8];
      s[kt] =
          __builtin_amdgcn_mfma_f32_16x16x32_bf16(kf, qf, bq[kt * 64], 0, 0, 0);
    }
    if (quad > 0) {  // kt=12 rows = keys 192+quad*4+r >= 196: mask
#pragma unroll
      for (int r = 0; r < 4; r++) s[12][r] = -1e30f;
    }
    // in-lane max over 52 values (keys owned by this lane)
    float mx = fmaxf(fmaxf(s[0][0], s[0][1]), fmaxf(s[0][2], s[0][3]));
#pragma unroll
    for (int kt = 1; kt < 13; kt++) {
      float a = fmaxf(fmaxf(s[kt][0], s[kt][1]), fmaxf(s[kt][2], s[kt][3]));
      mx = fmaxf(mx, a);
    }
    mx = fmaxf(mx, __shfl_xor(mx, 16, 64));
    mx = fmaxf(mx, __shfl_xor(mx, 32, 64));
    float4_t ps = z4;
#pragma unroll
    for (int kt = 0; kt < 13; kt++) {
#pragma unroll
      for (int r = 0; r < 4; r++) {
        float p = exp2f(s[kt][r] - mx);  // S pre-scaled by log2(e)
        s[kt][r] = p;
        ps[r] += p;
      }
    }
    float sum = (ps[0] + ps[1]) + (ps[2] + ps[3]);
    sum += __shfl_xor(sum, 16, 64);
    sum += __shfl_xor(sum, 32, 64);
    float inv = 1.f / sum;  // valid for q = l16
    // epilogue rows are q = quad*4+r: fetch inv from lane l16 = quad*4+r
    float invq[4];
#pragma unroll
    for (int r = 0; r < 4; r++) invq[r] = __shfl(inv, quad * 4 + r, 16);
    // P write: row l16, cols kt*16 + quad*4 .. +3 (8B aligned)
    short* prow = &P[wave][l16][0];
#pragma unroll
    for (int kt = 0; kt < 13; kt++) {
      uint2_t w;
      w[0] = cvt_pk_bf16(s[kt][0], s[kt][1]);
      w[1] = cvt_pk_bf16(s[kt][2], s[kt][3]);
      *(uint2_t*)&prow[kt * 16 + quad * 4] = w;  // unnormalized, <= 1
    }
    // in-wave LDS ordering guarantees P writes visible to same-wave reads
    float4_t o0 = z4, o1 = z4;
#pragma unroll
    for (int kt = 0; kt < 7; kt++) {
      short8 pf = *(short8*)&P[wave][l16][kt * 32 + quad * 8];
      short8 vf0 = *(short8*)&vT[l16][kt * 32 + quad * 8];
      short8 vf1 = *(short8*)&vT[16 + l16][kt * 32 + quad * 8];
      o0 = __builtin_amdgcn_mfma_f32_16x16x32_bf16(pf, vf0, o0, 0, 0, 0);
      o1 = __builtin_amdgcn_mfma_f32_16x16x32_bf16(pf, vf1, o1, 0, 0, 0);
    }
#pragma unroll
    for (int r = 0; r < 4; r++) {
      int row = qr0 + quad * 4 + r;
      if (row < NTOK) {
        int off = (base_row + row) * 512 + h * 32;
        aout[off + l16] = f2bf(o0[r] * invq[r]);
        aout[off + 16 + l16] = f2bf(o1[r] * invq[r]);
      }
    }
  }
}

// ---------------- fallback fused QKV-GEMM + attention (swapped, mirrored) ----
__global__ __launch_bounds__(256, 2) void fused_attn(
    const short* __restrict__ xb, const short* __restrict__ wt1,
    const float* __restrict__ bias, short* __restrict__ aout) {
  __shared__ __align__(16) short R1[64 * PSTR];
  __shared__ __align__(16) short R2[32 * PSTR];
  __shared__ __align__(16) short Qs[224][40];
  __shared__ __align__(16) short Ks[224][40];
  short(*As)[40] = (short(*)[40])R1;
  short(*P)[PSTR] = (short(*)[PSTR])R1;
  short(*Bs)[40] = (short(*)[40])R2;
  short(*vTs)[PSTR] = (short(*)[PSTR])R2;

  int bh = blockIdx.x, b = bh >> 4, h = bh & 15;
  int tid = threadIdx.x, wave = tid >> 6, lane = tid & 63;
  int quad = lane >> 4, l16 = lane & 15;
  int base_row = b * NTOK;

  float4_t z4 = {0.f, 0.f, 0.f, 0.f};
  float4_t acc[4][6];
#pragma unroll
  for (int i = 0; i < 4; i++)
#pragma unroll
    for (int n = 0; n < 6; n++) acc[i][n] = z4;

  int srow = tid >> 2, scol = (tid & 3) * 8;
  for (int k0 = 0; k0 < 512; k0 += 32) {
#pragma unroll
    for (int i = 0; i < 4; i++) {
      int r = srow + i * 64;
      if (r < 224) {
        int gr = base_row + r;
        if (gr > 25087) gr = 25087;
        *(short8*)&As[r][scol] = *(const short8*)&xb[gr * 512 + k0 + scol];
      }
    }
#pragma unroll
    for (int i = 0; i < 2; i++) {
      int r = srow + i * 64;
      if (r < 96) {
        int sec = r >> 5, r32 = r & 31;
        *(short8*)&Bs[r][scol] =
            *(const short8*)&wt1[(sec * 512 + h * 32 + r32) * 512 + k0 + scol];
      }
    }
    __syncthreads();
    short8 af[4], bfv[6];
#pragma unroll
    for (int i = 0; i < 4; i++) {
      int mt = (i < 3) ? (wave + 4 * i) : (12 + (wave & 1));
      af[i] = *(short8*)&As[mt * 16 + l16][quad * 8];
    }
#pragma unroll
    for (int n = 0; n < 6; n++) bfv[n] = *(short8*)&Bs[n * 16 + l16][quad * 8];
#pragma unroll
    for (int i = 0; i < 4; i++)
#pragma unroll
      for (int n = 0; n < 6; n++)
        acc[i][n] = __builtin_amdgcn_mfma_f32_16x16x32_bf16(af[i], bfv[n],
                                                            acc[i][n], 0, 0, 0);
    __syncthreads();
  }
  const float qscale = 0.17677669529663687f * 1.4426950408889634f;
#pragma unroll
  for (int i = 0; i < 4; i++) {
    if (i == 3 && wave >= 2) break;
    int mt = (i < 3) ? (wave + 4 * i) : (12 + wave);
    int row0 = mt * 16 + quad * 4;
#pragma unroll
    for (int n = 0; n < 6; n++) {
      int c = n * 16 + l16;
#pragma unroll
      for (int r = 0; r < 4; r++) {
        int row = row0 + r;
        float v = acc[i][n][r];
        if (c < 32)
          Qs[row][c] = f2bf(v * qscale);
        else if (c < 64)
          Ks[row][c - 32] = f2bf(v);
        else
          vTs[c - 64][row] = f2bf(v);
      }
    }
  }
  __syncthreads();
  // P pad cols 208..223: zero once (wave-private rows, written before use)
  {
    short4_t zp = {0, 0, 0, 0};
    *(short4_t*)&P[wave * 16 + l16][208 + quad * 4] = zp;
  }
  for (int i2 = 0; i2 < 4; i2++) {
    bool active = (i2 < 3) || (wave == 0);
    int qt = (i2 < 3) ? (wave + 4 * i2) : 12;
    int qr0 = qt * 16;
    float invq[4];
    if (active) {
      short8 qf = *(short8*)&Qs[qr0 + l16][quad * 8];
      const float4_t* bq =
          (const float4_t*)bias + (h * 13 + qt) * 13 * 64 + lane;
      float4_t s[13];
#pragma unroll
      for (int kt = 0; kt < 13; kt++) {
        short8 kf = *(short8*)&Ks[kt * 16 + l16][quad * 8];
        s[kt] = __builtin_amdgcn_mfma_f32_16x16x32_bf16(kf, qf, bq[kt * 64], 0,
                                                        0, 0);
      }
      if (quad > 0) {
#pragma unroll
        for (int r = 0; r < 4; r++) s[12][r] = -1e30f;
      }
      float mx = fmaxf(fmaxf(s[0][0], s[0][1]), fmaxf(s[0][2], s[0][3]));
#pragma unroll
      for (int kt = 1; kt < 13; kt++) {
        float a = fmaxf(fmaxf(s[kt][0], s[kt][1]), fmaxf(s[kt][2], s[kt][3]));
        mx = fmaxf(mx, a);
      }
      mx = fmaxf(mx, __shfl_xor(mx, 16, 64));
      mx = fmaxf(mx, __shfl_xor(mx, 32, 64));
      float4_t ps = z4;
#pragma unroll
      for (int kt = 0; kt < 13; kt++) {
#pragma unroll
        for (int r = 0; r < 4; r++) {
          float p = exp2f(s[kt][r] - mx);
          s[kt][r] = p;
          ps[r] += p;
        }
      }
      float sum = (ps[0] + ps[1]) + (ps[2] + ps[3]);
      sum += __shfl_xor(sum, 16, 64);
      sum += __shfl_xor(sum, 32, 64);
      float inv = 1.f / sum;
#pragma unroll
      for (int r = 0; r < 4; r++) invq[r] = __shfl(inv, quad * 4 + r, 16);
      short* prow = &P[wave * 16 + l16][0];
#pragma unroll
      for (int kt = 0; kt < 13; kt++) {
        uint2_t w;
        w[0] = cvt_pk_bf16(s[kt][0], s[kt][1]);
        w[1] = cvt_pk_bf16(s[kt][2], s[kt][3]);
        *(uint2_t*)&prow[kt * 16 + quad * 4] = w;
      }
    }
    __syncthreads();
    if (active) {
      float4_t o0 = z4, o1 = z4;
#pragma unroll
      for (int kt = 0; kt < 7; kt++) {
        short8 pf = *(short8*)&P[wave * 16 + l16][kt * 32 + quad * 8];
        short8 vf0 = *(short8*)&vTs[l16][kt * 32 + quad * 8];
        short8 vf1 = *(short8*)&vTs[16 + l16][kt * 32 + quad * 8];
        o0 = __builtin_amdgcn_mfma_f32_16x16x32_bf16(pf, vf0, o0, 0, 0, 0);
        o1 = __builtin_amdgcn_mfma_f32_16x16x32_bf16(pf, vf1, o1, 0, 0, 0);
      }
#pragma unroll
      for (int r = 0; r < 4; r++) {
        int row = qr0 + quad * 4 + r;
        if (row < NTOK) {
          int off = (base_row + row) * 512 + h * 32;
          aout[off + l16] = f2bf(o0[r] * invq[r]);
          aout[off + 16 + l16] = f2bf(o1[r] * invq[r]);
        }
      }
    }
    __syncthreads();
  }
}

// ------------- proj GEMM + bias: out_f32 = aout[25088,512] @ w2^T + b --------
__global__ __launch_bounds__(256) void proj_gemm(
    const short* __restrict__ a, const short* __restrict__ wt,
    const float* __restrict__ pb, float* __restrict__ out) {
  __shared__ __align__(16) short As[128][72];
  __shared__ __align__(16) short Bs[128][72];
  float4_t acc[4][4];
  float4_t z = {0.f, 0.f, 0.f, 0.f};
#pragma unroll
  for (int i = 0; i < 4; i++)
#pragma unroll
    for (int j = 0; j < 4; j++) acc[i][j] = z;
  // XCD-chunked bijective swizzle: nwg = 4*196 = 784 = 8*98
  int lin = blockIdx.x + blockIdx.y * 4;
  int xcd = lin & 7, loc = lin >> 3;
  int nl = xcd * 98 + loc;
  int bx = nl % 4, by = nl / 4;
  int m0 = by * 128, n0 = bx * 128;
  gemm_tile(a, wt, 512, m0, n0, As, Bs, acc);
  int lane = threadIdx.x & 63, wave = threadIdx.x >> 6;
  int quad = lane >> 4, l16 = lane & 15;
  int wm = (wave >> 1) * 64, wn = (wave & 1) * 64;
#pragma unroll
  for (int mi = 0; mi < 4; mi++)
#pragma unroll
    for (int ni = 0; ni < 4; ni++) {
      int colg = n0 + wn + ni * 16 + l16;
      float bv = pb[colg];
#pragma unroll
      for (int r = 0; r < 4; r++) {
        int rowg = m0 + wm + mi * 16 + quad * 4 + r;
        out[rowg * 512 + colg] = acc[mi][ni][r] + bv;
      }
    }
}

extern "C" void kernel_launch(void* const* d_in, const int* in_sizes, int n_in,
                              void* d_out, int out_size, void* d_ws,
                              size_t ws_size, hipStream_t stream) {
  const float* x = (const float*)d_in[0];       // [25088,512] fp32
  const float* qkv_w = (const float*)d_in[1];   // [512,1536] fp32
  const float* table = (const float*)d_in[2];   // [729,16] fp32
  const float* proj_w = (const float*)d_in[3];  // [512,512] fp32
  const float* proj_b = (const float*)d_in[4];  // [512] fp32
  const int* rpi = (const int*)d_in[5];         // [196,196] int32
  float* out = (float*)d_out;

  char* w = (char*)d_ws;
  short* wt1 = (short*)(w);              // 1536*512*2   = 1,572,864
  short* wt2 = (short*)(w + 1572864);    // 512*512*2    =   524,288
  float* bias = (float*)(w + 2097152);   // 16*13*13*64*4*4 = 2,768,896
  short* xb = (short*)(w + 4866048);     // 25088*512*2  = 25,690,112
  // split-path extra slabs (q,k,v) on top:
  short* qb = (short*)(w + 30556160);    // 2048*208*32*2 = 27,262,976
  short* kb = (short*)(w + 57819136);
  short* vb = (short*)(w + 85082112);    // V^T layout [bh][32][208], same size
  const size_t NEEDED_SPLIT = 112345088;
  const size_t NEEDED_FUSED = 30556160 + 25690112;  // fused path slabs

  int split = ws_size >= NEEDED_SPLIT;
  if (ws_size >= NEEDED_FUSED) {
    prep_kernel<<<10000, 256, 0, stream>>>(qkv_w, proj_w, table, rpi, x, wt1,
                                           wt2, bias, vb, xb, split);
  }
  if (split) {
    // split path: xb slab doubles as aout (xb dead after qkv_gemm)
    short* aout = xb;
    qkv_gemm<<<dim3(12, 196), 256, 0, stream>>>(xb, wt1, qb, kb, vb);
    attn_kernel<<<2048, 256, 0, stream>>>(qb, kb, vb, bias, aout);
    proj_gemm<<<dim3(4, 196), 256, 0, stream>>>(aout, wt2, proj_b, out);
  } else if (ws_size >= NEEDED_FUSED) {
    short* aout = (short*)(w + 30556160);  // separate slab, round-4 layout
    fused_attn<<<2048, 256, 0, stream>>>(xb, wt1, bias, aout);
    proj_gemm<<<dim3(4, 196), 256, 0, stream>>>(aout, wt2, proj_b, out);
  } else {
    fill_kernel<<<(out_size + 255) / 256, 256, 0, stream>>>(out, out_size);
  }
}

// Round 12
// 258.619 us; speedup vs baseline: 1.1654x; 1.0014x over previous
//
#include <hip/hip_runtime.h>

#define NTOK 196
#define QPAD 208
#define KP 208
#define PSTR 232
#define VKP 208

typedef __attribute__((ext_vector_type(8))) short short8;
typedef __attribute__((ext_vector_type(4))) short short4_t;
typedef __attribute__((ext_vector_type(4))) float float4_t;
typedef __attribute__((ext_vector_type(2))) unsigned int uint2_t;

__device__ __forceinline__ short f2bf(float f) {
  unsigned u = __float_as_uint(f);
  u = (u + 0x7fffu + ((u >> 16) & 1u)) >> 16;
  return (short)u;
}

// v_cvt_pk_bf16_f32: lo->bits[15:0], hi->bits[31:16], RNE (matches f2bf).
__device__ __forceinline__ unsigned cvt_pk_bf16(float lo, float hi) {
  unsigned r;
  asm("v_cvt_pk_bf16_f32 %0, %1, %2" : "=v"(r) : "v"(lo), "v"(hi));
  return r;
}

// ---------------- fallback: signal insufficient workspace ----------------
__global__ __launch_bounds__(256) void fill_kernel(float* __restrict__ out,
                                                   int n) {
  int i = blockIdx.x * 256 + threadIdx.x;
  if (i < n) out[i] = 1000.0f;
}

// ------------- transpose body: out_bf16[C][R] = in_f32[R][C] -----------------
__device__ __forceinline__ void transpose_body(const float* __restrict__ in,
                                               short* __restrict__ out, int R,
                                               int C, int bx, int by,
                                               float (*tile)[65]) {
  int c0 = bx * 64, r0 = by * 64;
  int tc = threadIdx.x & 63, tr = threadIdx.x >> 6;
#pragma unroll
  for (int s = 0; s < 16; s++) {
    int r = s * 4 + tr;
    tile[r][tc] = in[(r0 + r) * C + c0 + tc];
  }
  __syncthreads();
#pragma unroll
  for (int s = 0; s < 16; s++) {
    int i = s * 4 + tr;
    out[(c0 + i) * R + r0 + tc] = f2bf(tile[tc][i]);
  }
}

// ---- merged preamble: transposes + bias + V^T pad + x cvt (1 launch) ----
// blocks [0,192): qkv_w^T  [192,256): proj_w^T  [256,2960): bias-frag
// [2960,3728): vpad  [3728,10000): x fp32->bf16
// bias stored in MFMA-C fragment layout for the SWAPPED QK^T (mfma(K,Q)):
// C col = lane&15 = q, C row = (lane>>4)*4+r = key.  [h][qt13][kt13][lane64][r4]
// fp32, pre-scaled by log2(e) (softmax uses exp2; scale-invariant). 2.77MB.
__global__ __launch_bounds__(256) void prep_kernel(
    const float* __restrict__ qkv_w, const float* __restrict__ proj_w,
    const float* __restrict__ table, const int* __restrict__ rpi,
    const float* __restrict__ x, short* __restrict__ wt1,
    short* __restrict__ wt2, float* __restrict__ bias, short* __restrict__ vb,
    short* __restrict__ xb, int do_vpad) {
  __shared__ float tile[64][65];
  int blk = blockIdx.x;
  if (blk < 192) {
    transpose_body(qkv_w, wt1, 512, 1536, blk % 24, blk / 24, tile);
  } else if (blk < 256) {
    int i = blk - 192;
    transpose_body(proj_w, wt2, 512, 512, i % 8, i / 8, tile);
  } else if (blk < 2960) {
    int idx = (blk - 256) * 256 + threadIdx.x;  // < 16*13*13*64*4 = 692224
    int h = idx / 43264;                        // 13*13*64*4
    int rem = idx - h * 43264;
    int qt = rem / 3328;                        // 13*64*4
    int rem2 = rem - qt * 3328;
    int kt = rem2 >> 8;                         // 64*4
    int rem3 = rem2 & 255;
    int lane = rem3 >> 2, r = rem3 & 3;
    int q = qt * 16 + (lane & 15);              // swapped: col = q
    int k = kt * 16 + (lane >> 4) * 4 + r;      // swapped: row = key
    float v = 0.f;
    if (q < NTOK && k < NTOK)
      v = table[rpi[q * NTOK + k] * 16 + h] * 1.4426950408889634f;
    bias[idx] = v;
  } else if (blk < 3728) {
    if (do_vpad) {
      int i = (blk - 2960) * 256 + threadIdx.x;  // < 2048*32*3 = 196608
      int row = i / 3, g = i - 3 * (i / 3);
      short4_t z = {0, 0, 0, 0};
      *(short4_t*)&vb[row * VKP + 196 + g * 4] = z;
    }
  } else {
    int i = ((blk - 3728) * 256 + threadIdx.x) * 8;  // < 25088*512
    float4_t a = *(const float4_t*)&x[i];
    float4_t b = *(const float4_t*)&x[i + 4];
    short8 v;
    v[0] = f2bf(a[0]); v[1] = f2bf(a[1]); v[2] = f2bf(a[2]); v[3] = f2bf(a[3]);
    v[4] = f2bf(b[0]); v[5] = f2bf(b[1]); v[6] = f2bf(b[2]); v[7] = f2bf(b[3]);
    *(short8*)&xb[i] = v;
  }
}

// ---------------- shared 128x128 GEMM mainloop (validated, padded LDS) -------
// A/B settled (r4 vs r7): reg-staged+padded 78.4us beats global_load_lds+
// linear 84.6us at this shape (bank conflicts 4.8e6 vs 1.45e7). FINAL.
__device__ __forceinline__ void gemm_tile(const short* __restrict__ A,
                                          const short* __restrict__ B, int K,
                                          int m0, int n0, short (*As)[72],
                                          short (*Bs)[72], float4_t acc[4][4]) {
  int tid = threadIdx.x;
  int lane = tid & 63, wave = tid >> 6;
  int quad = lane >> 4, l16 = lane & 15;
  int wm = (wave >> 1) * 64, wn = (wave & 1) * 64;
  int srow = tid >> 3, scol = (tid & 7) * 8;
  for (int k0 = 0; k0 < K; k0 += 64) {
#pragma unroll
    for (int i = 0; i < 4; i++) {
      int r = srow + i * 32;
      *(short8*)&As[r][scol] = *(const short8*)&A[(m0 + r) * K + k0 + scol];
      *(short8*)&Bs[r][scol] = *(const short8*)&B[(n0 + r) * K + k0 + scol];
    }
    __syncthreads();
#pragma unroll
    for (int ks = 0; ks < 2; ks++) {
      short8 af[4], bfr[4];
#pragma unroll
      for (int i = 0; i < 4; i++) {
        af[i] = *(short8*)&As[wm + i * 16 + l16][ks * 32 + quad * 8];
        bfr[i] = *(short8*)&Bs[wn + i * 16 + l16][ks * 32 + quad * 8];
      }
#pragma unroll
      for (int mi = 0; mi < 4; mi++)
#pragma unroll
        for (int ni = 0; ni < 4; ni++)
          acc[mi][ni] = __builtin_amdgcn_mfma_f32_16x16x32_bf16(
              af[mi], bfr[ni], acc[mi][ni], 0, 0, 0);
    }
    __syncthreads();
  }
}

// -------- split path: QKV GEMM with scatter epilogue into q/k/v slabs --------
// V is written TRANSPOSED: vb[bh][d][VKP] so attn stages it with a coalesced
// row copy. Q is pre-scaled by 32^-0.5 * log2(e) for the exp2 softmax.
__global__ __launch_bounds__(256) void qkv_gemm(
    const short* __restrict__ xb, const short* __restrict__ wt1,
    short* __restrict__ qb, short* __restrict__ kb, short* __restrict__ vb) {
  __shared__ __align__(16) short As[128][72];
  __shared__ __align__(16) short Bs[128][72];
  float4_t acc[4][4];
  float4_t z = {0.f, 0.f, 0.f, 0.f};
#pragma unroll
  for (int i = 0; i < 4; i++)
#pragma unroll
    for (int j = 0; j < 4; j++) acc[i][j] = z;
  // XCD-chunked bijective swizzle: nwg = 12*196 = 2352 = 8*294
  int lin = blockIdx.x + blockIdx.y * 12;
  int xcd = lin & 7, loc = lin >> 3;
  int nl = xcd * 294 + loc;
  int bx = nl % 12, by = nl / 12;
  int m0 = by * 128, n0 = bx * 128;
  gemm_tile(xb, wt1, 512, m0, n0, As, Bs, acc);
  int lane = threadIdx.x & 63, wave = threadIdx.x >> 6;
  int quad = lane >> 4, l16 = lane & 15;
  int wm = (wave >> 1) * 64, wn = (wave & 1) * 64;
  const float qscale = 0.17677669529663687f * 1.4426950408889634f;
#pragma unroll
  for (int mi = 0; mi < 4; mi++)
#pragma unroll
    for (int ni = 0; ni < 4; ni++) {
      int colg = n0 + wn + ni * 16 + l16;
      int s = colg >> 9, rem = colg & 511;
      int h = rem >> 5, d = rem & 31;
      int rowg0 = m0 + wm + mi * 16 + quad * 4;
      if (s == 2) {
        int b = rowg0 / NTOK, nt = rowg0 - b * NTOK;  // nt % 4 == 0, <= 192
        short4_t v4;
        v4[0] = f2bf(acc[mi][ni][0]);
        v4[1] = f2bf(acc[mi][ni][1]);
        v4[2] = f2bf(acc[mi][ni][2]);
        v4[3] = f2bf(acc[mi][ni][3]);
        *(short4_t*)&vb[((b * 16 + h) * 32 + d) * VKP + nt] = v4;
      } else {
#pragma unroll
        for (int r = 0; r < 4; r++) {
          int rowg = rowg0 + r;
          int b = rowg / NTOK, n = rowg - b * NTOK;
          int off = ((b * 16 + h) * QPAD + n) * 32 + d;
          if (s == 0)
            qb[off] = f2bf(acc[mi][ni][r] * qscale);
          else
            kb[off] = f2bf(acc[mi][ni][r]);
        }
      }
    }
}

// -------- split path: attention, one block per (b,h), 4 waves --------
// SWAPPED QK^T (r11, validated) + P KEPT IN REGISTERS: the PV A-fragment is
// a fixed quad-permutation of the lane-local P values, built with
// v_permlane32_swap + v_permlane16_swap (4 VALU swaps per kt2):
//   E=w[2kt2], O=w[2kt2+1]; p32: a'={E0,E1,O0,O1}, b'={E2,E3,O2,O3};
//   p16: T1={E0,E2,O0,O2}(=u0/u1), T2={E1,E3,O1,O3}(=u2/u3).
// Verified per-element for all 4 dest quads. This deletes the P LDS slab
// (29.7 KB) and its 13 ds_write_b64 + 7 ds_read_b128 + lgkm waits per round.
// LDS = vT only (14.8 KB) -> 4 blocks/CU. Norm deferred to epilogue.
__global__ __launch_bounds__(256) void attn_kernel(
    const short* __restrict__ qb, const short* __restrict__ kb,
    const short* __restrict__ vb, const float* __restrict__ bias,
    short* __restrict__ aout) {
  __shared__ __align__(16) short vT[32][PSTR];
  int bh = blockIdx.x, b = bh >> 4, h = bh & 15;
  int tid = threadIdx.x, wave = tid >> 6, lane = tid & 63;
  int quad = lane >> 4, l16 = lane & 15;
  int base_row = b * NTOK;
  // stage V^T rows: 32 rows x 208 shorts, coalesced 16B chunks
  const short* vsrc = vb + bh * 32 * VKP;
  for (int i = tid; i < 32 * 26; i += 256) {
    int d = i / 26, c = (i - d * 26) * 8;
    *(short8*)&vT[d][c] = *(const short8*)&vsrc[d * VKP + c];
  }
  short8 z8 = {0, 0, 0, 0, 0, 0, 0, 0};
  if (tid < 96) {
    int d = tid / 3, c = 208 + (tid - d * 3) * 8;
    *(short8*)&vT[d][c] = z8;
  }
  __syncthreads();
  const float4_t* bfrag = (const float4_t*)bias;  // [h][13][13][64] float4
  float4_t z4 = {0.f, 0.f, 0.f, 0.f};
  for (int i2 = 0; i2 < 4; i2++) {
    bool active = (i2 < 3) || (wave == 0);
    if (!active) break;  // no barriers below: inactive waves simply exit
    int qt = (i2 < 3) ? (wave + 4 * i2) : 12;
    int qr0 = qt * 16;
    short8 qf = *(const short8*)&qb[(bh * QPAD + qr0 + l16) * 32 + quad * 8];
    const float4_t* bq = bfrag + (h * 13 + qt) * 13 * 64 + lane;
    float4_t s[13];
#pragma unroll
    for (int kt = 0; kt < 13; kt++) {
      short8 kf =
          *(const short8*)&kb[(bh * QPAD + kt * 16 + l16) * 32 + quad * 8];
      s[kt] =
          __builtin_amdgcn_mfma_f32_16x16x32_bf16(kf, qf, bq[kt * 64], 0, 0, 0);
    }
    if (quad > 0) {  // kt=12 rows = keys 192+quad*4+r >= 196: mask
#pragma unroll
      for (int r = 0; r < 4; r++) s[12][r] = -1e30f;
    }
    // in-lane max over 52 values (keys owned by this lane)
    float mx = fmaxf(fmaxf(s[0][0], s[0][1]), fmaxf(s[0][2], s[0][3]));
#pragma unroll
    for (int kt = 1; kt < 13; kt++) {
      float a = fmaxf(fmaxf(s[kt][0], s[kt][1]), fmaxf(s[kt][2], s[kt][3]));
      mx = fmaxf(mx, a);
    }
    mx = fmaxf(mx, __shfl_xor(mx, 16, 64));
    mx = fmaxf(mx, __shfl_xor(mx, 32, 64));
    float4_t ps = z4;
#pragma unroll
    for (int kt = 0; kt < 13; kt++) {
#pragma unroll
      for (int r = 0; r < 4; r++) {
        float p = exp2f(s[kt][r] - mx);  // S pre-scaled by log2(e)
        s[kt][r] = p;
        ps[r] += p;
      }
    }
    float sum = (ps[0] + ps[1]) + (ps[2] + ps[3]);
    sum += __shfl_xor(sum, 16, 64);
    sum += __shfl_xor(sum, 32, 64);
    float inv = 1.f / sum;  // valid for q = l16
    // epilogue rows are q = quad*4+r: fetch inv from lane l16 = quad*4+r
    float invq[4];
#pragma unroll
    for (int r = 0; r < 4; r++) invq[r] = __shfl(inv, quad * 4 + r, 16);
    // pack P in registers: w[kt] = {pk(r0,r1), pk(r2,r3)}, w[13]=0 (keys 208+)
    unsigned w[14][2];
#pragma unroll
    for (int kt = 0; kt < 13; kt++) {
      w[kt][0] = cvt_pk_bf16(s[kt][0], s[kt][1]);
      w[kt][1] = cvt_pk_bf16(s[kt][2], s[kt][3]);
    }
    w[13][0] = 0u;
    w[13][1] = 0u;
    float4_t o0 = z4, o1 = z4;
#pragma unroll
    for (int kt2 = 0; kt2 < 7; kt2++) {
      unsigned ax = w[2 * kt2][0], bx2 = w[2 * kt2 + 1][0];
      unsigned ay = w[2 * kt2][1], by2 = w[2 * kt2 + 1][1];
      asm("v_permlane32_swap_b32 %0, %1" : "+v"(ax), "+v"(bx2));
      asm("v_permlane16_swap_b32 %0, %1" : "+v"(ax), "+v"(bx2));
      asm("v_permlane32_swap_b32 %0, %1" : "+v"(ay), "+v"(by2));
      asm("v_permlane16_swap_b32 %0, %1" : "+v"(ay), "+v"(by2));
      union {
        unsigned u[4];
        short8 s8;
      } pfu;
      pfu.u[0] = ax;   // keys j0,  j0+1
      pfu.u[1] = ay;   // keys j0+2,j0+3
      pfu.u[2] = bx2;  // keys j0+4,j0+5
      pfu.u[3] = by2;  // keys j0+6,j0+7
      short8 vf0 = *(short8*)&vT[l16][kt2 * 32 + quad * 8];
      short8 vf1 = *(short8*)&vT[16 + l16][kt2 * 32 + quad * 8];
      o0 = __builtin_amdgcn_mfma_f32_16x16x32_bf16(pfu.s8, vf0, o0, 0, 0, 0);
      o1 = __builtin_amdgcn_mfma_f32_16x16x32_bf16(pfu.s8, vf1, o1, 0, 0, 0);
    }
#pragma unroll
    for (int r = 0; r < 4; r++) {
      int row = qr0 + quad * 4 + r;
      if (row < NTOK) {
        int off = (base_row + row) * 512 + h * 32;
        aout[off + l16] = f2bf(o0[r] * invq[r]);
        aout[off + 16 + l16] = f2bf(o1[r] * invq[r]);
      }
    }
  }
}

// ---------------- fallback fused QKV-GEMM + attention (swapped, mirrored) ----
__global__ __launch_bounds__(256, 2) void fused_attn(
    const short* __restrict__ xb, const short* __restrict__ wt1,
    const float* __restrict__ bias, short* __restrict__ aout) {
  __shared__ __align__(16) short R1[64 * PSTR];
  __shared__ __align__(16) short R2[32 * PSTR];
  __shared__ __align__(16) short Qs[224][40];
  __shared__ __align__(16) short Ks[224][40];
  short(*As)[40] = (short(*)[40])R1;
  short(*P)[PSTR] = (short(*)[PSTR])R1;
  short(*Bs)[40] = (short(*)[40])R2;
  short(*vTs)[PSTR] = (short(*)[PSTR])R2;

  int bh = blockIdx.x, b = bh >> 4, h = bh & 15;
  int tid = threadIdx.x, wave = tid >> 6, lane = tid & 63;
  int quad = lane >> 4, l16 = lane & 15;
  int base_row = b * NTOK;

  float4_t z4 = {0.f, 0.f, 0.f, 0.f};
  float4_t acc[4][6];
#pragma unroll
  for (int i = 0; i < 4; i++)
#pragma unroll
    for (int n = 0; n < 6; n++) acc[i][n] = z4;

  int srow = tid >> 2, scol = (tid & 3) * 8;
  for (int k0 = 0; k0 < 512; k0 += 32) {
#pragma unroll
    for (int i = 0; i < 4; i++) {
      int r = srow + i * 64;
      if (r < 224) {
        int gr = base_row + r;
        if (gr > 25087) gr = 25087;
        *(short8*)&As[r][scol] = *(const short8*)&xb[gr * 512 + k0 + scol];
      }
    }
#pragma unroll
    for (int i = 0; i < 2; i++) {
      int r = srow + i * 64;
      if (r < 96) {
        int sec = r >> 5, r32 = r & 31;
        *(short8*)&Bs[r][scol] =
            *(const short8*)&wt1[(sec * 512 + h * 32 + r32) * 512 + k0 + scol];
      }
    }
    __syncthreads();
    short8 af[4], bfv[6];
#pragma unroll
    for (int i = 0; i < 4; i++) {
      int mt = (i < 3) ? (wave + 4 * i) : (12 + (wave & 1));
      af[i] = *(short8*)&As[mt * 16 + l16][quad * 8];
    }
#pragma unroll
    for (int n = 0; n < 6; n++) bfv[n] = *(short8*)&Bs[n * 16 + l16][quad * 8];
#pragma unroll
    for (int i = 0; i < 4; i++)
#pragma unroll
      for (int n = 0; n < 6; n++)
        acc[i][n] = __builtin_amdgcn_mfma_f32_16x16x32_bf16(af[i], bfv[n],
                                                            acc[i][n], 0, 0, 0);
    __syncthreads();
  }
  const float qscale = 0.17677669529663687f * 1.4426950408889634f;
#pragma unroll
  for (int i = 0; i < 4; i++) {
    if (i == 3 && wave >= 2) break;
    int mt = (i < 3) ? (wave + 4 * i) : (12 + wave);
    int row0 = mt * 16 + quad * 4;
#pragma unroll
    for (int n = 0; n < 6; n++) {
      int c = n * 16 + l16;
#pragma unroll
      for (int r = 0; r < 4; r++) {
        int row = row0 + r;
        float v = acc[i][n][r];
        if (c < 32)
          Qs[row][c] = f2bf(v * qscale);
        else if (c < 64)
          Ks[row][c - 32] = f2bf(v);
        else
          vTs[c - 64][row] = f2bf(v);
      }
    }
  }
  __syncthreads();
  // P pad cols 208..223: zero once (wave-private rows, written before use)
  {
    short4_t zp = {0, 0, 0, 0};
    *(short4_t*)&P[wave * 16 + l16][208 + quad * 4] = zp;
  }
  for (int i2 = 0; i2 < 4; i2++) {
    bool active = (i2 < 3) || (wave == 0);
    int qt = (i2 < 3) ? (wave + 4 * i2) : 12;
    int qr0 = qt * 16;
    float invq[4];
    if (active) {
      short8 qf = *(short8*)&Qs[qr0 + l16][quad * 8];
      const float4_t* bq =
          (const float4_t*)bias + (h * 13 + qt) * 13 * 64 + lane;
      float4_t s[13];
#pragma unroll
      for (int kt = 0; kt < 13; kt++) {
        short8 kf = *(short8*)&Ks[kt * 16 + l16][quad * 8];
        s[kt] = __builtin_amdgcn_mfma_f32_16x16x32_bf16(kf, qf, bq[kt * 64], 0,
                                                        0, 0);
      }
      if (quad > 0) {
#pragma unroll
        for (int r = 0; r < 4; r++) s[12][r] = -1e30f;
      }
      float mx = fmaxf(fmaxf(s[0][0], s[0][1]), fmaxf(s[0][2], s[0][3]));
#pragma unroll
      for (int kt = 1; kt < 13; kt++) {
        float a = fmaxf(fmaxf(s[kt][0], s[kt][1]), fmaxf(s[kt][2], s[kt][3]));
        mx = fmaxf(mx, a);
      }
      mx = fmaxf(mx, __shfl_xor(mx, 16, 64));
      mx = fmaxf(mx, __shfl_xor(mx, 32, 64));
      float4_t ps = z4;
#pragma unroll
      for (int kt = 0; kt < 13; kt++) {
#pragma unroll
        for (int r = 0; r < 4; r++) {
          float p = exp2f(s[kt][r] - mx);
          s[kt][r] = p;
          ps[r] += p;
        }
      }
      float sum = (ps[0] + ps[1]) + (ps[2] + ps[3]);
      sum += __shfl_xor(sum, 16, 64);
      sum += __shfl_xor(sum, 32, 64);
      float inv = 1.f / sum;
#pragma unroll
      for (int r = 0; r < 4; r++) invq[r] = __shfl(inv, quad * 4 + r, 16);
      short* prow = &P[wave * 16 + l16][0];
#pragma unroll
      for (int kt = 0; kt < 13; kt++) {
        uint2_t w;
        w[0] = cvt_pk_bf16(s[kt][0], s[kt][1]);
        w[1] = cvt_pk_bf16(s[kt][2], s[kt][3]);
        *(uint2_t*)&prow[kt * 16 + quad * 4] = w;
      }
    }
    __syncthreads();
    if (active) {
      float4_t o0 = z4, o1 = z4;
#pragma unroll
      for (int kt = 0; kt < 7; kt++) {
        short8 pf = *(short8*)&P[wave * 16 + l16][kt * 32 + quad * 8];
        short8 vf0 = *(short8*)&vTs[l16][kt * 32 + quad * 8];
        short8 vf1 = *(short8*)&vTs[16 + l16][kt * 32 + quad * 8];
        o0 = __builtin_amdgcn_mfma_f32_16x16x32_bf16(pf, vf0, o0, 0, 0, 0);
        o1 = __builtin_amdgcn_mfma_f32_16x16x32_bf16(pf, vf1, o1, 0, 0, 0);
      }
#pragma unroll
      for (int r = 0; r < 4; r++) {
        int row = qr0 + quad * 4 + r;
        if (row < NTOK) {
          int off = (base_row + row) * 512 + h * 32;
          aout[off + l16] = f2bf(o0[r] * invq[r]);
          aout[off + 16 + l16] = f2bf(o1[r] * invq[r]);
        }
      }
    }
    __syncthreads();
  }
}

// ------------- proj GEMM + bias: out_f32 = aout[25088,512] @ w2^T + b --------
__global__ __launch_bounds__(256) void proj_gemm(
    const short* __restrict__ a, const short* __restrict__ wt,
    const float* __restrict__ pb, float* __restrict__ out) {
  __shared__ __align__(16) short As[128][72];
  __shared__ __align__(16) short Bs[128][72];
  float4_t acc[4][4];
  float4_t z = {0.f, 0.f, 0.f, 0.f};
#pragma unroll
  for (int i = 0; i < 4; i++)
#pragma unroll
    for (int j = 0; j < 4; j++) acc[i][j] = z;
  // XCD-chunked bijective swizzle: nwg = 4*196 = 784 = 8*98
  int lin = blockIdx.x + blockIdx.y * 4;
  int xcd = lin & 7, loc = lin >> 3;
  int nl = xcd * 98 + loc;
  int bx = nl % 4, by = nl / 4;
  int m0 = by * 128, n0 = bx * 128;
  gemm_tile(a, wt, 512, m0, n0, As, Bs, acc);
  int lane = threadIdx.x & 63, wave = threadIdx.x >> 6;
  int quad = lane >> 4, l16 = lane & 15;
  int wm = (wave >> 1) * 64, wn = (wave & 1) * 64;
#pragma unroll
  for (int mi = 0; mi < 4; mi++)
#pragma unroll
    for (int ni = 0; ni < 4; ni++) {
      int colg = n0 + wn + ni * 16 + l16;
      float bv = pb[colg];
#pragma unroll
      for (int r = 0; r < 4; r++) {
        int rowg = m0 + wm + mi * 16 + quad * 4 + r;
        out[rowg * 512 + colg] = acc[mi][ni][r] + bv;
      }
    }
}

extern "C" void kernel_launch(void* const* d_in, const int* in_sizes, int n_in,
                              void* d_out, int out_size, void* d_ws,
                              size_t ws_size, hipStream_t stream) {
  const float* x = (const float*)d_in[0];       // [25088,512] fp32
  const float* qkv_w = (const float*)d_in[1];   // [512,1536] fp32
  const float* table = (const float*)d_in[2];   // [729,16] fp32
  const float* proj_w = (const float*)d_in[3];  // [512,512] fp32
  const float* proj_b = (const float*)d_in[4];  // [512] fp32
  const int* rpi = (const int*)d_in[5];         // [196,196] int32
  float* out = (float*)d_out;

  char* w = (char*)d_ws;
  short* wt1 = (short*)(w);              // 1536*512*2   = 1,572,864
  short* wt2 = (short*)(w + 1572864);    // 512*512*2    =   524,288
  float* bias = (float*)(w + 2097152);   // 16*13*13*64*4*4 = 2,768,896
  short* xb = (short*)(w + 4866048);     // 25088*512*2  = 25,690,112
  // split-path extra slabs (q,k,v) on top:
  short* qb = (short*)(w + 30556160);    // 2048*208*32*2 = 27,262,976
  short* kb = (short*)(w + 57819136);
  short* vb = (short*)(w + 85082112);    // V^T layout [bh][32][208], same size
  const size_t NEEDED_SPLIT = 112345088;
  const size_t NEEDED_FUSED = 30556160 + 25690112;  // fused path slabs

  int split = ws_size >= NEEDED_SPLIT;
  if (ws_size >= NEEDED_FUSED) {
    prep_kernel<<<10000, 256, 0, stream>>>(qkv_w, proj_w, table, rpi, x, wt1,
                                           wt2, bias, vb, xb, split);
  }
  if (split) {
    // split path: xb slab doubles as aout (xb dead after qkv_gemm)
    short* aout = xb;
    qkv_gemm<<<dim3(12, 196), 256, 0, stream>>>(xb, wt1, qb, kb, vb);
    attn_kernel<<<2048, 256, 0, stream>>>(qb, kb, vb, bias, aout);
    proj_gemm<<<dim3(4, 196), 256, 0, stream>>>(aout, wt2, proj_b, out);
  } else if (ws_size >= NEEDED_FUSED) {
    short* aout = (short*)(w + 30556160);  // separate slab, round-4 layout
    fused_attn<<<2048, 256, 0, stream>>>(xb, wt1, bias, aout);
    proj_gemm<<<dim3(4, 196), 256, 0, stream>>>(aout, wt2, proj_b, out);
  } else {
    fill_kernel<<<(out_size + 255) / 256, 256, 0, stream>>>(out, out_size);
  }
}